// Round 1
// baseline (1999.173 us; speedup 1.0000x reference)
//
#include <hip/hip_runtime.h>
#include <hip/hip_bf16.h>
#include <math.h>

#define NDIM 2048
#define EDIM 5
#define CDIM 2
#define WIN 256
#define WOUT 128
#define NCLS 8
#define NTGT 1024
#define NN ((size_t)NDIM * NDIM)

// ---------------------------------------------------------------------------
// init: softmax of the three [C,E] weight mats (-> ws + d_out Ws slots),
// zero loss accumulators and degree buffers. d_ws is poisoned 0xAA each call.
// ---------------------------------------------------------------------------
__global__ void init_k(const float* __restrict__ w0a, const float* __restrict__ w0b,
                       const float* __restrict__ w1a,
                       float* __restrict__ sw, float* __restrict__ acc,
                       float* __restrict__ deg, float* __restrict__ dout) {
  int tid = threadIdx.x;  // 64 threads
  if (tid < 6) {
    int m = tid >> 1, c = tid & 1;
    const float* src = (m == 0) ? w0a : (m == 1) ? w0b : w1a;
    float mx = -1e30f;
    for (int e = 0; e < EDIM; ++e) mx = fmaxf(mx, src[c * EDIM + e]);
    float ex[EDIM]; float s = 0.f;
    for (int e = 0; e < EDIM; ++e) { ex[e] = expf(src[c * EDIM + e] - mx); s += ex[e]; }
    for (int e = 0; e < EDIM; ++e) {
      float r = ex[e] / s;
      sw[m * 10 + c * EDIM + e] = r;
      dout[1 + NTGT * NCLS + m * 10 + c * EDIM + e] = r;  // Ws outputs
    }
  }
  if (tid < 16) acc[tid] = 0.f;
  for (int i = tid; i < CDIM * NDIM; i += 64) deg[i] = 0.f;
}

// ---------------------------------------------------------------------------
// a[c] and b[c] from A (softmax-weighted sum over E), one pass over A.
// ---------------------------------------------------------------------------
__global__ __launch_bounds__(256) void wsum_ab_k(const float* __restrict__ A,
                                                 const float* __restrict__ sw,
                                                 float* __restrict__ a_out,
                                                 float* __restrict__ b_out) {
  size_t idx = (size_t)blockIdx.x * 256 + threadIdx.x;  // n*N+m
  float v[EDIM];
#pragma unroll
  for (int e = 0; e < EDIM; ++e) v[e] = A[idx * EDIM + e];
#pragma unroll
  for (int c = 0; c < CDIM; ++c) {
    float sa = 0.f, sb = 0.f;
#pragma unroll
    for (int e = 0; e < EDIM; ++e) {
      sa += sw[c * EDIM + e] * v[e];
      sb += sw[10 + c * EDIM + e] * v[e];
    }
    a_out[c * NN + idx] = sa;
    b_out[c * NN + idx] = sb;
  }
}

__global__ __launch_bounds__(256) void wsum_one_k(const float* __restrict__ A,
                                                  const float* __restrict__ sw,
                                                  float* __restrict__ a_out) {
  size_t idx = (size_t)blockIdx.x * 256 + threadIdx.x;
  float v[EDIM];
#pragma unroll
  for (int e = 0; e < EDIM; ++e) v[e] = A[idx * EDIM + e];
#pragma unroll
  for (int c = 0; c < CDIM; ++c) {
    float sa = 0.f;
#pragma unroll
    for (int e = 0; e < EDIM; ++e) sa += sw[c * EDIM + e] * v[e];
    a_out[c * NN + idx] = sa;
  }
}

// ---------------------------------------------------------------------------
// fp32 GEMM: C[M,Nn] = A[M,K] @ B[K,Nn] (all row-major), optional relu.
// 64x64 tile, BK=16, 256 threads, 4x4 per thread. M,Nn %64==0, K%16==0.
// ---------------------------------------------------------------------------
#define TS 64
#define BK 16
__global__ __launch_bounds__(256) void sgemm_k(const float* __restrict__ A,
                                               const float* __restrict__ B,
                                               float* __restrict__ C,
                                               int M, int K, int Nn,
                                               int lda, int ldb, int ldc, int relu) {
  __shared__ float As[BK][TS];
  __shared__ float Bs[BK][TS + 4];
  const int tid = threadIdx.x;
  const int brow = blockIdx.y * TS;
  const int bcol = blockIdx.x * TS;
  const int tx = tid & 15;
  const int ty = tid >> 4;
  const int la_r = tid >> 2;
  const int la_k = (tid & 3) << 2;
  const int lb_k = tid >> 4;
  const int lb_c = (tid & 15) << 2;
  float acc[4][4] = {{0.f}};
  for (int k0 = 0; k0 < K; k0 += BK) {
    float4 av = *(const float4*)(A + (size_t)(brow + la_r) * lda + k0 + la_k);
    float4 bv = *(const float4*)(B + (size_t)(k0 + lb_k) * ldb + bcol + lb_c);
    __syncthreads();
    As[la_k + 0][la_r] = av.x;
    As[la_k + 1][la_r] = av.y;
    As[la_k + 2][la_r] = av.z;
    As[la_k + 3][la_r] = av.w;
    *(float4*)&Bs[lb_k][lb_c] = bv;
    __syncthreads();
#pragma unroll
    for (int kk = 0; kk < BK; ++kk) {
      float a0 = As[kk][ty * 4 + 0], a1 = As[kk][ty * 4 + 1];
      float a2 = As[kk][ty * 4 + 2], a3 = As[kk][ty * 4 + 3];
      float b0 = Bs[kk][tx * 4 + 0], b1 = Bs[kk][tx * 4 + 1];
      float b2 = Bs[kk][tx * 4 + 2], b3 = Bs[kk][tx * 4 + 3];
      acc[0][0] += a0 * b0; acc[0][1] += a0 * b1; acc[0][2] += a0 * b2; acc[0][3] += a0 * b3;
      acc[1][0] += a1 * b0; acc[1][1] += a1 * b1; acc[1][2] += a1 * b2; acc[1][3] += a1 * b3;
      acc[2][0] += a2 * b0; acc[2][1] += a2 * b1; acc[2][2] += a2 * b2; acc[2][3] += a2 * b3;
      acc[3][0] += a3 * b0; acc[3][1] += a3 * b1; acc[3][2] += a3 * b2; acc[3][3] += a3 * b3;
    }
  }
#pragma unroll
  for (int i = 0; i < 4; ++i) {
    float4 o;
    o.x = acc[i][0]; o.y = acc[i][1]; o.z = acc[i][2]; o.w = acc[i][3];
    if (relu) {
      o.x = fmaxf(o.x, 0.f); o.y = fmaxf(o.y, 0.f);
      o.z = fmaxf(o.z, 0.f); o.w = fmaxf(o.w, 0.f);
    }
    *(float4*)(C + (size_t)(brow + ty * 4 + i) * ldc + bcol + tx * 4) = o;
  }
}

// ---------------------------------------------------------------------------
// column-degree (diag excluded) + column scale: norm(H, add=False) in place.
// ---------------------------------------------------------------------------
__global__ __launch_bounds__(256) void col_degree_k(const float* __restrict__ H,
                                                    float* __restrict__ deg) {
  int j = blockIdx.x * 256 + threadIdx.x;
  int i0 = blockIdx.y * 128;
  float s = 0.f;
  for (int i = i0; i < i0 + 128; ++i)
    if (i != j) s += H[(size_t)i * NDIM + j];
  atomicAdd(&deg[j], s);
}

__global__ __launch_bounds__(256) void col_scale_k(float* __restrict__ H,
                                                   const float* __restrict__ deg) {
  size_t idx = (size_t)blockIdx.x * 256 + threadIdx.x;
  int i = (int)(idx >> 11), j = (int)(idx & (NDIM - 1));
  float d = deg[j];
  float inv = (d == 0.f) ? 0.f : 1.f / d;
  float v = (i == j) ? 0.f : H[idx];
  H[idx] = v * inv;
}

// ---------------------------------------------------------------------------
// transpose 2048x2048 (LDS tiled)
// ---------------------------------------------------------------------------
__global__ void transpose_k(const float* __restrict__ S, float* __restrict__ D) {
  __shared__ float tile[32][33];
  int bx = blockIdx.x * 32;
  int by = blockIdx.y * 32;
  int tx = threadIdx.x;  // 32
  int ty = threadIdx.y;  // 8
#pragma unroll
  for (int r = 0; r < 32; r += 8)
    tile[ty + r][tx] = S[(size_t)(by + ty + r) * NDIM + bx + tx];
  __syncthreads();
#pragma unroll
  for (int r = 0; r < 32; r += 8)
    D[(size_t)(bx + ty + r) * NDIM + by + tx] = tile[tx][ty + r];
}

__global__ __launch_bounds__(256) void add2_k(const float* __restrict__ A,
                                              const float* __restrict__ B,
                                              float* __restrict__ O) {
  size_t i = (size_t)blockIdx.x * 256 + threadIdx.x;
  O[i] = A[i] + B[i];
}

// ---------------------------------------------------------------------------
// row-normalize with diagonal forced to 1 (transposed norm(...,add=True)):
// out[i][j] = ((j==i)?1:M[i][j]) / rowsum_with_diag1(i)
// ---------------------------------------------------------------------------
__global__ __launch_bounds__(256) void rownorm_diag1_k(float* __restrict__ Mt) {
  const int i = blockIdx.x;
  const int tid = threadIdx.x;
  float s = 0.f;
  for (int j = tid; j < NDIM; j += 256) {
    float v = (j == i) ? 1.f : Mt[(size_t)i * NDIM + j];
    s += v;
  }
  for (int off = 32; off > 0; off >>= 1) s += __shfl_down(s, off, 64);
  __shared__ float red[4];
  __shared__ float inv_s;
  if ((tid & 63) == 0) red[tid >> 6] = s;
  __syncthreads();
  if (tid == 0) {
    float t = red[0] + red[1] + red[2] + red[3];
    inv_s = (t == 0.f) ? 0.f : 1.f / t;
  }
  __syncthreads();
  float inv = inv_s;
  for (int j = tid; j < NDIM; j += 256) {
    float v = (j == i) ? 1.f : Mt[(size_t)i * NDIM + j];
    Mt[(size_t)i * NDIM + j] = v * inv;
  }
}

// ---------------------------------------------------------------------------
// BCE reconstruction loss accumulation over X_r vs X (sum of terms -> acc[1])
// ---------------------------------------------------------------------------
__global__ __launch_bounds__(256) void lossR_k(const float* __restrict__ Xr,
                                               const float* __restrict__ X,
                                               float* __restrict__ acc) {
  size_t i = (size_t)blockIdx.x * 256 + threadIdx.x;
  float xr = Xr[i];
  if (xr > 1.f) xr = 1.f / (1.f + expf(-xr));
  if (xr < 0.f) xr = 1.f / (1.f + expf(-xr));
  float p = fminf(fmaxf(xr, 1e-7f), 1.f - 1e-7f);
  float xv = X[i];
  float t = xv * logf(p) + (1.f - xv) * log1pf(-p);
  for (int off = 32; off > 0; off >>= 1) t += __shfl_down(t, off, 64);
  __shared__ float red[4];
  if ((threadIdx.x & 63) == 0) red[threadIdx.x >> 6] = t;
  __syncthreads();
  if (threadIdx.x == 0) atomicAdd(acc, red[0] + red[1] + red[2] + red[3]);
}

// ---------------------------------------------------------------------------
// y = X_o[target_x] @ lin_w^T + lin_b  (written to d_out), plus
// classification loss accumulation (sum of lse - y[target] -> acc[0])
// ---------------------------------------------------------------------------
__global__ __launch_bounds__(64) void y_loss_k(const float* __restrict__ Xo,
                                               const float* __restrict__ lin_w,
                                               const float* __restrict__ lin_b,
                                               const int* __restrict__ txs,
                                               const int* __restrict__ tgt,
                                               float* __restrict__ yout,
                                               float* __restrict__ accC) {
  int t = blockIdx.x;
  int lane = threadIdx.x;
  __shared__ float xo[WOUT];
  __shared__ float ys[NCLS];
  int x = txs[t];
  xo[lane] = Xo[(size_t)x * WOUT + lane];
  xo[lane + 64] = Xo[(size_t)x * WOUT + 64 + lane];
  __syncthreads();
  if (lane < NCLS) {
    float s = lin_b[lane];
    for (int d = 0; d < WOUT; ++d) s += xo[d] * lin_w[lane * WOUT + d];
    ys[lane] = s;
    yout[(size_t)t * NCLS + lane] = s;
  }
  __syncthreads();
  if (lane == 0) {
    float m = ys[0];
    for (int k = 1; k < NCLS; ++k) m = fmaxf(m, ys[k]);
    float se = 0.f;
    for (int k = 0; k < NCLS; ++k) se += expf(ys[k] - m);
    float lse = m + logf(se);
    atomicAdd(accC, lse - ys[tgt[t]]);
  }
}

__global__ void finalize_k(const float* __restrict__ acc, float* __restrict__ dout) {
  float lossC = acc[0] / (float)NTGT;
  float lossR = -acc[1] / (float)(NDIM * WIN);
  dout[0] = lossC + lossR;
  dout[1 + NTGT * NCLS + 30] = lossR;
}

// ---------------------------------------------------------------------------
extern "C" void kernel_launch(void* const* d_in, const int* in_sizes, int n_in,
                              void* d_out, int out_size, void* d_ws, size_t ws_size,
                              hipStream_t stream) {
  const float* A    = (const float*)d_in[0];
  const float* X    = (const float*)d_in[1];
  const float* W    = (const float*)d_in[2];
  const float* W1   = (const float*)d_in[3];
  const float* W2   = (const float*)d_in[4];
  const float* linw = (const float*)d_in[5];
  const float* linb = (const float*)d_in[6];
  const float* w0a  = (const float*)d_in[7];
  const float* w0b  = (const float*)d_in[8];
  const float* w1a  = (const float*)d_in[9];
  const int* txs    = (const int*)d_in[10];
  const int* tgt    = (const int*)d_in[11];
  float* dout = (float*)d_out;

  float* ws = (float*)d_ws;
  float* a_buf = ws;                       // C*NN : a -> a1 -> T (H1^T)
  float* b_buf = ws + 2 * NN;              // C*NN : b -> H1
  float* h_buf = ws + 4 * NN;              // C*NN : H -> Hn ; [0:NN] later Tsum/HsT
  float* sw    = ws + 6 * NN;              // 32
  float* acc   = sw + 32;                  // 16 ([0]=lossC sum, [1]=lossR sum)
  float* deg   = acc + 16;                 // C*N
  float* XW    = deg + CDIM * NDIM;        // N*WOUT
  float* Xcat  = XW + (size_t)NDIM * WOUT; // N*2*WOUT
  float* XC1   = Xcat + (size_t)NDIM * 2 * WOUT;
  float* XC2   = XC1 + (size_t)NDIM * WOUT;
  float* Xo    = XC2 + (size_t)NDIM * WIN;
  float* Xr    = Xo + (size_t)NDIM * WOUT;

  dim3 blk256(256);
  dim3 gridNN((unsigned)(NN / 256));
  dim3 gemm_grid_big(NDIM / TS, NDIM / TS);

  // 1. softmaxes + zero accumulators/deg
  init_k<<<dim3(1), dim3(64), 0, stream>>>(w0a, w0b, w1a, sw, acc, deg, dout);
  // 2. a, b
  wsum_ab_k<<<gridNN, blk256, 0, stream>>>(A, sw, a_buf, b_buf);
  // 3. H[c] = a[c] @ b[c]
  for (int c = 0; c < CDIM; ++c)
    sgemm_k<<<gemm_grid_big, blk256, 0, stream>>>(a_buf + c * NN, b_buf + c * NN,
                                                  h_buf + c * NN, NDIM, NDIM, NDIM,
                                                  NDIM, NDIM, NDIM, 0);
  // 4. Hn[c] = norm(H[c], add=False) in place
  for (int c = 0; c < CDIM; ++c) {
    col_degree_k<<<dim3(NDIM / 256, 16), blk256, 0, stream>>>(h_buf + c * NN, deg + c * NDIM);
    col_scale_k<<<gridNN, blk256, 0, stream>>>(h_buf + c * NN, deg + c * NDIM);
  }
  // 5. a1
  wsum_one_k<<<gridNN, blk256, 0, stream>>>(A, sw + 20, a_buf);
  // 6. H1[c] = Hn[c] @ a1[c]
  for (int c = 0; c < CDIM; ++c)
    sgemm_k<<<gemm_grid_big, blk256, 0, stream>>>(h_buf + c * NN, a_buf + c * NN,
                                                  b_buf + c * NN, NDIM, NDIM, NDIM,
                                                  NDIM, NDIM, NDIM, 0);
  // 7. T[c] = H1[c]^T
  for (int c = 0; c < CDIM; ++c)
    transpose_k<<<dim3(NDIM / 32, NDIM / 32), dim3(32, 8), 0, stream>>>(b_buf + c * NN,
                                                                        a_buf + c * NN);
  // 8. Tsum = T0 + T1 (= Hsum^T)
  add2_k<<<gridNN, blk256, 0, stream>>>(a_buf, a_buf + NN, h_buf);
  // 9. row-normalize (diag=1): Hn2T[c] and HsT
  rownorm_diag1_k<<<dim3(NDIM), blk256, 0, stream>>>(a_buf);
  rownorm_diag1_k<<<dim3(NDIM), blk256, 0, stream>>>(a_buf + NN);
  rownorm_diag1_k<<<dim3(NDIM), blk256, 0, stream>>>(h_buf);
  // 10. XW = X @ W
  sgemm_k<<<dim3(WOUT / TS, NDIM / TS), blk256, 0, stream>>>(X, W, XW, NDIM, WIN, WOUT,
                                                             WIN, WOUT, WOUT, 0);
  // 11. Xcat[:, c*128:(c+1)*128] = relu(Hn2T[c] @ XW)
  for (int c = 0; c < CDIM; ++c)
    sgemm_k<<<dim3(WOUT / TS, NDIM / TS), blk256, 0, stream>>>(a_buf + c * NN, XW,
                                                               Xcat + c * WOUT, NDIM, NDIM,
                                                               WOUT, NDIM, WOUT, 2 * WOUT, 1);
  // 12. XC1 = Xcat @ W1 ; XC2 = Xcat @ W2
  sgemm_k<<<dim3(WOUT / TS, NDIM / TS), blk256, 0, stream>>>(Xcat, W1, XC1, NDIM, 2 * WOUT,
                                                             WOUT, 2 * WOUT, WOUT, WOUT, 0);
  sgemm_k<<<dim3(WIN / TS, NDIM / TS), blk256, 0, stream>>>(Xcat, W2, XC2, NDIM, 2 * WOUT,
                                                            WIN, 2 * WOUT, WIN, WIN, 0);
  // 13. Xo = HsT @ XC1 ; Xr = HsT @ XC2
  sgemm_k<<<dim3(WOUT / TS, NDIM / TS), blk256, 0, stream>>>(h_buf, XC1, Xo, NDIM, NDIM,
                                                             WOUT, NDIM, WOUT, WOUT, 0);
  sgemm_k<<<dim3(WIN / TS, NDIM / TS), blk256, 0, stream>>>(h_buf, XC2, Xr, NDIM, NDIM,
                                                            WIN, NDIM, WIN, WIN, 0);
  // 14. losses + y
  lossR_k<<<dim3((unsigned)(NDIM * WIN / 256)), blk256, 0, stream>>>(Xr, X, acc + 1);
  y_loss_k<<<dim3(NTGT), dim3(64), 0, stream>>>(Xo, linw, linb, txs, tgt, dout + 1, acc);
  finalize_k<<<dim3(1), dim3(1), 0, stream>>>(acc, dout);
}

// Round 2
// 575.883 us; speedup vs baseline: 3.4715x; 3.4715x over previous
//
#include <hip/hip_runtime.h>
#include <hip/hip_bf16.h>
#include <math.h>

#define NDIM 2048
#define EDIM 5
#define CDIM 2
#define WIN 256
#define WOUT 128
#define NCLS 8
#define NTGT 1024
#define NN ((size_t)NDIM * NDIM)

typedef __attribute__((ext_vector_type(8))) short short8v;
typedef __attribute__((ext_vector_type(4))) float float4v;

__device__ __forceinline__ void gl2lds16(const void* g, void* l) {
  __builtin_amdgcn_global_load_lds((__attribute__((address_space(1))) const unsigned int*)g,
                                   (__attribute__((address_space(3))) unsigned int*)l, 16, 0, 0);
}

// ---------------------------------------------------------------------------
// init: softmax of the three [C,E] weight mats, zero accumulators + degrees
// ---------------------------------------------------------------------------
__global__ void init_k(const float* __restrict__ w0a, const float* __restrict__ w0b,
                       const float* __restrict__ w1a,
                       float* __restrict__ sw, float* __restrict__ acc,
                       float* __restrict__ deg, float* __restrict__ dout) {
  int tid = threadIdx.x;  // 64
  if (tid < 6) {
    int m = tid >> 1, c = tid & 1;
    const float* src = (m == 0) ? w0a : (m == 1) ? w0b : w1a;
    float mx = -1e30f;
    for (int e = 0; e < EDIM; ++e) mx = fmaxf(mx, src[c * EDIM + e]);
    float ex[EDIM]; float s = 0.f;
    for (int e = 0; e < EDIM; ++e) { ex[e] = expf(src[c * EDIM + e] - mx); s += ex[e]; }
    for (int e = 0; e < EDIM; ++e) {
      float r = ex[e] / s;
      sw[m * 10 + c * EDIM + e] = r;
      dout[1 + NTGT * NCLS + m * 10 + c * EDIM + e] = r;
    }
  }
  if (tid < 16) acc[tid] = 0.f;
  for (int i = tid; i < CDIM * NDIM; i += 64) deg[i] = 0.f;
}

__global__ __launch_bounds__(256) void zero_k(float* __restrict__ p, int n) {
  int i = blockIdx.x * 256 + threadIdx.x;
  if (i < n) p[i] = 0.f;
}

// ---------------------------------------------------------------------------
// a (bf16) and b (fp32) from A
// ---------------------------------------------------------------------------
__global__ __launch_bounds__(256) void wsum_ab_k(const float* __restrict__ A,
                                                 const float* __restrict__ sw,
                                                 __hip_bfloat16* __restrict__ a_out,
                                                 float* __restrict__ b_out) {
  size_t idx = (size_t)blockIdx.x * 256 + threadIdx.x;
  float v[EDIM];
#pragma unroll
  for (int e = 0; e < EDIM; ++e) v[e] = A[idx * EDIM + e];
#pragma unroll
  for (int c = 0; c < CDIM; ++c) {
    float sa = 0.f, sb = 0.f;
#pragma unroll
    for (int e = 0; e < EDIM; ++e) {
      sa += sw[c * EDIM + e] * v[e];
      sb += sw[10 + c * EDIM + e] * v[e];
    }
    a_out[c * NN + idx] = __float2bfloat16(sa);
    b_out[c * NN + idx] = sb;
  }
}

__global__ __launch_bounds__(256) void wsum_one_k(const float* __restrict__ A,
                                                  const float* __restrict__ sw,
                                                  float* __restrict__ a_out) {
  size_t idx = (size_t)blockIdx.x * 256 + threadIdx.x;
  float v[EDIM];
#pragma unroll
  for (int e = 0; e < EDIM; ++e) v[e] = A[idx * EDIM + e];
#pragma unroll
  for (int c = 0; c < CDIM; ++c) {
    float sa = 0.f;
#pragma unroll
    for (int e = 0; e < EDIM; ++e) sa += sw[c * EDIM + e] * v[e];
    a_out[c * NN + idx] = sa;
  }
}

// ---------------------------------------------------------------------------
// tiled transpose + fp32 -> bf16 convert: src [R][Cc] -> dst [Cc][R]
// ---------------------------------------------------------------------------
__global__ void tcvt_k(const float* __restrict__ src, __hip_bfloat16* __restrict__ dst,
                       int R, int Cc, size_t sstride, size_t dstride) {
  __shared__ float t[32][33];
  src += blockIdx.z * sstride;
  dst += blockIdx.z * dstride;
  int bx = blockIdx.x * 32;  // col base in src
  int by = blockIdx.y * 32;  // row base in src
  int tx = threadIdx.x, ty = threadIdx.y;
#pragma unroll
  for (int r = 0; r < 32; r += 8)
    t[ty + r][tx] = src[(size_t)(by + ty + r) * Cc + bx + tx];
  __syncthreads();
#pragma unroll
  for (int r = 0; r < 32; r += 8)
    dst[(size_t)(bx + ty + r) * R + by + tx] = __float2bfloat16(t[tx][ty + r]);
}

// ---------------------------------------------------------------------------
// MFMA bf16 GEMM, B^T input: C[M,N] = A[M,K] @ BT[N,K]^T, row strides = K.
// 128x128 tile, BK=32, 256 threads (4 waves 2x2, 64x64 each, 4x4 MFMA tiles).
// blockIdx.z = batch*nsplit + split; nsplit>1 -> atomicAdd into pre-zeroed C.
// ---------------------------------------------------------------------------
__global__ __launch_bounds__(256) void mfma_bt_k(
    const __hip_bfloat16* __restrict__ Ab, const __hip_bfloat16* __restrict__ Bt,
    float* __restrict__ C, int M, int N, int K, int ldc,
    size_t sA, size_t sB, size_t sC, int nsplit) {
  __shared__ __hip_bfloat16 As[128 * 32];
  __shared__ __hip_bfloat16 Bs[128 * 32];
  const int tid = threadIdx.x;
  const int lane = tid & 63;
  const int wave = tid >> 6;
  const int batch = blockIdx.z / nsplit;
  const int split = blockIdx.z - batch * nsplit;
  const __hip_bfloat16* A = Ab + (size_t)batch * sA;
  const __hip_bfloat16* B = Bt + (size_t)batch * sB;
  float* Cp = C + (size_t)batch * sC;
  const int row0 = blockIdx.y * 128;
  const int col0 = blockIdx.x * 128;
  const int kchunk = K / nsplit;
  const int kbeg = split * kchunk;
  const int kend = kbeg + kchunk;

  const int wr = (wave >> 1) * 64;
  const int wc = (wave & 1) * 64;
  const int q = lane >> 4;
  const int r = lane & 15;

  float4v acc[4][4] = {};

  // staging: two 16B chunks per thread for each tile (tile row = 32 bf16 = 64B)
  const int off0 = tid * 16;
  const int off1 = 4096 + tid * 16;
  const int r0 = off0 >> 6, c0 = (off0 & 63) >> 1;
  const int r1 = off1 >> 6, c1 = (off1 & 63) >> 1;
  char* lA = (char*)As + wave * 1024;
  char* lB = (char*)Bs + wave * 1024;

  for (int k0 = kbeg; k0 < kend; k0 += 32) {
    __syncthreads();  // prior iter's ds_reads done before overwrite
    gl2lds16(A + (size_t)(row0 + r0) * K + k0 + c0, lA);
    gl2lds16(A + (size_t)(row0 + r1) * K + k0 + c1, lA + 4096);
    gl2lds16(B + (size_t)(col0 + r0) * K + k0 + c0, lB);
    gl2lds16(B + (size_t)(col0 + r1) * K + k0 + c1, lB + 4096);
    __syncthreads();  // vmcnt(0) drain -> staged data visible

    short8v af[4], bf[4];
#pragma unroll
    for (int i = 0; i < 4; ++i) {
      af[i] = *(const short8v*)((const char*)As + (size_t)(wr + i * 16 + r) * 64 + q * 16);
      bf[i] = *(const short8v*)((const char*)Bs + (size_t)(wc + i * 16 + r) * 64 + q * 16);
    }
#pragma unroll
    for (int i = 0; i < 4; ++i)
#pragma unroll
      for (int j = 0; j < 4; ++j)
        acc[i][j] = __builtin_amdgcn_mfma_f32_16x16x32_bf16(af[i], bf[j], acc[i][j], 0, 0, 0);
  }

#pragma unroll
  for (int i = 0; i < 4; ++i) {
    int row = row0 + wr + i * 16 + q * 4;
#pragma unroll
    for (int j = 0; j < 4; ++j) {
      int col = col0 + wc + j * 16 + r;
#pragma unroll
      for (int e = 0; e < 4; ++e) {
        float v = acc[i][j][e];
        if (nsplit > 1) atomicAdd(&Cp[(size_t)(row + e) * ldc + col], v);
        else Cp[(size_t)(row + e) * ldc + col] = v;
      }
    }
  }
}

// ---------------------------------------------------------------------------
// fp32 GEMM for the small-K tail: C[M,Nn] = A[M,K] @ B[K,Nn], row-major.
// ---------------------------------------------------------------------------
#define TS 64
#define BK 16
__global__ __launch_bounds__(256) void sgemm_k(const float* __restrict__ A,
                                               const float* __restrict__ B,
                                               float* __restrict__ C,
                                               int M, int K, int Nn,
                                               int lda, int ldb, int ldc) {
  __shared__ float As[BK][TS];
  __shared__ float Bs[BK][TS + 4];
  const int tid = threadIdx.x;
  const int brow = blockIdx.y * TS;
  const int bcol = blockIdx.x * TS;
  const int tx = tid & 15;
  const int ty = tid >> 4;
  const int la_r = tid >> 2;
  const int la_k = (tid & 3) << 2;
  const int lb_k = tid >> 4;
  const int lb_c = (tid & 15) << 2;
  float acc[4][4] = {{0.f}};
  for (int k0 = 0; k0 < K; k0 += BK) {
    float4 av = *(const float4*)(A + (size_t)(brow + la_r) * lda + k0 + la_k);
    float4 bv = *(const float4*)(B + (size_t)(k0 + lb_k) * ldb + bcol + lb_c);
    __syncthreads();
    As[la_k + 0][la_r] = av.x;
    As[la_k + 1][la_r] = av.y;
    As[la_k + 2][la_r] = av.z;
    As[la_k + 3][la_r] = av.w;
    *(float4*)&Bs[lb_k][lb_c] = bv;
    __syncthreads();
#pragma unroll
    for (int kk = 0; kk < BK; ++kk) {
      float a0 = As[kk][ty * 4 + 0], a1 = As[kk][ty * 4 + 1];
      float a2 = As[kk][ty * 4 + 2], a3 = As[kk][ty * 4 + 3];
      float b0 = Bs[kk][tx * 4 + 0], b1 = Bs[kk][tx * 4 + 1];
      float b2 = Bs[kk][tx * 4 + 2], b3 = Bs[kk][tx * 4 + 3];
      acc[0][0] += a0 * b0; acc[0][1] += a0 * b1; acc[0][2] += a0 * b2; acc[0][3] += a0 * b3;
      acc[1][0] += a1 * b0; acc[1][1] += a1 * b1; acc[1][2] += a1 * b2; acc[1][3] += a1 * b3;
      acc[2][0] += a2 * b0; acc[2][1] += a2 * b1; acc[2][2] += a2 * b2; acc[2][3] += a2 * b3;
      acc[3][0] += a3 * b0; acc[3][1] += a3 * b1; acc[3][2] += a3 * b2; acc[3][3] += a3 * b3;
    }
  }
#pragma unroll
  for (int i = 0; i < 4; ++i) {
    float4 o;
    o.x = acc[i][0]; o.y = acc[i][1]; o.z = acc[i][2]; o.w = acc[i][3];
    *(float4*)(C + (size_t)(brow + ty * 4 + i) * ldc + bcol + tx * 4) = o;
  }
}

// ---------------------------------------------------------------------------
// column degree (diag excluded) + column scale -> bf16 (norm(H, add=False))
// ---------------------------------------------------------------------------
__global__ __launch_bounds__(256) void col_degree_k(const float* __restrict__ H,
                                                    float* __restrict__ deg) {
  int j = blockIdx.x * 256 + threadIdx.x;
  int i0 = blockIdx.y * 128;
  float s = 0.f;
  for (int i = i0; i < i0 + 128; ++i)
    if (i != j) s += H[(size_t)i * NDIM + j];
  atomicAdd(&deg[j], s);
}

__global__ __launch_bounds__(256) void col_scale_bf_k(const float* __restrict__ H,
                                                      const float* __restrict__ deg,
                                                      __hip_bfloat16* __restrict__ out) {
  size_t idx = (size_t)blockIdx.x * 256 + threadIdx.x;
  int i = (int)(idx >> 11), j = (int)(idx & (NDIM - 1));
  float d = deg[j];
  float inv = (d == 0.f) ? 0.f : 1.f / d;
  float v = (i == j) ? 0.f : H[idx];
  out[idx] = __float2bfloat16(v * inv);
}

__global__ __launch_bounds__(256) void add2_k(const float* __restrict__ A,
                                              const float* __restrict__ B,
                                              float* __restrict__ O) {
  size_t i = (size_t)blockIdx.x * 256 + threadIdx.x;
  O[i] = A[i] + B[i];
}

// ---------------------------------------------------------------------------
// row-normalize fp32 input with diag forced to 1, write bf16
// ---------------------------------------------------------------------------
__global__ __launch_bounds__(256) void rownorm_bf_k(const float* __restrict__ Min,
                                                    __hip_bfloat16* __restrict__ Mout) {
  const int i = blockIdx.x;
  const int tid = threadIdx.x;
  float s = 0.f;
  for (int j = tid; j < NDIM; j += 256) {
    float v = (j == i) ? 1.f : Min[(size_t)i * NDIM + j];
    s += v;
  }
  for (int off = 32; off > 0; off >>= 1) s += __shfl_down(s, off, 64);
  __shared__ float red[4];
  __shared__ float inv_s;
  if ((tid & 63) == 0) red[tid >> 6] = s;
  __syncthreads();
  if (tid == 0) {
    float t = red[0] + red[1] + red[2] + red[3];
    inv_s = (t == 0.f) ? 0.f : 1.f / t;
  }
  __syncthreads();
  float inv = inv_s;
  for (int j = tid; j < NDIM; j += 256) {
    float v = (j == i) ? 1.f : Min[(size_t)i * NDIM + j];
    Mout[(size_t)i * NDIM + j] = __float2bfloat16(v * inv);
  }
}

// Xcat[n][c*128+d] = relu(XcPre[c][n][d])
__global__ __launch_bounds__(256) void relu_merge_k(const float* __restrict__ XcPre,
                                                    float* __restrict__ Xcat) {
  int idx = blockIdx.x * 256 + threadIdx.x;
  int c = idx >> 18;
  int rem = idx & 262143;
  int n = rem >> 7;
  int d = rem & 127;
  Xcat[(size_t)n * 256 + (c << 7) + d] = fmaxf(XcPre[idx], 0.f);
}

// W12[k][0:128]=W1[k][:], W12[k][128:384]=W2[k][:]
__global__ __launch_bounds__(256) void w12_k(const float* __restrict__ W1,
                                             const float* __restrict__ W2,
                                             float* __restrict__ W12) {
  int idx = blockIdx.x * 256 + threadIdx.x;
  int k = idx / 384;
  int j = idx - k * 384;
  W12[idx] = (j < 128) ? W1[k * 128 + j] : W2[k * 256 + (j - 128)];
}

// ---------------------------------------------------------------------------
// BCE loss over Xr (cols 128..384 of XoXr, ld 384) vs X
// ---------------------------------------------------------------------------
__global__ __launch_bounds__(256) void lossR_k(const float* __restrict__ XoXr,
                                               const float* __restrict__ X,
                                               float* __restrict__ acc) {
  size_t i = (size_t)blockIdx.x * 256 + threadIdx.x;
  int n = (int)(i >> 8);
  int d = (int)(i & 255);
  float xr = XoXr[(size_t)n * 384 + 128 + d];
  if (xr > 1.f) xr = 1.f / (1.f + expf(-xr));
  if (xr < 0.f) xr = 1.f / (1.f + expf(-xr));
  float p = fminf(fmaxf(xr, 1e-7f), 1.f - 1e-7f);
  float xv = X[i];
  float t = xv * logf(p) + (1.f - xv) * log1pf(-p);
  for (int off = 32; off > 0; off >>= 1) t += __shfl_down(t, off, 64);
  __shared__ float red[4];
  if ((threadIdx.x & 63) == 0) red[threadIdx.x >> 6] = t;
  __syncthreads();
  if (threadIdx.x == 0) atomicAdd(acc, red[0] + red[1] + red[2] + red[3]);
}

// ---------------------------------------------------------------------------
// y = Xo[target_x] @ lin_w^T + lin_b (Xo = cols 0..128 of XoXr, ld 384)
// ---------------------------------------------------------------------------
__global__ __launch_bounds__(64) void y_loss_k(const float* __restrict__ XoXr,
                                               const float* __restrict__ lin_w,
                                               const float* __restrict__ lin_b,
                                               const int* __restrict__ txs,
                                               const int* __restrict__ tgt,
                                               float* __restrict__ yout,
                                               float* __restrict__ accC) {
  int t = blockIdx.x;
  int lane = threadIdx.x;
  __shared__ float xo[WOUT];
  __shared__ float ys[NCLS];
  int x = txs[t];
  xo[lane] = XoXr[(size_t)x * 384 + lane];
  xo[lane + 64] = XoXr[(size_t)x * 384 + 64 + lane];
  __syncthreads();
  if (lane < NCLS) {
    float s = lin_b[lane];
    for (int d = 0; d < WOUT; ++d) s += xo[d] * lin_w[lane * WOUT + d];
    ys[lane] = s;
    yout[(size_t)t * NCLS + lane] = s;
  }
  __syncthreads();
  if (lane == 0) {
    float m = ys[0];
    for (int k = 1; k < NCLS; ++k) m = fmaxf(m, ys[k]);
    float se = 0.f;
    for (int k = 0; k < NCLS; ++k) se += expf(ys[k] - m);
    float lse = m + logf(se);
    atomicAdd(accC, lse - ys[tgt[t]]);
  }
}

__global__ void finalize_k(const float* __restrict__ acc, float* __restrict__ dout) {
  float lossC = acc[0] / (float)NTGT;
  float lossR = -acc[1] / (float)(NDIM * WIN);
  dout[0] = lossC + lossR;
  dout[1 + NTGT * NCLS + 30] = lossR;
}

// ---------------------------------------------------------------------------
extern "C" void kernel_launch(void* const* d_in, const int* in_sizes, int n_in,
                              void* d_out, int out_size, void* d_ws, size_t ws_size,
                              hipStream_t stream) {
  const float* A    = (const float*)d_in[0];
  const float* X    = (const float*)d_in[1];
  const float* W    = (const float*)d_in[2];
  const float* W1   = (const float*)d_in[3];
  const float* W2   = (const float*)d_in[4];
  const float* linw = (const float*)d_in[5];
  const float* linb = (const float*)d_in[6];
  const float* w0a  = (const float*)d_in[7];
  const float* w0b  = (const float*)d_in[8];
  const float* w1a  = (const float*)d_in[9];
  const int* txs    = (const int*)d_in[10];
  const int* tgt    = (const int*)d_in[11];
  float* dout = (float*)d_out;

  float* ws = (float*)d_ws;
  // region map (float units); bf16 regions hold 2*NN bf16 in NN floats
  __hip_bfloat16* abf  = (__hip_bfloat16*)(ws);            // [0,NN): a bf16 (2ch); later Tsum f32 region
  float* fbig          = ws + NN;                           // [NN,3NN): b -> H -> a1 -> H1T (2*NN f32)
  __hip_bfloat16* bTbf = (__hip_bfloat16*)(ws + 3 * NN);    // [3NN,4NN): bT -> a1T -> Hn2T (bf16 2ch)
  __hip_bfloat16* Hnbf = (__hip_bfloat16*)(ws + 4 * NN);    // [4NN,5NN): Hn (bf16 2ch) -> HsT (bf16 1ch)
  float* Tsum = ws;                                         // reuse [0,NN) after GEMM1
  float* sm   = ws + 5 * NN;
  float* sw    = sm;                 sm += 32;
  float* acc   = sm;                 sm += 16;
  float* deg   = sm;                 sm += CDIM * NDIM;
  float* XW    = sm;                 sm += (size_t)NDIM * WOUT;
  __hip_bfloat16* XWTbf = (__hip_bfloat16*)sm;  sm += (size_t)NDIM * WOUT / 2;
  float* XcPre = sm;                 sm += (size_t)CDIM * NDIM * WOUT;
  float* Xcat  = sm;                 sm += (size_t)NDIM * 2 * WOUT;
  float* W12   = sm;                 sm += (size_t)(2 * WOUT) * 384;
  float* XC12  = sm;                 sm += (size_t)NDIM * 384;
  __hip_bfloat16* XC12Tbf = (__hip_bfloat16*)sm; sm += (size_t)NDIM * 384 / 2;
  float* XoXr  = sm;                 sm += (size_t)NDIM * 384;

  dim3 blk256(256);
  dim3 gridNN((unsigned)(NN / 256));

  // 1. softmaxes + zero acc/deg ; zero split-K outputs
  init_k<<<dim3(1), dim3(64), 0, stream>>>(w0a, w0b, w1a, sw, acc, deg, dout);
  zero_k<<<dim3(CDIM * NDIM * WOUT / 256), blk256, 0, stream>>>(XcPre, CDIM * NDIM * WOUT);
  zero_k<<<dim3(NDIM * 384 / 256), blk256, 0, stream>>>(XoXr, NDIM * 384);
  // 2. a(bf16), b(f32)
  wsum_ab_k<<<gridNN, blk256, 0, stream>>>(A, sw, abf, fbig);
  // 3. bT bf16
  tcvt_k<<<dim3(64, 64, 2), dim3(32, 8), 0, stream>>>(fbig, bTbf, NDIM, NDIM, NN, NN);
  // 4. H[c] = a[c] @ b[c]  (overwrites b region with f32 H)
  mfma_bt_k<<<dim3(16, 16, 2), blk256, 0, stream>>>(abf, bTbf, fbig, NDIM, NDIM, NDIM,
                                                    NDIM, NN, NN, NN, 1);
  // 5. Hn[c] = norm(H[c], False) -> bf16
  for (int c = 0; c < CDIM; ++c) {
    col_degree_k<<<dim3(NDIM / 256, 16), blk256, 0, stream>>>(fbig + c * NN, deg + c * NDIM);
    col_scale_bf_k<<<gridNN, blk256, 0, stream>>>(fbig + c * NN, deg + c * NDIM,
                                                  Hnbf + c * NN);
  }
  // 6. a1 f32 (overwrites H) ; a1T bf16 (overwrites bT)
  wsum_one_k<<<gridNN, blk256, 0, stream>>>(A, sw + 20, fbig);
  tcvt_k<<<dim3(64, 64, 2), dim3(32, 8), 0, stream>>>(fbig, bTbf, NDIM, NDIM, NN, NN);
  // 7. H1T[c] = a1T[c] @ Hn[c]^T  (f32, overwrites a1 region)
  mfma_bt_k<<<dim3(16, 16, 2), blk256, 0, stream>>>(bTbf, Hnbf, fbig, NDIM, NDIM, NDIM,
                                                    NDIM, NN, NN, NN, 1);
  // 8. Tsum = H1T0 + H1T1 (into region 0)
  add2_k<<<gridNN, blk256, 0, stream>>>(fbig, fbig + NN, Tsum);
  // 9. Hn2T[c] bf16 (overwrites a1T) ; HsT bf16 (overwrites Hn)
  rownorm_bf_k<<<dim3(NDIM), blk256, 0, stream>>>(fbig, bTbf);
  rownorm_bf_k<<<dim3(NDIM), blk256, 0, stream>>>(fbig + NN, bTbf + NN);
  rownorm_bf_k<<<dim3(NDIM), blk256, 0, stream>>>(Tsum, Hnbf);
  // 10. XW = X @ W (f32) ; XWT bf16
  sgemm_k<<<dim3(WOUT / TS, NDIM / TS), blk256, 0, stream>>>(X, W, XW, NDIM, WIN, WOUT,
                                                             WIN, WOUT, WOUT);
  tcvt_k<<<dim3(WOUT / 32, NDIM / 32, 1), dim3(32, 8), 0, stream>>>(XW, XWTbf, NDIM, WOUT, 0, 0);
  // 11. XcPre[c] = Hn2T[c] @ XW  (split-K 8, atomic)
  mfma_bt_k<<<dim3(1, 16, 16), blk256, 0, stream>>>(bTbf, XWTbf, XcPre, NDIM, WOUT, NDIM,
                                                    WOUT, NN, 0, (size_t)NDIM * WOUT, 8);
  // 12. Xcat = relu+merge ; W12 ; XC12 = Xcat @ [W1|W2] ; XC12T bf16
  relu_merge_k<<<dim3(CDIM * NDIM * WOUT / 256), blk256, 0, stream>>>(XcPre, Xcat);
  w12_k<<<dim3(2 * WOUT * 384 / 256), blk256, 0, stream>>>(W1, W2, W12);
  sgemm_k<<<dim3(384 / TS, NDIM / TS), blk256, 0, stream>>>(Xcat, W12, XC12, NDIM, 2 * WOUT,
                                                            384, 2 * WOUT, 384, 384);
  tcvt_k<<<dim3(384 / 32, NDIM / 32, 1), dim3(32, 8), 0, stream>>>(XC12, XC12Tbf, NDIM, 384, 0, 0);
  // 13. XoXr = HsT @ XC12  (split-K 8, atomic)
  mfma_bt_k<<<dim3(3, 16, 8), blk256, 0, stream>>>(Hnbf, XC12Tbf, XoXr, NDIM, 384, NDIM,
                                                   384, 0, 0, 0, 8);
  // 14. losses + y
  lossR_k<<<dim3((unsigned)(NDIM * WIN / 256)), blk256, 0, stream>>>(XoXr, X, acc + 1);
  y_loss_k<<<dim3(NTGT), dim3(64), 0, stream>>>(XoXr, linw, linb, txs, tgt, dout + 1, acc);
  finalize_k<<<dim3(1), dim3(1), 0, stream>>>(acc, dout);
}

// Round 3
// 456.606 us; speedup vs baseline: 4.3783x; 1.2612x over previous
//
#include <hip/hip_runtime.h>
#include <hip/hip_bf16.h>
#include <math.h>

#define NDIM 2048
#define EDIM 5
#define CDIM 2
#define WIN 256
#define WOUT 128
#define NCLS 8
#define NTGT 1024
#define NN ((size_t)NDIM * NDIM)

typedef __attribute__((ext_vector_type(8))) short short8v;
typedef __attribute__((ext_vector_type(4))) float float4v;

__device__ __forceinline__ void gl2lds16(const void* g, void* l) {
  __builtin_amdgcn_global_load_lds((__attribute__((address_space(1))) const unsigned int*)g,
                                   (__attribute__((address_space(3))) unsigned int*)l, 16, 0, 0);
}

// ---------------------------------------------------------------------------
// init: softmax of the three [C,E] weight mats, zero accumulators + degrees
// ---------------------------------------------------------------------------
__global__ void init_k(const float* __restrict__ w0a, const float* __restrict__ w0b,
                       const float* __restrict__ w1a,
                       float* __restrict__ sw, float* __restrict__ acc,
                       float* __restrict__ deg, float* __restrict__ dout) {
  int tid = threadIdx.x;  // 64
  if (tid < 6) {
    int m = tid >> 1, c = tid & 1;
    const float* src = (m == 0) ? w0a : (m == 1) ? w0b : w1a;
    float mx = -1e30f;
    for (int e = 0; e < EDIM; ++e) mx = fmaxf(mx, src[c * EDIM + e]);
    float ex[EDIM]; float s = 0.f;
    for (int e = 0; e < EDIM; ++e) { ex[e] = expf(src[c * EDIM + e] - mx); s += ex[e]; }
    for (int e = 0; e < EDIM; ++e) {
      float r = ex[e] / s;
      sw[m * 10 + c * EDIM + e] = r;
      dout[1 + NTGT * NCLS + m * 10 + c * EDIM + e] = r;
    }
  }
  if (tid < 16) acc[tid] = 0.f;
  for (int i = tid; i < CDIM * NDIM; i += 64) deg[i] = 0.f;
}

// zero XcPre + XoXr (atomic split-K outputs) and build W12 = [W1|W2] rows
__global__ __launch_bounds__(256) void prep_tail_k(const float* __restrict__ W1,
                                                   const float* __restrict__ W2,
                                                   float* __restrict__ XcPre,
                                                   float* __restrict__ XoXr,
                                                   float* __restrict__ W12) {
  int idx = blockIdx.x * 256 + threadIdx.x;
  const int nXc = CDIM * NDIM * WOUT;   // 524288
  const int nXo = NDIM * 384;           // 786432
  if (idx < nXc) { XcPre[idx] = 0.f; return; }
  idx -= nXc;
  if (idx < nXo) { XoXr[idx] = 0.f; return; }
  idx -= nXo;
  if (idx < 2 * WOUT * 384) {
    int k = idx / 384, j = idx - k * 384;
    W12[idx] = (j < 128) ? W1[k * 128 + j] : W2[k * 256 + (j - 128)];
  }
}

// ---------------------------------------------------------------------------
// one pass over A: a bf16 (row-major) + bT bf16 (transposed via LDS tile)
// ---------------------------------------------------------------------------
__global__ void wsum_abt_k(const float* __restrict__ A, const float* __restrict__ sw,
                           __hip_bfloat16* __restrict__ a_out,
                           __hip_bfloat16* __restrict__ bT) {
  __shared__ float tb[CDIM][32][33];
  int bx = blockIdx.x * 32, by = blockIdx.y * 32;
  int tx = threadIdx.x, ty = threadIdx.y;
#pragma unroll
  for (int rr = 0; rr < 32; rr += 8) {
    int n = by + ty + rr, m = bx + tx;
    size_t base = ((size_t)n * NDIM + m) * EDIM;
    float v0 = A[base], v1 = A[base + 1], v2 = A[base + 2], v3 = A[base + 3], v4 = A[base + 4];
#pragma unroll
    for (int c = 0; c < CDIM; ++c) {
      float sa = sw[c*5]*v0 + sw[c*5+1]*v1 + sw[c*5+2]*v2 + sw[c*5+3]*v3 + sw[c*5+4]*v4;
      float sb = sw[10+c*5]*v0 + sw[10+c*5+1]*v1 + sw[10+c*5+2]*v2 + sw[10+c*5+3]*v3 + sw[10+c*5+4]*v4;
      a_out[c * NN + (size_t)n * NDIM + m] = __float2bfloat16(sa);
      tb[c][ty + rr][tx] = sb;
    }
  }
  __syncthreads();
#pragma unroll
  for (int rr = 0; rr < 32; rr += 8) {
    int mm = bx + ty + rr, nn2 = by + tx;
#pragma unroll
    for (int c = 0; c < CDIM; ++c)
      bT[c * NN + (size_t)mm * NDIM + nn2] = __float2bfloat16(tb[c][tx][ty + rr]);
  }
}

// same but transposed-only output (a1T), coefficients at swp[c*5+e]
__global__ void wsum_onet_k(const float* __restrict__ A, const float* __restrict__ swp,
                            __hip_bfloat16* __restrict__ aT) {
  __shared__ float tb[CDIM][32][33];
  int bx = blockIdx.x * 32, by = blockIdx.y * 32;
  int tx = threadIdx.x, ty = threadIdx.y;
#pragma unroll
  for (int rr = 0; rr < 32; rr += 8) {
    int n = by + ty + rr, m = bx + tx;
    size_t base = ((size_t)n * NDIM + m) * EDIM;
    float v0 = A[base], v1 = A[base + 1], v2 = A[base + 2], v3 = A[base + 3], v4 = A[base + 4];
#pragma unroll
    for (int c = 0; c < CDIM; ++c)
      tb[c][ty + rr][tx] = swp[c*5]*v0 + swp[c*5+1]*v1 + swp[c*5+2]*v2 + swp[c*5+3]*v3 + swp[c*5+4]*v4;
  }
  __syncthreads();
#pragma unroll
  for (int rr = 0; rr < 32; rr += 8) {
    int mm = bx + ty + rr, nn2 = by + tx;
#pragma unroll
    for (int c = 0; c < CDIM; ++c)
      aT[c * NN + (size_t)mm * NDIM + nn2] = __float2bfloat16(tb[c][tx][ty + rr]);
  }
}

// ---------------------------------------------------------------------------
// small tcvt: fp32 [R][Cc] -> bf16 [Cc][R]
// ---------------------------------------------------------------------------
__global__ void tcvt_k(const float* __restrict__ src, __hip_bfloat16* __restrict__ dst,
                       int R, int Cc) {
  __shared__ float t[32][33];
  int bx = blockIdx.x * 32;
  int by = blockIdx.y * 32;
  int tx = threadIdx.x, ty = threadIdx.y;
#pragma unroll
  for (int r = 0; r < 32; r += 8)
    t[ty + r][tx] = src[(size_t)(by + ty + r) * Cc + bx + tx];
  __syncthreads();
#pragma unroll
  for (int r = 0; r < 32; r += 8)
    dst[(size_t)(bx + ty + r) * R + by + tx] = __float2bfloat16(t[tx][ty + r]);
}

// ---------------------------------------------------------------------------
// MFMA bf16 GEMM, B^T input: C[M,N] = A[M,K] @ BT[N,K]^T.
// obf16: C is bf16 (plain store). else f32 (atomic if nsplit>1).
// cs != nullptr: atomicAdd per-column sums of C tile into cs[batch*NDIM + col].
// ---------------------------------------------------------------------------
__global__ __launch_bounds__(256) void mfma_bt_k(
    const __hip_bfloat16* __restrict__ Ab, const __hip_bfloat16* __restrict__ Bt,
    void* __restrict__ Cv, int M, int N, int K, int ldc,
    size_t sA, size_t sB, size_t sC, int nsplit, int obf16,
    float* __restrict__ cs) {
  __shared__ __hip_bfloat16 As[128 * 32];
  __shared__ __hip_bfloat16 Bs[128 * 32];
  const int tid = threadIdx.x;
  const int lane = tid & 63;
  const int wave = tid >> 6;
  const int batch = blockIdx.z / nsplit;
  const int split = blockIdx.z - batch * nsplit;
  const __hip_bfloat16* A = Ab + (size_t)batch * sA;
  const __hip_bfloat16* B = Bt + (size_t)batch * sB;
  const int row0 = blockIdx.y * 128;
  const int col0 = blockIdx.x * 128;
  const int kchunk = K / nsplit;
  const int kbeg = split * kchunk;
  const int kend = kbeg + kchunk;

  const int wr = (wave >> 1) * 64;
  const int wc = (wave & 1) * 64;
  const int q = lane >> 4;
  const int r = lane & 15;

  float4v acc[4][4] = {};

  const int off0 = tid * 16;
  const int off1 = 4096 + tid * 16;
  const int r0 = off0 >> 6, c0 = (off0 & 63) >> 1;
  const int r1 = off1 >> 6, c1 = (off1 & 63) >> 1;
  char* lA = (char*)As + wave * 1024;
  char* lB = (char*)Bs + wave * 1024;

  for (int k0 = kbeg; k0 < kend; k0 += 32) {
    __syncthreads();
    gl2lds16(A + (size_t)(row0 + r0) * K + k0 + c0, lA);
    gl2lds16(A + (size_t)(row0 + r1) * K + k0 + c1, lA + 4096);
    gl2lds16(B + (size_t)(col0 + r0) * K + k0 + c0, lB);
    gl2lds16(B + (size_t)(col0 + r1) * K + k0 + c1, lB + 4096);
    __syncthreads();

    short8v af[4], bf[4];
#pragma unroll
    for (int i = 0; i < 4; ++i) {
      af[i] = *(const short8v*)((const char*)As + (size_t)(wr + i * 16 + r) * 64 + q * 16);
      bf[i] = *(const short8v*)((const char*)Bs + (size_t)(wc + i * 16 + r) * 64 + q * 16);
    }
#pragma unroll
    for (int i = 0; i < 4; ++i)
#pragma unroll
      for (int j = 0; j < 4; ++j)
        acc[i][j] = __builtin_amdgcn_mfma_f32_16x16x32_bf16(af[i], bf[j], acc[i][j], 0, 0, 0);
  }

  if (obf16) {
    __hip_bfloat16* Cp = (__hip_bfloat16*)Cv + (size_t)batch * sC;
#pragma unroll
    for (int i = 0; i < 4; ++i) {
      int row = row0 + wr + i * 16 + q * 4;
#pragma unroll
      for (int j = 0; j < 4; ++j) {
        int col = col0 + wc + j * 16 + r;
#pragma unroll
        for (int e = 0; e < 4; ++e)
          Cp[(size_t)(row + e) * ldc + col] = __float2bfloat16(acc[i][j][e]);
      }
    }
  } else {
    float* Cp = (float*)Cv + (size_t)batch * sC;
#pragma unroll
    for (int i = 0; i < 4; ++i) {
      int row = row0 + wr + i * 16 + q * 4;
#pragma unroll
      for (int j = 0; j < 4; ++j) {
        int col = col0 + wc + j * 16 + r;
#pragma unroll
        for (int e = 0; e < 4; ++e) {
          float v = acc[i][j][e];
          if (nsplit > 1) atomicAdd(&Cp[(size_t)(row + e) * ldc + col], v);
          else Cp[(size_t)(row + e) * ldc + col] = v;
        }
      }
    }
  }

  if (cs) {  // column sums of this block's tile (incl diag; fixed up later)
    float* csp = cs + (size_t)batch * NDIM;
#pragma unroll
    for (int j = 0; j < 4; ++j) {
      float s = 0.f;
#pragma unroll
      for (int i = 0; i < 4; ++i)
#pragma unroll
        for (int e = 0; e < 4; ++e) s += acc[i][j][e];
      s += __shfl_xor(s, 16, 64);
      s += __shfl_xor(s, 32, 64);
      if (lane < 16) atomicAdd(&csp[col0 + wc + j * 16 + r], s);
    }
  }
}

// ---------------------------------------------------------------------------
// fp32 GEMM for the small-K tail: C[M,Nn] = A[M,K] @ B[K,Nn], row-major.
// ---------------------------------------------------------------------------
#define TS 64
#define BK 16
__global__ __launch_bounds__(256) void sgemm_k(const float* __restrict__ A,
                                               const float* __restrict__ B,
                                               float* __restrict__ C,
                                               int M, int K, int Nn,
                                               int lda, int ldb, int ldc) {
  __shared__ float As[BK][TS];
  __shared__ float Bs[BK][TS + 4];
  const int tid = threadIdx.x;
  const int brow = blockIdx.y * TS;
  const int bcol = blockIdx.x * TS;
  const int tx = tid & 15;
  const int ty = tid >> 4;
  const int la_r = tid >> 2;
  const int la_k = (tid & 3) << 2;
  const int lb_k = tid >> 4;
  const int lb_c = (tid & 15) << 2;
  float acc[4][4] = {{0.f}};
  for (int k0 = 0; k0 < K; k0 += BK) {
    float4 av = *(const float4*)(A + (size_t)(brow + la_r) * lda + k0 + la_k);
    float4 bv = *(const float4*)(B + (size_t)(k0 + lb_k) * ldb + bcol + lb_c);
    __syncthreads();
    As[la_k + 0][la_r] = av.x;
    As[la_k + 1][la_r] = av.y;
    As[la_k + 2][la_r] = av.z;
    As[la_k + 3][la_r] = av.w;
    *(float4*)&Bs[lb_k][lb_c] = bv;
    __syncthreads();
#pragma unroll
    for (int kk = 0; kk < BK; ++kk) {
      float a0 = As[kk][ty * 4 + 0], a1 = As[kk][ty * 4 + 1];
      float a2 = As[kk][ty * 4 + 2], a3 = As[kk][ty * 4 + 3];
      float b0 = Bs[kk][tx * 4 + 0], b1 = Bs[kk][tx * 4 + 1];
      float b2 = Bs[kk][tx * 4 + 2], b3 = Bs[kk][tx * 4 + 3];
      acc[0][0] += a0 * b0; acc[0][1] += a0 * b1; acc[0][2] += a0 * b2; acc[0][3] += a0 * b3;
      acc[1][0] += a1 * b0; acc[1][1] += a1 * b1; acc[1][2] += a1 * b2; acc[1][3] += a1 * b3;
      acc[2][0] += a2 * b0; acc[2][1] += a2 * b1; acc[2][2] += a2 * b2; acc[2][3] += a2 * b3;
      acc[3][0] += a3 * b0; acc[3][1] += a3 * b1; acc[3][2] += a3 * b2; acc[3][3] += a3 * b3;
    }
  }
#pragma unroll
  for (int i = 0; i < 4; ++i) {
    float4 o;
    o.x = acc[i][0]; o.y = acc[i][1]; o.z = acc[i][2]; o.w = acc[i][3];
    *(float4*)(C + (size_t)(brow + ty * 4 + i) * ldc + bcol + tx * 4) = o;
  }
}

// deg[c][j] -= H_bf16[c][j][j]   (exclude diagonal from column sums)
__global__ void diag_fix_k(const __hip_bfloat16* __restrict__ H, float* __restrict__ deg) {
  int idx = blockIdx.x * 256 + threadIdx.x;  // 4096
  int c = idx >> 11, j = idx & (NDIM - 1);
  deg[idx] -= __bfloat162float(H[(size_t)c * NN + (size_t)j * NDIM + j]);
  (void)c;
}

// Hn = norm(H, add=False): zero diag, scale column j by 1/deg[j]; bf16 in/out
__global__ __launch_bounds__(256) void col_scale_bf_k(const __hip_bfloat16* __restrict__ H,
                                                      const float* __restrict__ deg,
                                                      __hip_bfloat16* __restrict__ out) {
  size_t idx = (size_t)blockIdx.x * 256 + threadIdx.x;  // over 2*NN
  int j = (int)(idx & (NDIM - 1));
  int i = (int)((idx >> 11) & (NDIM - 1));
  int c = (int)(idx >> 22);
  float d = deg[c * NDIM + j];
  float inv = (d == 0.f) ? 0.f : 1.f / d;
  float v = (i == j) ? 0.f : __bfloat162float(H[idx]);
  out[idx] = __float2bfloat16(v * inv);
}

// ---------------------------------------------------------------------------
// one pass over H1T (both channels, bf16): row-norm (diag->1) for ch0, ch1,
// and their sum. Writes Hn2T[0], Hn2T[1], HsT (all bf16).
// ---------------------------------------------------------------------------
__global__ __launch_bounds__(256) void rowmega_k(const __hip_bfloat16* __restrict__ H1T,
                                                 __hip_bfloat16* __restrict__ Hn2T,
                                                 __hip_bfloat16* __restrict__ HsT) {
  const int m = blockIdx.x;
  const int tid = threadIdx.x;
  const __hip_bfloat16* r0p = H1T + (size_t)m * NDIM;
  const __hip_bfloat16* r1p = H1T + NN + (size_t)m * NDIM;
  float v0[8], v1[8];
  float s0 = 0.f, s1 = 0.f;
#pragma unroll
  for (int t = 0; t < 8; ++t) {
    int col = t * 256 + tid;
    v0[t] = __bfloat162float(r0p[col]);
    v1[t] = __bfloat162float(r1p[col]);
    s0 += v0[t]; s1 += v1[t];
  }
  __shared__ float ds[2];
  __shared__ float red[2][4];
  __shared__ float bc[3];
  if (tid == (m & 255)) { ds[0] = v0[m >> 8]; ds[1] = v1[m >> 8]; }
  for (int off = 32; off > 0; off >>= 1) {
    s0 += __shfl_down(s0, off, 64);
    s1 += __shfl_down(s1, off, 64);
  }
  if ((tid & 63) == 0) { red[0][tid >> 6] = s0; red[1][tid >> 6] = s1; }
  __syncthreads();
  if (tid == 0) {
    float t0 = red[0][0] + red[0][1] + red[0][2] + red[0][3];
    float t1 = red[1][0] + red[1][1] + red[1][2] + red[1][3];
    float r0 = t0 - ds[0] + 1.f;
    float r1 = t1 - ds[1] + 1.f;
    float rs = t0 + t1 - ds[0] - ds[1] + 1.f;
    bc[0] = (r0 == 0.f) ? 0.f : 1.f / r0;
    bc[1] = (r1 == 0.f) ? 0.f : 1.f / r1;
    bc[2] = (rs == 0.f) ? 0.f : 1.f / rs;
  }
  __syncthreads();
  float i0 = bc[0], i1 = bc[1], is = bc[2];
#pragma unroll
  for (int t = 0; t < 8; ++t) {
    int col = t * 256 + tid;
    bool dg = (col == m);
    Hn2T[(size_t)m * NDIM + col] = __float2bfloat16((dg ? 1.f : v0[t]) * i0);
    Hn2T[NN + (size_t)m * NDIM + col] = __float2bfloat16((dg ? 1.f : v1[t]) * i1);
    HsT[(size_t)m * NDIM + col] = __float2bfloat16((dg ? 1.f : (v0[t] + v1[t])) * is);
  }
}

// Xcat[n][c*128+d] = relu(XcPre[c][n][d])
__global__ __launch_bounds__(256) void relu_merge_k(const float* __restrict__ XcPre,
                                                    float* __restrict__ Xcat) {
  int idx = blockIdx.x * 256 + threadIdx.x;
  int c = idx >> 18;
  int rem = idx & 262143;
  int n = rem >> 7;
  int d = rem & 127;
  Xcat[(size_t)n * 256 + (c << 7) + d] = fmaxf(XcPre[idx], 0.f);
}

// ---------------------------------------------------------------------------
// BCE loss over Xr (cols 128..384 of XoXr, ld 384) vs X
// ---------------------------------------------------------------------------
__global__ __launch_bounds__(256) void lossR_k(const float* __restrict__ XoXr,
                                               const float* __restrict__ X,
                                               float* __restrict__ acc) {
  size_t i = (size_t)blockIdx.x * 256 + threadIdx.x;
  int n = (int)(i >> 8);
  int d = (int)(i & 255);
  float xr = XoXr[(size_t)n * 384 + 128 + d];
  if (xr > 1.f) xr = 1.f / (1.f + expf(-xr));
  if (xr < 0.f) xr = 1.f / (1.f + expf(-xr));
  float p = fminf(fmaxf(xr, 1e-7f), 1.f - 1e-7f);
  float xv = X[i];
  float t = xv * logf(p) + (1.f - xv) * log1pf(-p);
  for (int off = 32; off > 0; off >>= 1) t += __shfl_down(t, off, 64);
  __shared__ float red[4];
  if ((threadIdx.x & 63) == 0) red[threadIdx.x >> 6] = t;
  __syncthreads();
  if (threadIdx.x == 0) atomicAdd(acc, red[0] + red[1] + red[2] + red[3]);
}

// ---------------------------------------------------------------------------
// y = Xo[target_x] @ lin_w^T + lin_b (Xo = cols 0..128 of XoXr, ld 384)
// ---------------------------------------------------------------------------
__global__ __launch_bounds__(64) void y_loss_k(const float* __restrict__ XoXr,
                                               const float* __restrict__ lin_w,
                                               const float* __restrict__ lin_b,
                                               const int* __restrict__ txs,
                                               const int* __restrict__ tgt,
                                               float* __restrict__ yout,
                                               float* __restrict__ accC) {
  int t = blockIdx.x;
  int lane = threadIdx.x;
  __shared__ float xo[WOUT];
  __shared__ float ys[NCLS];
  int x = txs[t];
  xo[lane] = XoXr[(size_t)x * 384 + lane];
  xo[lane + 64] = XoXr[(size_t)x * 384 + 64 + lane];
  __syncthreads();
  if (lane < NCLS) {
    float s = lin_b[lane];
    for (int d = 0; d < WOUT; ++d) s += xo[d] * lin_w[lane * WOUT + d];
    ys[lane] = s;
    yout[(size_t)t * NCLS + lane] = s;
  }
  __syncthreads();
  if (lane == 0) {
    float m = ys[0];
    for (int k = 1; k < NCLS; ++k) m = fmaxf(m, ys[k]);
    float se = 0.f;
    for (int k = 0; k < NCLS; ++k) se += expf(ys[k] - m);
    float lse = m + logf(se);
    atomicAdd(accC, lse - ys[tgt[t]]);
  }
}

__global__ void finalize_k(const float* __restrict__ acc, float* __restrict__ dout) {
  float lossC = acc[0] / (float)NTGT;
  float lossR = -acc[1] / (float)(NDIM * WIN);
  dout[0] = lossC + lossR;
  dout[1 + NTGT * NCLS + 30] = lossR;
}

// ---------------------------------------------------------------------------
extern "C" void kernel_launch(void* const* d_in, const int* in_sizes, int n_in,
                              void* d_out, int out_size, void* d_ws, size_t ws_size,
                              hipStream_t stream) {
  const float* A    = (const float*)d_in[0];
  const float* X    = (const float*)d_in[1];
  const float* W    = (const float*)d_in[2];
  const float* W1   = (const float*)d_in[3];
  const float* W2   = (const float*)d_in[4];
  const float* linw = (const float*)d_in[5];
  const float* linb = (const float*)d_in[6];
  const float* w0a  = (const float*)d_in[7];
  const float* w0b  = (const float*)d_in[8];
  const float* w1a  = (const float*)d_in[9];
  const int* txs    = (const int*)d_in[10];
  const int* tgt    = (const int*)d_in[11];
  float* dout = (float*)d_out;

  float* ws = (float*)d_ws;
  // regions (float units); each NN-float region holds 2*NN bf16
  __hip_bfloat16* R0 = (__hip_bfloat16*)(ws);           // a -> a1T -> HsT
  __hip_bfloat16* R1 = (__hip_bfloat16*)(ws + NN);      // bT -> H1T
  __hip_bfloat16* R2 = (__hip_bfloat16*)(ws + 2 * NN);  // H -> Hn2T
  __hip_bfloat16* R3 = (__hip_bfloat16*)(ws + 3 * NN);  // Hn
  float* sm   = ws + 4 * NN;
  float* sw    = sm;                 sm += 32;
  float* acc   = sm;                 sm += 16;
  float* deg   = sm;                 sm += CDIM * NDIM;
  float* XW    = sm;                 sm += (size_t)NDIM * WOUT;
  __hip_bfloat16* XWTbf = (__hip_bfloat16*)sm;  sm += (size_t)NDIM * WOUT / 2;
  float* XcPre = sm;                 sm += (size_t)CDIM * NDIM * WOUT;
  float* Xcat  = sm;                 sm += (size_t)NDIM * 2 * WOUT;
  float* W12   = sm;                 sm += (size_t)(2 * WOUT) * 384;
  float* XC12  = sm;                 sm += (size_t)NDIM * 384;
  __hip_bfloat16* XC12Tbf = (__hip_bfloat16*)sm; sm += (size_t)NDIM * 384 / 2;
  float* XoXr  = sm;                 sm += (size_t)NDIM * 384;

  dim3 blk256(256);

  // 1. softmaxes + zero acc/deg; zero split-K outputs + W12
  init_k<<<dim3(1), dim3(64), 0, stream>>>(w0a, w0b, w1a, sw, acc, deg, dout);
  prep_tail_k<<<dim3((CDIM*NDIM*WOUT + NDIM*384 + 2*WOUT*384 + 255)/256), blk256, 0, stream>>>(
      W1, W2, XcPre, XoXr, W12);
  // 2. a (R0), bT (R1)
  wsum_abt_k<<<dim3(64, 64), dim3(32, 8), 0, stream>>>(A, sw, R0, R1);
  // 3. H[c] = a[c] @ b[c] -> bf16 R2, with column sums into deg
  mfma_bt_k<<<dim3(16, 16, 2), blk256, 0, stream>>>(R0, R1, R2, NDIM, NDIM, NDIM,
                                                    NDIM, NN, NN, NN, 1, 1, deg);
  // 4. deg -= diag(H); Hn = colscale(H) -> R3
  diag_fix_k<<<dim3(CDIM * NDIM / 256), blk256, 0, stream>>>(R2, deg);
  col_scale_bf_k<<<dim3((unsigned)(2 * NN / 256)), blk256, 0, stream>>>(R2, deg, R3);
  // 5. a1T -> R0
  wsum_onet_k<<<dim3(64, 64), dim3(32, 8), 0, stream>>>(A, sw + 20, R0);
  // 6. H1T[c] = a1T[c] @ Hn[c]^T -> bf16 R1
  mfma_bt_k<<<dim3(16, 16, 2), blk256, 0, stream>>>(R0, R3, R1, NDIM, NDIM, NDIM,
                                                    NDIM, NN, NN, NN, 1, 1, nullptr);
  // 7. row norms: Hn2T -> R2 (2ch), HsT -> R0
  rowmega_k<<<dim3(NDIM), blk256, 0, stream>>>(R1, R2, R0);
  // 8. XW = X @ W (f32); XWT bf16
  sgemm_k<<<dim3(WOUT / TS, NDIM / TS), blk256, 0, stream>>>(X, W, XW, NDIM, WIN, WOUT,
                                                             WIN, WOUT, WOUT);
  tcvt_k<<<dim3(WOUT / 32, NDIM / 32), dim3(32, 8), 0, stream>>>(XW, XWTbf, NDIM, WOUT);
  // 9. XcPre[c] = Hn2T[c] @ XW (split-K 8, atomic f32)
  mfma_bt_k<<<dim3(1, 16, 16), blk256, 0, stream>>>(R2, XWTbf, XcPre, NDIM, WOUT, NDIM,
                                                    WOUT, NN, 0, (size_t)NDIM * WOUT, 8, 0, nullptr);
  // 10. Xcat = relu+merge; XC12 = Xcat @ [W1|W2]; XC12T bf16
  relu_merge_k<<<dim3(CDIM * NDIM * WOUT / 256), blk256, 0, stream>>>(XcPre, Xcat);
  sgemm_k<<<dim3(384 / TS, NDIM / TS), blk256, 0, stream>>>(Xcat, W12, XC12, NDIM, 2 * WOUT,
                                                            384, 2 * WOUT, 384, 384);
  tcvt_k<<<dim3(384 / 32, NDIM / 32), dim3(32, 8), 0, stream>>>(XC12, XC12Tbf, NDIM, 384);
  // 11. XoXr = HsT @ XC12 (split-K 8, atomic f32)
  mfma_bt_k<<<dim3(3, 16, 8), blk256, 0, stream>>>(R0, XC12Tbf, XoXr, NDIM, 384, NDIM,
                                                   384, 0, 0, 0, 8, 0, nullptr);
  // 12. losses + y
  lossR_k<<<dim3((unsigned)(NDIM * WIN / 256)), blk256, 0, stream>>>(XoXr, X, acc + 1);
  y_loss_k<<<dim3(NTGT), dim3(64), 0, stream>>>(XoXr, linw, linb, txs, tgt, dout + 1, acc);
  finalize_k<<<dim3(1), dim3(1), 0, stream>>>(acc, dout);
}

// Round 4
// 446.055 us; speedup vs baseline: 4.4819x; 1.0237x over previous
//
#include <hip/hip_runtime.h>
#include <hip/hip_bf16.h>
#include <math.h>

#define NDIM 2048
#define EDIM 5
#define CDIM 2
#define WIN 256
#define WOUT 128
#define NCLS 8
#define NTGT 1024
#define NN ((size_t)NDIM * NDIM)

typedef __attribute__((ext_vector_type(8))) short short8v;
typedef __attribute__((ext_vector_type(4))) float float4v;

__device__ __forceinline__ void gl2lds16(const void* g, void* l) {
  __builtin_amdgcn_global_load_lds((__attribute__((address_space(1))) const unsigned int*)g,
                                   (__attribute__((address_space(3))) unsigned int*)l, 16, 0, 0);
}
__device__ __forceinline__ float bf2f(unsigned short u) {
  return __uint_as_float(((unsigned)u) << 16);
}
__device__ __forceinline__ unsigned short f2bf(float f) {
  __hip_bfloat16 h = __float2bfloat16(f);
  return *(unsigned short*)&h;
}

// ---------------------------------------------------------------------------
// init: softmax of the three [C,E] weight mats, zero accumulators + degrees
// ---------------------------------------------------------------------------
__global__ void init_k(const float* __restrict__ w0a, const float* __restrict__ w0b,
                       const float* __restrict__ w1a,
                       float* __restrict__ sw, float* __restrict__ acc,
                       float* __restrict__ deg, float* __restrict__ dout) {
  int tid = threadIdx.x;  // 64
  if (tid < 6) {
    int m = tid >> 1, c = tid & 1;
    const float* src = (m == 0) ? w0a : (m == 1) ? w0b : w1a;
    float mx = -1e30f;
    for (int e = 0; e < EDIM; ++e) mx = fmaxf(mx, src[c * EDIM + e]);
    float ex[EDIM]; float s = 0.f;
    for (int e = 0; e < EDIM; ++e) { ex[e] = expf(src[c * EDIM + e] - mx); s += ex[e]; }
    for (int e = 0; e < EDIM; ++e) {
      float r = ex[e] / s;
      sw[m * 10 + c * EDIM + e] = r;
      dout[1 + NTGT * NCLS + m * 10 + c * EDIM + e] = r;
    }
  }
  if (tid < 16) acc[tid] = 0.f;
  for (int i = tid; i < CDIM * NDIM; i += 64) deg[i] = 0.f;
}

// zero XcPre + XoXr (atomic split-K outputs) and build W12 = [W1|W2] rows
__global__ __launch_bounds__(256) void prep_tail_k(const float* __restrict__ W1,
                                                   const float* __restrict__ W2,
                                                   float* __restrict__ XcPre,
                                                   float* __restrict__ XoXr,
                                                   float* __restrict__ W12) {
  int idx = blockIdx.x * 256 + threadIdx.x;
  const int nXc = CDIM * NDIM * WOUT;
  const int nXo = NDIM * 384;
  if (idx < nXc) { XcPre[idx] = 0.f; return; }
  idx -= nXc;
  if (idx < nXo) { XoXr[idx] = 0.f; return; }
  idx -= nXo;
  if (idx < 2 * WOUT * 384) {
    int k = idx / 384, j = idx - k * 384;
    W12[idx] = (j < 128) ? W1[k * 128 + j] : W2[k * 256 + (j - 128)];
  }
}

// ---------------------------------------------------------------------------
// ONE pass over A: a bf16 (row-major), bT bf16 (transposed), a1T bf16 (transposed)
// ---------------------------------------------------------------------------
__global__ void wsum_all_k(const float* __restrict__ A, const float* __restrict__ sw,
                           __hip_bfloat16* __restrict__ a_out,
                           __hip_bfloat16* __restrict__ bT,
                           __hip_bfloat16* __restrict__ a1T) {
  __shared__ float tb[CDIM][32][33];
  __shared__ float tc[CDIM][32][33];
  int bx = blockIdx.x * 32, by = blockIdx.y * 32;
  int tx = threadIdx.x, ty = threadIdx.y;
#pragma unroll
  for (int rr = 0; rr < 32; rr += 8) {
    int n = by + ty + rr, m = bx + tx;
    size_t base = ((size_t)n * NDIM + m) * EDIM;
    float v0 = A[base], v1 = A[base + 1], v2 = A[base + 2], v3 = A[base + 3], v4 = A[base + 4];
#pragma unroll
    for (int c = 0; c < CDIM; ++c) {
      float sa = sw[c*5]*v0 + sw[c*5+1]*v1 + sw[c*5+2]*v2 + sw[c*5+3]*v3 + sw[c*5+4]*v4;
      float sb = sw[10+c*5]*v0 + sw[10+c*5+1]*v1 + sw[10+c*5+2]*v2 + sw[10+c*5+3]*v3 + sw[10+c*5+4]*v4;
      float sc = sw[20+c*5]*v0 + sw[20+c*5+1]*v1 + sw[20+c*5+2]*v2 + sw[20+c*5+3]*v3 + sw[20+c*5+4]*v4;
      a_out[c * NN + (size_t)n * NDIM + m] = __float2bfloat16(sa);
      tb[c][ty + rr][tx] = sb;
      tc[c][ty + rr][tx] = sc;
    }
  }
  __syncthreads();
#pragma unroll
  for (int rr = 0; rr < 32; rr += 8) {
    int mm = bx + ty + rr, nn2 = by + tx;
#pragma unroll
    for (int c = 0; c < CDIM; ++c) {
      bT[c * NN + (size_t)mm * NDIM + nn2] = __float2bfloat16(tb[c][tx][ty + rr]);
      a1T[c * NN + (size_t)mm * NDIM + nn2] = __float2bfloat16(tc[c][tx][ty + rr]);
    }
  }
}

// ---------------------------------------------------------------------------
// MFMA bf16 GEMM, B^T input: C[M,N] = A[M,K] @ BT[N,K]^T.
// z = batch*nsplit+split. obf16: bf16 store at base + batch*sC + split*sSplit
// (bf16 elem offsets). else: f32 out + batch*sC, atomicAdd when nsplit>1.
// cs: atomicAdd per-column f32 sums into cs[batch*NDIM+col].
// ---------------------------------------------------------------------------
__global__ __launch_bounds__(256) void mfma_bt_k(
    const __hip_bfloat16* __restrict__ Ab, const __hip_bfloat16* __restrict__ Bt,
    void* __restrict__ Cv, int K, int ldc,
    size_t sA, size_t sB, size_t sC, size_t sSplit, int nsplit, int obf16,
    float* __restrict__ cs) {
  __shared__ __hip_bfloat16 As[128 * 32];
  __shared__ __hip_bfloat16 Bs[128 * 32];
  const int tid = threadIdx.x;
  const int lane = tid & 63;
  const int wave = tid >> 6;
  const int batch = blockIdx.z / nsplit;
  const int split = blockIdx.z - batch * nsplit;
  const __hip_bfloat16* A = Ab + (size_t)batch * sA;
  const __hip_bfloat16* B = Bt + (size_t)batch * sB;
  const int row0 = blockIdx.y * 128;
  const int col0 = blockIdx.x * 128;
  const int kchunk = K / nsplit;
  const int kbeg = split * kchunk;
  const int kend = kbeg + kchunk;

  const int wr = (wave >> 1) * 64;
  const int wc = (wave & 1) * 64;
  const int q = lane >> 4;
  const int r = lane & 15;

  float4v acc[4][4] = {};

  const int off0 = tid * 16;
  const int off1 = 4096 + tid * 16;
  const int r0 = off0 >> 6, c0 = (off0 & 63) >> 1;
  const int r1 = off1 >> 6, c1 = (off1 & 63) >> 1;
  char* lA = (char*)As + wave * 1024;
  char* lB = (char*)Bs + wave * 1024;

  for (int k0 = kbeg; k0 < kend; k0 += 32) {
    __syncthreads();
    gl2lds16(A + (size_t)(row0 + r0) * K + k0 + c0, lA);
    gl2lds16(A + (size_t)(row0 + r1) * K + k0 + c1, lA + 4096);
    gl2lds16(B + (size_t)(col0 + r0) * K + k0 + c0, lB);
    gl2lds16(B + (size_t)(col0 + r1) * K + k0 + c1, lB + 4096);
    __syncthreads();

    short8v af[4], bf[4];
#pragma unroll
    for (int i = 0; i < 4; ++i) {
      af[i] = *(const short8v*)((const char*)As + (size_t)(wr + i * 16 + r) * 64 + q * 16);
      bf[i] = *(const short8v*)((const char*)Bs + (size_t)(wc + i * 16 + r) * 64 + q * 16);
    }
#pragma unroll
    for (int i = 0; i < 4; ++i)
#pragma unroll
      for (int j = 0; j < 4; ++j)
        acc[i][j] = __builtin_amdgcn_mfma_f32_16x16x32_bf16(af[i], bf[j], acc[i][j], 0, 0, 0);
  }

  if (obf16) {
    __hip_bfloat16* Cp = (__hip_bfloat16*)Cv + (size_t)batch * sC + (size_t)split * sSplit;
#pragma unroll
    for (int i = 0; i < 4; ++i) {
      int row = row0 + wr + i * 16 + q * 4;
#pragma unroll
      for (int j = 0; j < 4; ++j) {
        int col = col0 + wc + j * 16 + r;
#pragma unroll
        for (int e = 0; e < 4; ++e)
          Cp[(size_t)(row + e) * ldc + col] = __float2bfloat16(acc[i][j][e]);
      }
    }
  } else {
    float* Cp = (float*)Cv + (size_t)batch * sC;
#pragma unroll
    for (int i = 0; i < 4; ++i) {
      int row = row0 + wr + i * 16 + q * 4;
#pragma unroll
      for (int j = 0; j < 4; ++j) {
        int col = col0 + wc + j * 16 + r;
#pragma unroll
        for (int e = 0; e < 4; ++e) {
          float v = acc[i][j][e];
          if (nsplit > 1) atomicAdd(&Cp[(size_t)(row + e) * ldc + col], v);
          else Cp[(size_t)(row + e) * ldc + col] = v;
        }
      }
    }
  }

  if (cs) {
    float* csp = cs + (size_t)batch * NDIM;
#pragma unroll
    for (int j = 0; j < 4; ++j) {
      float s = 0.f;
#pragma unroll
      for (int i = 0; i < 4; ++i)
#pragma unroll
        for (int e = 0; e < 4; ++e) s += acc[i][j][e];
      s += __shfl_xor(s, 16, 64);
      s += __shfl_xor(s, 32, 64);
      if (lane < 16) atomicAdd(&csp[col0 + wc + j * 16 + r], s);
    }
  }
}

// ---------------------------------------------------------------------------
// deg -> inv-degree: deginv[c][j] = 1/(deg[c][j] - diag(P0+P1)), 0 if zero
// ---------------------------------------------------------------------------
__global__ void diag_fix_k(const __hip_bfloat16* __restrict__ P0,
                           const __hip_bfloat16* __restrict__ P1,
                           float* __restrict__ deg) {
  int idx = blockIdx.x * 256 + threadIdx.x;  // 4096
  int c = idx >> 11, j = idx & (NDIM - 1);
  size_t dpos = (size_t)c * NN + (size_t)j * NDIM + j;
  float d = deg[idx] - bf2f(*(const unsigned short*)(P0 + dpos))
                     - bf2f(*(const unsigned short*)(P1 + dpos));
  deg[idx] = (d == 0.f) ? 0.f : 1.f / d;
}

// ---------------------------------------------------------------------------
// Hn = norm(H, add=False) from split partials: (P0+P1), zero diag, col scale.
// 8 contiguous elements per thread (16B loads/stores).
// ---------------------------------------------------------------------------
__global__ __launch_bounds__(256) void col_scale_k(const __hip_bfloat16* __restrict__ P0,
                                                   const __hip_bfloat16* __restrict__ P1,
                                                   const float* __restrict__ deginv,
                                                   __hip_bfloat16* __restrict__ out) {
  size_t base = ((size_t)blockIdx.x * 256 + threadIdx.x) * 8;  // over 2*NN
  int c = (int)(base >> 22);
  int i = (int)((base >> 11) & (NDIM - 1));
  int j0 = (int)(base & (NDIM - 1));
  union { short8v v; unsigned short u[8]; } p0, p1, o;
  p0.v = *(const short8v*)(P0 + base);
  p1.v = *(const short8v*)(P1 + base);
#pragma unroll
  for (int t = 0; t < 8; ++t) {
    int j = j0 + t;
    float v = (i == j) ? 0.f : (bf2f(p0.u[t]) + bf2f(p1.u[t]));
    o.u[t] = f2bf(v * deginv[c * NDIM + j]);
  }
  *(short8v*)(out + base) = o.v;
}

// ---------------------------------------------------------------------------
// row norms from H1T split partials (Q0,Q1; each 2ch): writes Hn2T[0],
// Hn2T[1] and HsT (all bf16). One block per row m; 8 elems/thread.
// ---------------------------------------------------------------------------
__global__ __launch_bounds__(256) void rowmega_k(const __hip_bfloat16* __restrict__ Q0,
                                                 const __hip_bfloat16* __restrict__ Q1,
                                                 __hip_bfloat16* __restrict__ Hn2T,
                                                 __hip_bfloat16* __restrict__ HsT) {
  const int m = blockIdx.x;
  const int tid = threadIdx.x;
  const size_t rb = (size_t)m * NDIM + tid * 8;
  union { short8v v; unsigned short u[8]; } a0, b0, a1, b1;
  a0.v = *(const short8v*)(Q0 + rb);        // ch0 split0
  b0.v = *(const short8v*)(Q1 + rb);        // ch0 split1
  a1.v = *(const short8v*)(Q0 + NN + rb);   // ch1 split0
  b1.v = *(const short8v*)(Q1 + NN + rb);   // ch1 split1
  float v0[8], v1[8];
  float s0 = 0.f, s1 = 0.f;
#pragma unroll
  for (int t = 0; t < 8; ++t) {
    v0[t] = bf2f(a0.u[t]) + bf2f(b0.u[t]);
    v1[t] = bf2f(a1.u[t]) + bf2f(b1.u[t]);
    s0 += v0[t]; s1 += v1[t];
  }
  __shared__ float ds[2];
  __shared__ float red[2][4];
  __shared__ float bc[3];
  if (tid == (m >> 3)) { ds[0] = v0[m & 7]; ds[1] = v1[m & 7]; }
  for (int off = 32; off > 0; off >>= 1) {
    s0 += __shfl_down(s0, off, 64);
    s1 += __shfl_down(s1, off, 64);
  }
  if ((tid & 63) == 0) { red[0][tid >> 6] = s0; red[1][tid >> 6] = s1; }
  __syncthreads();
  if (tid == 0) {
    float t0 = red[0][0] + red[0][1] + red[0][2] + red[0][3];
    float t1 = red[1][0] + red[1][1] + red[1][2] + red[1][3];
    float r0 = t0 - ds[0] + 1.f;
    float r1 = t1 - ds[1] + 1.f;
    float rs = t0 + t1 - ds[0] - ds[1] + 1.f;
    bc[0] = (r0 == 0.f) ? 0.f : 1.f / r0;
    bc[1] = (r1 == 0.f) ? 0.f : 1.f / r1;
    bc[2] = (rs == 0.f) ? 0.f : 1.f / rs;
  }
  __syncthreads();
  float i0 = bc[0], i1 = bc[1], is = bc[2];
  union { short8v v; unsigned short u[8]; } o0, o1, os;
#pragma unroll
  for (int t = 0; t < 8; ++t) {
    bool dg = (tid * 8 + t == m);
    o0.u[t] = f2bf((dg ? 1.f : v0[t]) * i0);
    o1.u[t] = f2bf((dg ? 1.f : v1[t]) * i1);
    os.u[t] = f2bf((dg ? 1.f : (v0[t] + v1[t])) * is);
  }
  *(short8v*)(Hn2T + rb) = o0.v;
  *(short8v*)(Hn2T + NN + rb) = o1.v;
  *(short8v*)(HsT + rb) = os.v;
}

// ---------------------------------------------------------------------------
// fp32 GEMM (small K), epilogue stores TRANSPOSED bf16: Dt[N][M], ldt=M.
// ---------------------------------------------------------------------------
#define TS 64
#define BK 16
__global__ __launch_bounds__(256) void sgemm_tb_k(const float* __restrict__ A,
                                                  const float* __restrict__ B,
                                                  __hip_bfloat16* __restrict__ Dt,
                                                  int K, int lda, int ldb, int ldt) {
  __shared__ float As[BK][TS];
  __shared__ float Bs[BK][TS + 4];
  const int tid = threadIdx.x;
  const int brow = blockIdx.y * TS;
  const int bcol = blockIdx.x * TS;
  const int tx = tid & 15;
  const int ty = tid >> 4;
  const int la_r = tid >> 2;
  const int la_k = (tid & 3) << 2;
  const int lb_k = tid >> 4;
  const int lb_c = (tid & 15) << 2;
  float acc[4][4] = {{0.f}};
  for (int k0 = 0; k0 < K; k0 += BK) {
    float4 av = *(const float4*)(A + (size_t)(brow + la_r) * lda + k0 + la_k);
    float4 bv = *(const float4*)(B + (size_t)(k0 + lb_k) * ldb + bcol + lb_c);
    __syncthreads();
    As[la_k + 0][la_r] = av.x;
    As[la_k + 1][la_r] = av.y;
    As[la_k + 2][la_r] = av.z;
    As[la_k + 3][la_r] = av.w;
    *(float4*)&Bs[lb_k][lb_c] = bv;
    __syncthreads();
#pragma unroll
    for (int kk = 0; kk < BK; ++kk) {
      float a0 = As[kk][ty * 4 + 0], a1 = As[kk][ty * 4 + 1];
      float a2 = As[kk][ty * 4 + 2], a3 = As[kk][ty * 4 + 3];
      float b0 = Bs[kk][tx * 4 + 0], b1 = Bs[kk][tx * 4 + 1];
      float b2 = Bs[kk][tx * 4 + 2], b3 = Bs[kk][tx * 4 + 3];
      acc[0][0] += a0 * b0; acc[0][1] += a0 * b1; acc[0][2] += a0 * b2; acc[0][3] += a0 * b3;
      acc[1][0] += a1 * b0; acc[1][1] += a1 * b1; acc[1][2] += a1 * b2; acc[1][3] += a1 * b3;
      acc[2][0] += a2 * b0; acc[2][1] += a2 * b1; acc[2][2] += a2 * b2; acc[2][3] += a2 * b3;
      acc[3][0] += a3 * b0; acc[3][1] += a3 * b1; acc[3][2] += a3 * b2; acc[3][3] += a3 * b3;
    }
  }
#pragma unroll
  for (int i = 0; i < 4; ++i)
#pragma unroll
    for (int j = 0; j < 4; ++j)
      Dt[(size_t)(bcol + tx * 4 + j) * ldt + brow + ty * 4 + i] = __float2bfloat16(acc[i][j]);
}

// Xcat[n][c*128+d] = relu(XcPre[c][n][d])
__global__ __launch_bounds__(256) void relu_merge_k(const float* __restrict__ XcPre,
                                                    float* __restrict__ Xcat) {
  int idx = blockIdx.x * 256 + threadIdx.x;
  int c = idx >> 18;
  int rem = idx & 262143;
  int n = rem >> 7;
  int d = rem & 127;
  Xcat[(size_t)n * 256 + (c << 7) + d] = fmaxf(XcPre[idx], 0.f);
}

// ---------------------------------------------------------------------------
// BCE loss over Xr (cols 128..384 of XoXr, ld 384) vs X
// ---------------------------------------------------------------------------
__global__ __launch_bounds__(256) void lossR_k(const float* __restrict__ XoXr,
                                               const float* __restrict__ X,
                                               float* __restrict__ acc) {
  size_t i = (size_t)blockIdx.x * 256 + threadIdx.x;
  int n = (int)(i >> 8);
  int d = (int)(i & 255);
  float xr = XoXr[(size_t)n * 384 + 128 + d];
  if (xr > 1.f) xr = 1.f / (1.f + expf(-xr));
  if (xr < 0.f) xr = 1.f / (1.f + expf(-xr));
  float p = fminf(fmaxf(xr, 1e-7f), 1.f - 1e-7f);
  float xv = X[i];
  float t = xv * logf(p) + (1.f - xv) * log1pf(-p);
  for (int off = 32; off > 0; off >>= 1) t += __shfl_down(t, off, 64);
  __shared__ float red[4];
  if ((threadIdx.x & 63) == 0) red[threadIdx.x >> 6] = t;
  __syncthreads();
  if (threadIdx.x == 0) atomicAdd(acc, red[0] + red[1] + red[2] + red[3]);
}

// ---------------------------------------------------------------------------
// y = Xo[target_x] @ lin_w^T + lin_b (Xo = cols 0..128 of XoXr, ld 384)
// ---------------------------------------------------------------------------
__global__ __launch_bounds__(64) void y_loss_k(const float* __restrict__ XoXr,
                                               const float* __restrict__ lin_w,
                                               const float* __restrict__ lin_b,
                                               const int* __restrict__ txs,
                                               const int* __restrict__ tgt,
                                               float* __restrict__ yout,
                                               float* __restrict__ accC) {
  int t = blockIdx.x;
  int lane = threadIdx.x;
  __shared__ float xo[WOUT];
  __shared__ float ys[NCLS];
  int x = txs[t];
  xo[lane] = XoXr[(size_t)x * 384 + lane];
  xo[lane + 64] = XoXr[(size_t)x * 384 + 64 + lane];
  __syncthreads();
  if (lane < NCLS) {
    float s = lin_b[lane];
    for (int d = 0; d < WOUT; ++d) s += xo[d] * lin_w[lane * WOUT + d];
    ys[lane] = s;
    yout[(size_t)t * NCLS + lane] = s;
  }
  __syncthreads();
  if (lane == 0) {
    float m = ys[0];
    for (int k = 1; k < NCLS; ++k) m = fmaxf(m, ys[k]);
    float se = 0.f;
    for (int k = 0; k < NCLS; ++k) se += expf(ys[k] - m);
    float lse = m + logf(se);
    atomicAdd(accC, lse - ys[tgt[t]]);
  }
}

__global__ void finalize_k(const float* __restrict__ acc, float* __restrict__ dout) {
  float lossC = acc[0] / (float)NTGT;
  float lossR = -acc[1] / (float)(NDIM * WIN);
  dout[0] = lossC + lossR;
  dout[1 + NTGT * NCLS + 30] = lossR;
}

// ---------------------------------------------------------------------------
extern "C" void kernel_launch(void* const* d_in, const int* in_sizes, int n_in,
                              void* d_out, int out_size, void* d_ws, size_t ws_size,
                              hipStream_t stream) {
  const float* A    = (const float*)d_in[0];
  const float* X    = (const float*)d_in[1];
  const float* W    = (const float*)d_in[2];
  const float* W1   = (const float*)d_in[3];
  const float* W2   = (const float*)d_in[4];
  const float* linw = (const float*)d_in[5];
  const float* linb = (const float*)d_in[6];
  const float* w0a  = (const float*)d_in[7];
  const float* w0b  = (const float*)d_in[8];
  const float* w1a  = (const float*)d_in[9];
  const int* txs    = (const int*)d_in[10];
  const int* tgt    = (const int*)d_in[11];
  float* dout = (float*)d_out;

  float* ws = (float*)d_ws;
  // 5 big regions, NN floats each (each holds 2ch x NN bf16):
  // RA: a -> Hn -> HsT ; RB: bT -> Q0 ; RC: a1T -> Hn2T ; RD: P0 -> Q1 ; RE: P1
  __hip_bfloat16* RA = (__hip_bfloat16*)(ws);
  __hip_bfloat16* RB = (__hip_bfloat16*)(ws + NN);
  __hip_bfloat16* RC = (__hip_bfloat16*)(ws + 2 * NN);
  __hip_bfloat16* RD = (__hip_bfloat16*)(ws + 3 * NN);
  __hip_bfloat16* RE = (__hip_bfloat16*)(ws + 4 * NN);
  float* sm   = ws + 5 * NN;
  float* sw    = sm;                 sm += 32;
  float* acc   = sm;                 sm += 16;
  float* deg   = sm;                 sm += CDIM * NDIM;
  __hip_bfloat16* XWT = (__hip_bfloat16*)sm;    sm += (size_t)NDIM * WOUT / 2;
  float* XcPre = sm;                 sm += (size_t)CDIM * NDIM * WOUT;
  float* Xcat  = sm;                 sm += (size_t)NDIM * 2 * WOUT;
  float* W12   = sm;                 sm += (size_t)(2 * WOUT) * 384;
  __hip_bfloat16* XC12T = (__hip_bfloat16*)sm;  sm += (size_t)NDIM * 384 / 2;
  float* XoXr  = sm;                 sm += (size_t)NDIM * 384;

  dim3 blk256(256);

  // 1. softmaxes + zero acc/deg; zero split-K tail outputs + W12
  init_k<<<dim3(1), dim3(64), 0, stream>>>(w0a, w0b, w1a, sw, acc, deg, dout);
  prep_tail_k<<<dim3((CDIM*NDIM*WOUT + NDIM*384 + 2*WOUT*384 + 255)/256), blk256, 0, stream>>>(
      W1, W2, XcPre, XoXr, W12);
  // 2. one pass over A: a(RA), bT(RB), a1T(RC)
  wsum_all_k<<<dim3(64, 64), dim3(32, 8), 0, stream>>>(A, sw, RA, RB, RC);
  // 3. H partials: P0(RD), P1(RE) bf16; column sums into deg. splitK=2, 1024 blocks
  mfma_bt_k<<<dim3(16, 16, 4), blk256, 0, stream>>>(RA, RB, RD, NDIM, NDIM,
                                                    NN, NN, NN, 2 * NN, 2, 1, deg);
  // 4. deg -> inv(deg - diag); Hn = colscale(P0+P1) -> RA
  diag_fix_k<<<dim3(CDIM * NDIM / 256), blk256, 0, stream>>>(RD, RE, deg);
  col_scale_k<<<dim3((unsigned)(2 * NN / 2048)), blk256, 0, stream>>>(RD, RE, deg, RA);
  // 5. H1T partials: Q0(RB), Q1(RD). H1T[c] = a1T[c] @ Hn[c]^T. splitK=2
  mfma_bt_k<<<dim3(16, 16, 4), blk256, 0, stream>>>(RC, RA, RB, NDIM, NDIM,
                                                    NN, NN, NN, 4 * NN, 2, 1, nullptr);
  // 6. row norms: Hn2T -> RC (2ch), HsT -> RA
  rowmega_k<<<dim3(NDIM), blk256, 0, stream>>>(RB, RD, RC, RA);
  // 7. XWT = (X @ W)^T bf16
  sgemm_tb_k<<<dim3(WOUT / TS, NDIM / TS), blk256, 0, stream>>>(X, W, XWT, WIN,
                                                                WIN, WOUT, NDIM);
  // 8. XcPre[c] = Hn2T[c] @ XW (split-K 8, atomic f32)
  mfma_bt_k<<<dim3(1, 16, 16), blk256, 0, stream>>>(RC, XWT, XcPre, NDIM, WOUT,
                                                    NN, 0, (size_t)NDIM * WOUT, 0, 8, 0, nullptr);
  // 9. Xcat = relu+merge; XC12T = (Xcat @ [W1|W2])^T bf16
  relu_merge_k<<<dim3(CDIM * NDIM * WOUT / 256), blk256, 0, stream>>>(XcPre, Xcat);
  sgemm_tb_k<<<dim3(384 / TS, NDIM / TS), blk256, 0, stream>>>(Xcat, W12, XC12T, 2 * WOUT,
                                                               2 * WOUT, 384, NDIM);
  // 10. XoXr = HsT @ XC12 (split-K 8, atomic f32)
  mfma_bt_k<<<dim3(3, 16, 8), blk256, 0, stream>>>(RA, XC12T, XoXr, NDIM, 384,
                                                   0, 0, 0, 0, 8, 0, nullptr);
  // 11. losses + y
  lossR_k<<<dim3((unsigned)(NDIM * WIN / 256)), blk256, 0, stream>>>(XoXr, X, acc + 1);
  y_loss_k<<<dim3(NTGT), dim3(64), 0, stream>>>(XoXr, linw, linb, txs, tgt, dout + 1, acc);
  finalize_k<<<dim3(1), dim3(1), 0, stream>>>(acc, dout);
}

// Round 5
// 387.958 us; speedup vs baseline: 5.1531x; 1.1497x over previous
//
#include <hip/hip_runtime.h>
#include <hip/hip_bf16.h>
#include <math.h>

#define NDIM 2048
#define EDIM 5
#define CDIM 2
#define WIN 256
#define WOUT 128
#define NCLS 8
#define NTGT 1024
#define NN ((size_t)NDIM * NDIM)

typedef __attribute__((ext_vector_type(8))) short short8v;
typedef __attribute__((ext_vector_type(4))) float float4v;

__device__ __forceinline__ void gl2lds16(const void* g, void* l) {
  __builtin_amdgcn_global_load_lds((__attribute__((address_space(1))) const unsigned int*)g,
                                   (__attribute__((address_space(3))) unsigned int*)l, 16, 0, 0);
}
__device__ __forceinline__ float bf2f(unsigned short u) {
  return __uint_as_float(((unsigned)u) << 16);
}
__device__ __forceinline__ unsigned short f2bf(float f) {
  __hip_bfloat16 h = __float2bfloat16(f);
  return *(unsigned short*)&h;
}

// ---------------------------------------------------------------------------
// mega setup kernel. blocks < 4096: one 32x32 tile of A -> a, bT, a1T (bf16,
// softmax coefs computed in-block). blocks >= 4096: zero XcPre/XoXr/deg/acc,
// build W12, compute Ws softmax outputs into dout.
// ---------------------------------------------------------------------------
#define N_XC (CDIM * NDIM * WOUT)
#define N_XO (NDIM * 384)
#define N_W12 (2 * WOUT * 384)
#define N_PREP (N_XC + N_XO + N_W12 + CDIM * NDIM + 16 + 30)
__global__ __launch_bounds__(256) void wsum_mega_k(
    const float* __restrict__ A, const float* __restrict__ w0a,
    const float* __restrict__ w0b, const float* __restrict__ w1a,
    __hip_bfloat16* __restrict__ a_out, __hip_bfloat16* __restrict__ bT,
    __hip_bfloat16* __restrict__ a1T,
    float* __restrict__ acc, float* __restrict__ deg,
    float* __restrict__ XcPre, float* __restrict__ XoXr, float* __restrict__ W12,
    const float* __restrict__ W1, const float* __restrict__ W2,
    float* __restrict__ dout) {
  const int b = blockIdx.x;
  const int tid = threadIdx.x;
  if (b >= 4096) {
    int idx = (b - 4096) * 256 + tid;
    if (idx < N_XC) { XcPre[idx] = 0.f; return; }
    idx -= N_XC;
    if (idx < N_XO) { XoXr[idx] = 0.f; return; }
    idx -= N_XO;
    if (idx < N_W12) {
      int k = idx / 384, j = idx - k * 384;
      W12[idx] = (j < 128) ? W1[k * 128 + j] : W2[k * 256 + (j - 128)];
      return;
    }
    idx -= N_W12;
    if (idx < CDIM * NDIM) { deg[idx] = 0.f; return; }
    idx -= CDIM * NDIM;
    if (idx < 16) { acc[idx] = 0.f; return; }
    idx -= 16;
    if (idx < 30) {
      int m = idx / 10, rr = idx - m * 10, c = rr / 5, e = rr - c * 5;
      const float* src = (m == 0) ? w0a : (m == 1) ? w0b : w1a;
      float mx = -1e30f;
      for (int t = 0; t < 5; ++t) mx = fmaxf(mx, src[c * 5 + t]);
      float s = 0.f, ve = 0.f;
      for (int t = 0; t < 5; ++t) {
        float ex = expf(src[c * 5 + t] - mx);
        s += ex;
        if (t == e) ve = ex;
      }
      dout[1 + NTGT * NCLS + idx] = ve / s;
    }
    return;
  }
  // tile work
  __shared__ float swl[32];
  __shared__ float tb[CDIM][32][33];
  __shared__ float tc[CDIM][32][33];
  if (tid < 6) {
    int m = tid >> 1, c = tid & 1;
    const float* src = (m == 0) ? w0a : (m == 1) ? w0b : w1a;
    float mx = -1e30f;
    for (int e = 0; e < 5; ++e) mx = fmaxf(mx, src[c * 5 + e]);
    float ex[5]; float s = 0.f;
    for (int e = 0; e < 5; ++e) { ex[e] = expf(src[c * 5 + e] - mx); s += ex[e]; }
    for (int e = 0; e < 5; ++e) swl[m * 10 + c * 5 + e] = ex[e] / s;
  }
  __syncthreads();
  const int bx = (b & 63) * 32, by = (b >> 6) * 32;
  const int tx = tid & 31, ty = tid >> 5;
#pragma unroll
  for (int rr = 0; rr < 32; rr += 8) {
    int n = by + ty + rr, m = bx + tx;
    size_t base = ((size_t)n * NDIM + m) * EDIM;
    float v0 = A[base], v1 = A[base + 1], v2 = A[base + 2], v3 = A[base + 3], v4 = A[base + 4];
#pragma unroll
    for (int c = 0; c < CDIM; ++c) {
      float sa = swl[c*5]*v0 + swl[c*5+1]*v1 + swl[c*5+2]*v2 + swl[c*5+3]*v3 + swl[c*5+4]*v4;
      float sb = swl[10+c*5]*v0 + swl[10+c*5+1]*v1 + swl[10+c*5+2]*v2 + swl[10+c*5+3]*v3 + swl[10+c*5+4]*v4;
      float sc = swl[20+c*5]*v0 + swl[20+c*5+1]*v1 + swl[20+c*5+2]*v2 + swl[20+c*5+3]*v3 + swl[20+c*5+4]*v4;
      a_out[c * NN + (size_t)n * NDIM + m] = __float2bfloat16(sa);
      tb[c][ty + rr][tx] = sb;
      tc[c][ty + rr][tx] = sc;
    }
  }
  __syncthreads();
#pragma unroll
  for (int rr = 0; rr < 32; rr += 8) {
    int mm = bx + ty + rr, nn2 = by + tx;
#pragma unroll
    for (int c = 0; c < CDIM; ++c) {
      bT[c * NN + (size_t)mm * NDIM + nn2] = __float2bfloat16(tb[c][tx][ty + rr]);
      a1T[c * NN + (size_t)mm * NDIM + nn2] = __float2bfloat16(tc[c][tx][ty + rr]);
    }
  }
}

// ---------------------------------------------------------------------------
// MFMA bf16 GEMM, B^T input: C[M,N] = A[M,K] @ BT[N,K]^T. BK=64, 128x128 tile.
// LDS rows are 128 B (8 x 16 B granules), XOR-swizzled by (row & 7) to kill
// bank conflicts; the swizzle is applied on the global gather side since
// global_load_lds scatters lanes linearly (wave-uniform base + lane*16).
// obf16: store bf16 at batch*sC. else f32 (+atomicAdd when nsplit>1).
// cs: per-column sums EXCLUDING the diagonal -> cs[batch*NDIM + col].
// ---------------------------------------------------------------------------
__global__ __launch_bounds__(256) void mfma_bt_k(
    const __hip_bfloat16* __restrict__ Ab, const __hip_bfloat16* __restrict__ Bt,
    void* __restrict__ Cv, int K, int ldc,
    size_t sA, size_t sB, size_t sC, int nsplit, int obf16,
    float* __restrict__ cs) {
  __shared__ __hip_bfloat16 As[128 * 64];
  __shared__ __hip_bfloat16 Bs[128 * 64];
  const int tid = threadIdx.x;
  const int lane = tid & 63;
  const int wave = tid >> 6;
  const int batch = blockIdx.z / nsplit;
  const int split = blockIdx.z - batch * nsplit;
  const __hip_bfloat16* A = Ab + (size_t)batch * sA;
  const __hip_bfloat16* B = Bt + (size_t)batch * sB;
  const int row0 = blockIdx.y * 128;
  const int col0 = blockIdx.x * 128;
  const int kchunk = K / nsplit;
  const int kbeg = split * kchunk;
  const int kend = kbeg + kchunk;

  const int wr = (wave >> 1) * 64;
  const int wc = (wave & 1) * 64;
  const int q = lane >> 4;
  const int r = lane & 15;

  float4v acc[4][4] = {};

  // staging: lane l of wave w at call-site s covers row s*32+w*8+(l>>3),
  // global granule (l&7)^((l>>3)&7)  (16 B granules, 8 bf16 each)
  const int srow = lane >> 3;
  const int scol = ((lane & 7) ^ (srow & 7)) * 8;  // bf16 elems
  // frag reads: row = wr/wc + i*16 + r; granule (h*4+q)^(r&7)
  const int fsw = r & 7;

  for (int k0 = kbeg; k0 < kend; k0 += 64) {
    __syncthreads();
#pragma unroll
    for (int s = 0; s < 4; ++s) {
      gl2lds16(A + (size_t)(row0 + s * 32 + wave * 8 + srow) * K + k0 + scol,
               (char*)As + s * 4096 + wave * 1024);
      gl2lds16(B + (size_t)(col0 + s * 32 + wave * 8 + srow) * K + k0 + scol,
               (char*)Bs + s * 4096 + wave * 1024);
    }
    __syncthreads();
#pragma unroll
    for (int h = 0; h < 2; ++h) {
      short8v af[4], bf[4];
#pragma unroll
      for (int i = 0; i < 4; ++i) {
        af[i] = *(const short8v*)((const char*)As + (size_t)(wr + i * 16 + r) * 128 +
                                  (((h * 4 + q) ^ fsw) * 16));
        bf[i] = *(const short8v*)((const char*)Bs + (size_t)(wc + i * 16 + r) * 128 +
                                  (((h * 4 + q) ^ fsw) * 16));
      }
#pragma unroll
      for (int i = 0; i < 4; ++i)
#pragma unroll
        for (int j = 0; j < 4; ++j)
          acc[i][j] = __builtin_amdgcn_mfma_f32_16x16x32_bf16(af[i], bf[j], acc[i][j], 0, 0, 0);
    }
  }

  if (obf16) {
    __hip_bfloat16* Cp = (__hip_bfloat16*)Cv + (size_t)batch * sC;
#pragma unroll
    for (int i = 0; i < 4; ++i) {
      int row = row0 + wr + i * 16 + q * 4;
#pragma unroll
      for (int j = 0; j < 4; ++j) {
        int col = col0 + wc + j * 16 + r;
#pragma unroll
        for (int e = 0; e < 4; ++e)
          Cp[(size_t)(row + e) * ldc + col] = __float2bfloat16(acc[i][j][e]);
      }
    }
  } else {
    float* Cp = (float*)Cv + (size_t)batch * sC;
#pragma unroll
    for (int i = 0; i < 4; ++i) {
      int row = row0 + wr + i * 16 + q * 4;
#pragma unroll
      for (int j = 0; j < 4; ++j) {
        int col = col0 + wc + j * 16 + r;
#pragma unroll
        for (int e = 0; e < 4; ++e) {
          float v = acc[i][j][e];
          if (nsplit > 1) atomicAdd(&Cp[(size_t)(row + e) * ldc + col], v);
          else Cp[(size_t)(row + e) * ldc + col] = v;
        }
      }
    }
  }

  if (cs) {  // column sums excluding the diagonal element
    float* csp = cs + (size_t)batch * NDIM;
#pragma unroll
    for (int j = 0; j < 4; ++j) {
      int col = col0 + wc + j * 16 + r;
      float s = 0.f;
#pragma unroll
      for (int i = 0; i < 4; ++i) {
        int rowb = row0 + wr + i * 16 + q * 4;
#pragma unroll
        for (int e = 0; e < 4; ++e)
          if (rowb + e != col) s += acc[i][j][e];
      }
      s += __shfl_xor(s, 16, 64);
      s += __shfl_xor(s, 32, 64);
      if (lane < 16) atomicAdd(&csp[col], s);
    }
  }
}

// ---------------------------------------------------------------------------
// Hn = norm(H, add=False): zero diag, col j scaled by 1/deg[j] (deg excludes
// diag already). bf16 in/out, 8 elems/thread.
// ---------------------------------------------------------------------------
__global__ __launch_bounds__(256) void col_scale_k(const __hip_bfloat16* __restrict__ H,
                                                   const float* __restrict__ deg,
                                                   __hip_bfloat16* __restrict__ out) {
  size_t base = ((size_t)blockIdx.x * 256 + threadIdx.x) * 8;  // over 2*NN
  int c = (int)(base >> 22);
  int i = (int)((base >> 11) & (NDIM - 1));
  int j0 = (int)(base & (NDIM - 1));
  union { short8v v; unsigned short u[8]; } p, o;
  p.v = *(const short8v*)(H + base);
#pragma unroll
  for (int t = 0; t < 8; ++t) {
    int j = j0 + t;
    float d = deg[c * NDIM + j];
    float inv = (d == 0.f) ? 0.f : 1.f / d;
    float v = (i == j) ? 0.f : bf2f(p.u[t]);
    o.u[t] = f2bf(v * inv);
  }
  *(short8v*)(out + base) = o.v;
}

// ---------------------------------------------------------------------------
// row norms over H1T (2ch bf16): Hn2T[0], Hn2T[1], HsT (diag forced to 1).
// ---------------------------------------------------------------------------
__global__ __launch_bounds__(256) void rowmega_k(const __hip_bfloat16* __restrict__ H1T,
                                                 __hip_bfloat16* __restrict__ Hn2T,
                                                 __hip_bfloat16* __restrict__ HsT) {
  const int m = blockIdx.x;
  const int tid = threadIdx.x;
  const size_t rb = (size_t)m * NDIM + tid * 8;
  union { short8v v; unsigned short u[8]; } a0, a1;
  a0.v = *(const short8v*)(H1T + rb);
  a1.v = *(const short8v*)(H1T + NN + rb);
  float v0[8], v1[8];
  float s0 = 0.f, s1 = 0.f;
#pragma unroll
  for (int t = 0; t < 8; ++t) {
    v0[t] = bf2f(a0.u[t]);
    v1[t] = bf2f(a1.u[t]);
    s0 += v0[t]; s1 += v1[t];
  }
  __shared__ float ds[2];
  __shared__ float red[2][4];
  __shared__ float bc[3];
  if (tid == (m >> 3)) { ds[0] = v0[m & 7]; ds[1] = v1[m & 7]; }
  for (int off = 32; off > 0; off >>= 1) {
    s0 += __shfl_down(s0, off, 64);
    s1 += __shfl_down(s1, off, 64);
  }
  if ((tid & 63) == 0) { red[0][tid >> 6] = s0; red[1][tid >> 6] = s1; }
  __syncthreads();
  if (tid == 0) {
    float t0 = red[0][0] + red[0][1] + red[0][2] + red[0][3];
    float t1 = red[1][0] + red[1][1] + red[1][2] + red[1][3];
    float r0 = t0 - ds[0] + 1.f;
    float r1 = t1 - ds[1] + 1.f;
    float rs = t0 + t1 - ds[0] - ds[1] + 1.f;
    bc[0] = (r0 == 0.f) ? 0.f : 1.f / r0;
    bc[1] = (r1 == 0.f) ? 0.f : 1.f / r1;
    bc[2] = (rs == 0.f) ? 0.f : 1.f / rs;
  }
  __syncthreads();
  float i0 = bc[0], i1 = bc[1], is = bc[2];
  union { short8v v; unsigned short u[8]; } o0, o1, os;
#pragma unroll
  for (int t = 0; t < 8; ++t) {
    bool dg = (tid * 8 + t == m);
    o0.u[t] = f2bf((dg ? 1.f : v0[t]) * i0);
    o1.u[t] = f2bf((dg ? 1.f : v1[t]) * i1);
    os.u[t] = f2bf((dg ? 1.f : (v0[t] + v1[t])) * is);
  }
  *(short8v*)(Hn2T + rb) = o0.v;
  *(short8v*)(Hn2T + NN + rb) = o1.v;
  *(short8v*)(HsT + rb) = os.v;
}

// ---------------------------------------------------------------------------
// fp32 GEMM (small K), stores TRANSPOSED bf16: Dt[N][M], ldt=M.
// amode=1: A element (n,k) = relu(XcPre[k>>7][n][k&127]) (lda ignored).
// ---------------------------------------------------------------------------
#define TS 64
#define BK 16
__global__ __launch_bounds__(256) void sgemm_tb_k(const float* __restrict__ A,
                                                  const float* __restrict__ B,
                                                  __hip_bfloat16* __restrict__ Dt,
                                                  int K, int lda, int ldb, int ldt,
                                                  int amode) {
  __shared__ float As[BK][TS];
  __shared__ float Bs[BK][TS + 4];
  const int tid = threadIdx.x;
  const int brow = blockIdx.y * TS;
  const int bcol = blockIdx.x * TS;
  const int tx = tid & 15;
  const int ty = tid >> 4;
  const int la_r = tid >> 2;
  const int la_k = (tid & 3) << 2;
  const int lb_k = tid >> 4;
  const int lb_c = (tid & 15) << 2;
  float acc[4][4] = {{0.f}};
  for (int k0 = 0; k0 < K; k0 += BK) {
    float4 av;
    if (amode == 0) {
      av = *(const float4*)(A + (size_t)(brow + la_r) * lda + k0 + la_k);
    } else {
      int k = k0 + la_k;
      const float* ap = A + (size_t)(k >> 7) * ((size_t)NDIM * WOUT) +
                        (size_t)(brow + la_r) * WOUT + (k & 127);
      av = *(const float4*)ap;
      av.x = fmaxf(av.x, 0.f); av.y = fmaxf(av.y, 0.f);
      av.z = fmaxf(av.z, 0.f); av.w = fmaxf(av.w, 0.f);
    }
    float4 bv = *(const float4*)(B + (size_t)(k0 + lb_k) * ldb + bcol + lb_c);
    __syncthreads();
    As[la_k + 0][la_r] = av.x;
    As[la_k + 1][la_r] = av.y;
    As[la_k + 2][la_r] = av.z;
    As[la_k + 3][la_r] = av.w;
    *(float4*)&Bs[lb_k][lb_c] = bv;
    __syncthreads();
#pragma unroll
    for (int kk = 0; kk < BK; ++kk) {
      float a0 = As[kk][ty * 4 + 0], a1 = As[kk][ty * 4 + 1];
      float a2 = As[kk][ty * 4 + 2], a3 = As[kk][ty * 4 + 3];
      float b0 = Bs[kk][tx * 4 + 0], b1 = Bs[kk][tx * 4 + 1];
      float b2 = Bs[kk][tx * 4 + 2], b3 = Bs[kk][tx * 4 + 3];
      acc[0][0] += a0 * b0; acc[0][1] += a0 * b1; acc[0][2] += a0 * b2; acc[0][3] += a0 * b3;
      acc[1][0] += a1 * b0; acc[1][1] += a1 * b1; acc[1][2] += a1 * b2; acc[1][3] += a1 * b3;
      acc[2][0] += a2 * b0; acc[2][1] += a2 * b1; acc[2][2] += a2 * b2; acc[2][3] += a2 * b3;
      acc[3][0] += a3 * b0; acc[3][1] += a3 * b1; acc[3][2] += a3 * b2; acc[3][3] += a3 * b3;
    }
  }
#pragma unroll
  for (int i = 0; i < 4; ++i)
#pragma unroll
    for (int j = 0; j < 4; ++j)
      Dt[(size_t)(bcol + tx * 4 + j) * ldt + brow + ty * 4 + i] = __float2bfloat16(acc[i][j]);
}

// ---------------------------------------------------------------------------
// blocks [0,2048): BCE loss row n. blocks [2048,3072): y + class loss.
// ---------------------------------------------------------------------------
__global__ __launch_bounds__(256) void loss_mega_k(const float* __restrict__ XoXr,
                                                   const float* __restrict__ X,
                                                   const float* __restrict__ lin_w,
                                                   const float* __restrict__ lin_b,
                                                   const int* __restrict__ txs,
                                                   const int* __restrict__ tgt,
                                                   float* __restrict__ yout,
                                                   float* __restrict__ acc) {
  const int b = blockIdx.x;
  const int tid = threadIdx.x;
  if (b < 2048) {
    float xr = XoXr[(size_t)b * 384 + 128 + tid];
    if (xr > 1.f) xr = 1.f / (1.f + expf(-xr));
    if (xr < 0.f) xr = 1.f / (1.f + expf(-xr));
    float p = fminf(fmaxf(xr, 1e-7f), 1.f - 1e-7f);
    float xv = X[(size_t)b * WIN + tid];
    float t = xv * logf(p) + (1.f - xv) * log1pf(-p);
    for (int off = 32; off > 0; off >>= 1) t += __shfl_down(t, off, 64);
    __shared__ float red[4];
    if ((tid & 63) == 0) red[tid >> 6] = t;
    __syncthreads();
    if (tid == 0) atomicAdd(acc + 1, red[0] + red[1] + red[2] + red[3]);
    return;
  }
  const int t = b - 2048;
  __shared__ float xo[WOUT];
  __shared__ float ys[NCLS];
  int x = txs[t];
  if (tid < WOUT) xo[tid] = XoXr[(size_t)x * 384 + tid];
  __syncthreads();
  if (tid < NCLS) {
    float s = lin_b[tid];
    for (int d = 0; d < WOUT; ++d) s += xo[d] * lin_w[tid * WOUT + d];
    ys[tid] = s;
    yout[(size_t)t * NCLS + tid] = s;
  }
  __syncthreads();
  if (tid == 0) {
    float m = ys[0];
    for (int k = 1; k < NCLS; ++k) m = fmaxf(m, ys[k]);
    float se = 0.f;
    for (int k = 0; k < NCLS; ++k) se += expf(ys[k] - m);
    float lse = m + logf(se);
    atomicAdd(acc, lse - ys[tgt[t]]);
  }
}

__global__ void finalize_k(const float* __restrict__ acc, float* __restrict__ dout) {
  float lossC = acc[0] / (float)NTGT;
  float lossR = -acc[1] / (float)(NDIM * WIN);
  dout[0] = lossC + lossR;
  dout[1 + NTGT * NCLS + 30] = lossR;
}

// ---------------------------------------------------------------------------
extern "C" void kernel_launch(void* const* d_in, const int* in_sizes, int n_in,
                              void* d_out, int out_size, void* d_ws, size_t ws_size,
                              hipStream_t stream) {
  const float* A    = (const float*)d_in[0];
  const float* X    = (const float*)d_in[1];
  const float* W    = (const float*)d_in[2];
  const float* W1   = (const float*)d_in[3];
  const float* W2   = (const float*)d_in[4];
  const float* linw = (const float*)d_in[5];
  const float* linb = (const float*)d_in[6];
  const float* w0a  = (const float*)d_in[7];
  const float* w0b  = (const float*)d_in[8];
  const float* w1a  = (const float*)d_in[9];
  const int* txs    = (const int*)d_in[10];
  const int* tgt    = (const int*)d_in[11];
  float* dout = (float*)d_out;

  float* ws = (float*)d_ws;
  // 5 big regions, NN floats = 2*NN bf16 each:
  // RA: a -> H1T ; RB: bT -> Hn2T ; RC: a1T -> HsT ; RD: H ; RE: Hn
  __hip_bfloat16* RA = (__hip_bfloat16*)(ws);
  __hip_bfloat16* RB = (__hip_bfloat16*)(ws + NN);
  __hip_bfloat16* RC = (__hip_bfloat16*)(ws + 2 * NN);
  __hip_bfloat16* RD = (__hip_bfloat16*)(ws + 3 * NN);
  __hip_bfloat16* RE = (__hip_bfloat16*)(ws + 4 * NN);
  float* sm   = ws + 5 * NN;
  float* acc   = sm;                 sm += 16;
  float* deg   = sm;                 sm += CDIM * NDIM;
  __hip_bfloat16* XWT = (__hip_bfloat16*)sm;    sm += (size_t)NDIM * WOUT / 2;
  float* XcPre = sm;                 sm += (size_t)CDIM * NDIM * WOUT;
  float* W12   = sm;                 sm += (size_t)(2 * WOUT) * 384;
  __hip_bfloat16* XC12T = (__hip_bfloat16*)sm;  sm += (size_t)NDIM * 384 / 2;
  float* XoXr  = sm;                 sm += (size_t)NDIM * 384;

  dim3 blk256(256);

  // 1. fused setup: a(RA), bT(RB), a1T(RC) + all zeroing + W12 + Ws
  wsum_mega_k<<<dim3(4096 + (N_PREP + 255) / 256), blk256, 0, stream>>>(
      A, w0a, w0b, w1a, RA, RB, RC, acc, deg, XcPre, XoXr, W12, W1, W2, dout);
  // 2. H[c] = a[c] @ b[c] -> bf16 RD; diag-excluded column sums -> deg
  mfma_bt_k<<<dim3(16, 16, 2), blk256, 0, stream>>>(RA, RB, RD, NDIM, NDIM,
                                                    NN, NN, NN, 1, 1, deg);
  // 3. Hn = colscale(H) -> RE
  col_scale_k<<<dim3((unsigned)(2 * NN / 2048)), blk256, 0, stream>>>(RD, deg, RE);
  // 4. H1T[c] = a1T[c] @ Hn[c]^T -> bf16 RA
  mfma_bt_k<<<dim3(16, 16, 2), blk256, 0, stream>>>(RC, RE, RA, NDIM, NDIM,
                                                    NN, NN, NN, 1, 1, nullptr);
  // 5. row norms: Hn2T -> RB (2ch), HsT -> RC
  rowmega_k<<<dim3(NDIM), blk256, 0, stream>>>(RA, RB, RC);
  // 6. XWT = (X @ W)^T bf16
  sgemm_tb_k<<<dim3(WOUT / TS, NDIM / TS), blk256, 0, stream>>>(X, W, XWT, WIN,
                                                                WIN, WOUT, NDIM, 0);
  // 7. XcPre[c] = Hn2T[c] @ XW (split-K 8, atomic f32)
  mfma_bt_k<<<dim3(1, 16, 16), blk256, 0, stream>>>(RB, XWT, XcPre, NDIM, WOUT,
                                                    NN, 0, (size_t)NDIM * WOUT, 8, 0, nullptr);
  // 8. XC12T = (relu(Xcat) @ [W1|W2])^T bf16  (relu+concat fused into A-load)
  sgemm_tb_k<<<dim3(384 / TS, NDIM / TS), blk256, 0, stream>>>(XcPre, W12, XC12T, 2 * WOUT,
                                                               0, 384, NDIM, 1);
  // 9. XoXr = HsT @ XC12 (split-K 8, atomic f32)
  mfma_bt_k<<<dim3(3, 16, 8), blk256, 0, stream>>>(RC, XC12T, XoXr, NDIM, 384,
                                                   0, 0, 0, 8, 0, nullptr);
  // 10. losses + y
  loss_mega_k<<<dim3(2048 + NTGT), blk256, 0, stream>>>(XoXr, X, linw, linb, txs, tgt,
                                                        dout + 1, acc);
  finalize_k<<<dim3(1), dim3(1), 0, stream>>>(acc, dout);
}

// Round 6
// 341.705 us; speedup vs baseline: 5.8506x; 1.1354x over previous
//
#include <hip/hip_runtime.h>
#include <hip/hip_bf16.h>
#include <math.h>

#define NDIM 2048
#define EDIM 5
#define CDIM 2
#define WIN 256
#define WOUT 128
#define NCLS 8
#define NTGT 1024
#define NN ((size_t)NDIM * NDIM)
#define HNSC 256.0f          // Hn stored as fp8 * HNSC (raw ~5e-4 underflows e4m3)
#define HNSCI 0.00390625f    // 1/HNSC

typedef __attribute__((ext_vector_type(8))) short short8v;
typedef __attribute__((ext_vector_type(4))) float float4v;
typedef __attribute__((ext_vector_type(8))) int int8v;
typedef __attribute__((ext_vector_type(4))) int int4v;
typedef __attribute__((ext_vector_type(2))) int int2v;

__device__ __forceinline__ void gl2lds16(const void* g, void* l) {
  __builtin_amdgcn_global_load_lds((__attribute__((address_space(1))) const unsigned int*)g,
                                   (__attribute__((address_space(3))) unsigned int*)l, 16, 0, 0);
}
__device__ __forceinline__ float bf2f(unsigned short u) {
  return __uint_as_float(((unsigned)u) << 16);
}
__device__ __forceinline__ unsigned short f2bf(float f) {
  __hip_bfloat16 h = __float2bfloat16(f);
  return *(unsigned short*)&h;
}
__device__ __forceinline__ unsigned char f2fp8(float f) {
  return (unsigned char)(__builtin_amdgcn_cvt_pk_fp8_f32(f, f, 0, false) & 0xff);
}

// ---------------------------------------------------------------------------
// mega setup kernel. blocks < 4096: one 32x32 tile of A -> a, bT, a1T (fp8
// e4m3, softmax coefs computed in-block). blocks >= 4096: zero
// XcPre/XoXr/deg/acc, build W12, compute Ws softmax outputs into dout.
// ---------------------------------------------------------------------------
#define N_XC (CDIM * NDIM * WOUT)
#define N_XO (NDIM * 384)
#define N_W12 (2 * WOUT * 384)
#define N_PREP (N_XC + N_XO + N_W12 + CDIM * NDIM + 16 + 30)
__global__ __launch_bounds__(256) void wsum_mega_k(
    const float* __restrict__ A, const float* __restrict__ w0a,
    const float* __restrict__ w0b, const float* __restrict__ w1a,
    unsigned char* __restrict__ a_out, unsigned char* __restrict__ bT,
    unsigned char* __restrict__ a1T,
    float* __restrict__ acc, float* __restrict__ deg,
    float* __restrict__ XcPre, float* __restrict__ XoXr, float* __restrict__ W12,
    const float* __restrict__ W1, const float* __restrict__ W2,
    float* __restrict__ dout) {
  const int b = blockIdx.x;
  const int tid = threadIdx.x;
  if (b >= 4096) {
    int idx = (b - 4096) * 256 + tid;
    if (idx < N_XC) { XcPre[idx] = 0.f; return; }
    idx -= N_XC;
    if (idx < N_XO) { XoXr[idx] = 0.f; return; }
    idx -= N_XO;
    if (idx < N_W12) {
      int k = idx / 384, j = idx - k * 384;
      W12[idx] = (j < 128) ? W1[k * 128 + j] : W2[k * 256 + (j - 128)];
      return;
    }
    idx -= N_W12;
    if (idx < CDIM * NDIM) { deg[idx] = 0.f; return; }
    idx -= CDIM * NDIM;
    if (idx < 16) { acc[idx] = 0.f; return; }
    idx -= 16;
    if (idx < 30) {
      int m = idx / 10, rr = idx - m * 10, c = rr / 5, e = rr - c * 5;
      const float* src = (m == 0) ? w0a : (m == 1) ? w0b : w1a;
      float mx = -1e30f;
      for (int t = 0; t < 5; ++t) mx = fmaxf(mx, src[c * 5 + t]);
      float s = 0.f, ve = 0.f;
      for (int t = 0; t < 5; ++t) {
        float ex = expf(src[c * 5 + t] - mx);
        s += ex;
        if (t == e) ve = ex;
      }
      dout[1 + NTGT * NCLS + idx] = ve / s;
    }
    return;
  }
  // tile work
  __shared__ float swl[32];
  __shared__ float tb[CDIM][32][33];
  __shared__ float tc[CDIM][32][33];
  if (tid < 6) {
    int m = tid >> 1, c = tid & 1;
    const float* src = (m == 0) ? w0a : (m == 1) ? w0b : w1a;
    float mx = -1e30f;
    for (int e = 0; e < 5; ++e) mx = fmaxf(mx, src[c * 5 + e]);
    float ex[5]; float s = 0.f;
    for (int e = 0; e < 5; ++e) { ex[e] = expf(src[c * 5 + e] - mx); s += ex[e]; }
    for (int e = 0; e < 5; ++e) swl[m * 10 + c * 5 + e] = ex[e] / s;
  }
  __syncthreads();
  const int bx = (b & 63) * 32, by = (b >> 6) * 32;
  const int tx = tid & 31, ty = tid >> 5;
#pragma unroll
  for (int rr = 0; rr < 32; rr += 8) {
    int n = by + ty + rr, m = bx + tx;
    size_t base = ((size_t)n * NDIM + m) * EDIM;
    float v0 = A[base], v1 = A[base + 1], v2 = A[base + 2], v3 = A[base + 3], v4 = A[base + 4];
#pragma unroll
    for (int c = 0; c < CDIM; ++c) {
      float sa = swl[c*5]*v0 + swl[c*5+1]*v1 + swl[c*5+2]*v2 + swl[c*5+3]*v3 + swl[c*5+4]*v4;
      float sb = swl[10+c*5]*v0 + swl[10+c*5+1]*v1 + swl[10+c*5+2]*v2 + swl[10+c*5+3]*v3 + swl[10+c*5+4]*v4;
      float sc = swl[20+c*5]*v0 + swl[20+c*5+1]*v1 + swl[20+c*5+2]*v2 + swl[20+c*5+3]*v3 + swl[20+c*5+4]*v4;
      a_out[c * NN + (size_t)n * NDIM + m] = f2fp8(sa);
      tb[c][ty + rr][tx] = sb;
      tc[c][ty + rr][tx] = sc;
    }
  }
  __syncthreads();
#pragma unroll
  for (int rr = 0; rr < 32; rr += 8) {
    int mm = bx + ty + rr, nn2 = by + tx;
#pragma unroll
    for (int c = 0; c < CDIM; ++c) {
      bT[c * NN + (size_t)mm * NDIM + nn2] = f2fp8(tb[c][tx][ty + rr]);
      a1T[c * NN + (size_t)mm * NDIM + nn2] = f2fp8(tc[c][tx][ty + rr]);
    }
  }
}

// ---------------------------------------------------------------------------
// MX-fp8 (unit scale) MFMA GEMM, B^T input: C[M,N] = A[M,K] @ BT[N,K]^T.
// 128x128 tile, BK=128 fp8 bytes = 128 B LDS rows, XOR-swizzle (row&7) on the
// global gather side (same conflict-free geometry as the R5 bf16 kernel).
// mfma_scale_f32_16x16x128_f8f6f4, scales = 0x7F7F7F7F (=1.0 any byte sel).
// Output bf16 at batch*sC. cs: diag-excluded column sums -> cs[batch*N + col].
// ---------------------------------------------------------------------------
__global__ __launch_bounds__(256) void mfma_fp8_k(
    const unsigned char* __restrict__ Ab, const unsigned char* __restrict__ Bt,
    __hip_bfloat16* __restrict__ Cv, int K, int ldc,
    size_t sA, size_t sB, size_t sC, float* __restrict__ cs) {
  __shared__ __align__(16) unsigned char As[128 * 128];
  __shared__ __align__(16) unsigned char Bs[128 * 128];
  const int tid = threadIdx.x;
  const int lane = tid & 63;
  const int wave = tid >> 6;
  const int batch = blockIdx.z;
  const unsigned char* A = Ab + (size_t)batch * sA;
  const unsigned char* B = Bt + (size_t)batch * sB;
  const int row0 = blockIdx.y * 128;
  const int col0 = blockIdx.x * 128;

  const int wr = (wave >> 1) * 64;
  const int wc = (wave & 1) * 64;
  const int q = lane >> 4;
  const int r = lane & 15;

  float4v acc[4][4] = {};

  const int srow = lane >> 3;                        // 0..7
  const int scol = ((lane & 7) ^ (srow & 7)) * 16;   // swizzled global granule, bytes
  const int fsw = r & 7;

  for (int k0 = 0; k0 < K; k0 += 128) {
    __syncthreads();
#pragma unroll
    for (int s = 0; s < 4; ++s) {
      gl2lds16(A + (size_t)(row0 + s * 32 + wave * 8 + srow) * K + k0 + scol,
               As + s * 4096 + wave * 1024);
      gl2lds16(B + (size_t)(col0 + s * 32 + wave * 8 + srow) * K + k0 + scol,
               Bs + s * 4096 + wave * 1024);
    }
    __syncthreads();

    union { int8v v; int4v h[2]; } ua[4], ub[4];
#pragma unroll
    for (int i = 0; i < 4; ++i) {
      const unsigned char* pa = As + (size_t)(wr + i * 16 + r) * 128;
      const unsigned char* pb = Bs + (size_t)(wc + i * 16 + r) * 128;
      ua[i].h[0] = *(const int4v*)(pa + (((2 * q) ^ fsw) * 16));
      ua[i].h[1] = *(const int4v*)(pa + (((2 * q + 1) ^ fsw) * 16));
      ub[i].h[0] = *(const int4v*)(pb + (((2 * q) ^ fsw) * 16));
      ub[i].h[1] = *(const int4v*)(pb + (((2 * q + 1) ^ fsw) * 16));
    }
#pragma unroll
    for (int i = 0; i < 4; ++i)
#pragma unroll
      for (int j = 0; j < 4; ++j)
        acc[i][j] = __builtin_amdgcn_mfma_scale_f32_16x16x128_f8f6f4(
            ua[i].v, ub[j].v, acc[i][j], 0, 0, 0, 0x7F7F7F7F, 0, 0x7F7F7F7F);
  }

  __hip_bfloat16* Cp = Cv + (size_t)batch * sC;
#pragma unroll
  for (int i = 0; i < 4; ++i) {
    int row = row0 + wr + i * 16 + q * 4;
#pragma unroll
    for (int j = 0; j < 4; ++j) {
      int col = col0 + wc + j * 16 + r;
#pragma unroll
      for (int e = 0; e < 4; ++e)
        Cp[(size_t)(row + e) * ldc + col] = __float2bfloat16(acc[i][j][e]);
    }
  }

  if (cs) {  // column sums excluding the diagonal element
    float* csp = cs + (size_t)batch * NDIM;
#pragma unroll
    for (int j = 0; j < 4; ++j) {
      int col = col0 + wc + j * 16 + r;
      float s = 0.f;
#pragma unroll
      for (int i = 0; i < 4; ++i) {
        int rowb = row0 + wr + i * 16 + q * 4;
#pragma unroll
        for (int e = 0; e < 4; ++e)
          if (rowb + e != col) s += acc[i][j][e];
      }
      s += __shfl_xor(s, 16, 64);
      s += __shfl_xor(s, 32, 64);
      if (lane < 16) atomicAdd(&csp[col], s);
    }
  }
}

// ---------------------------------------------------------------------------
// bf16 MFMA GEMM (tail): B^T input, BK=64, swizzled. f32 out, atomic if
// nsplit>1 into pre-zeroed C.
// ---------------------------------------------------------------------------
__global__ __launch_bounds__(256) void mfma_bt_k(
    const __hip_bfloat16* __restrict__ Ab, const __hip_bfloat16* __restrict__ Bt,
    float* __restrict__ Cv, int K, int ldc,
    size_t sA, size_t sB, size_t sC, int nsplit) {
  __shared__ __hip_bfloat16 As[128 * 64];
  __shared__ __hip_bfloat16 Bs[128 * 64];
  const int tid = threadIdx.x;
  const int lane = tid & 63;
  const int wave = tid >> 6;
  const int batch = blockIdx.z / nsplit;
  const int split = blockIdx.z - batch * nsplit;
  const __hip_bfloat16* A = Ab + (size_t)batch * sA;
  const __hip_bfloat16* B = Bt + (size_t)batch * sB;
  const int row0 = blockIdx.y * 128;
  const int col0 = blockIdx.x * 128;
  const int kchunk = K / nsplit;
  const int kbeg = split * kchunk;
  const int kend = kbeg + kchunk;

  const int wr = (wave >> 1) * 64;
  const int wc = (wave & 1) * 64;
  const int q = lane >> 4;
  const int r = lane & 15;

  float4v acc[4][4] = {};

  const int srow = lane >> 3;
  const int scol = ((lane & 7) ^ (srow & 7)) * 8;
  const int fsw = r & 7;

  for (int k0 = kbeg; k0 < kend; k0 += 64) {
    __syncthreads();
#pragma unroll
    for (int s = 0; s < 4; ++s) {
      gl2lds16(A + (size_t)(row0 + s * 32 + wave * 8 + srow) * K + k0 + scol,
               (char*)As + s * 4096 + wave * 1024);
      gl2lds16(B + (size_t)(col0 + s * 32 + wave * 8 + srow) * K + k0 + scol,
               (char*)Bs + s * 4096 + wave * 1024);
    }
    __syncthreads();
#pragma unroll
    for (int h = 0; h < 2; ++h) {
      short8v af[4], bf[4];
#pragma unroll
      for (int i = 0; i < 4; ++i) {
        af[i] = *(const short8v*)((const char*)As + (size_t)(wr + i * 16 + r) * 128 +
                                  (((h * 4 + q) ^ fsw) * 16));
        bf[i] = *(const short8v*)((const char*)Bs + (size_t)(wc + i * 16 + r) * 128 +
                                  (((h * 4 + q) ^ fsw) * 16));
      }
#pragma unroll
      for (int i = 0; i < 4; ++i)
#pragma unroll
        for (int j = 0; j < 4; ++j)
          acc[i][j] = __builtin_amdgcn_mfma_f32_16x16x32_bf16(af[i], bf[j], acc[i][j], 0, 0, 0);
    }
  }

  float* Cp = Cv + (size_t)batch * sC;
#pragma unroll
  for (int i = 0; i < 4; ++i) {
    int row = row0 + wr + i * 16 + q * 4;
#pragma unroll
    for (int j = 0; j < 4; ++j) {
      int col = col0 + wc + j * 16 + r;
#pragma unroll
      for (int e = 0; e < 4; ++e) {
        float v = acc[i][j][e];
        if (nsplit > 1) atomicAdd(&Cp[(size_t)(row + e) * ldc + col], v);
        else Cp[(size_t)(row + e) * ldc + col] = v;
      }
    }
  }
}

// ---------------------------------------------------------------------------
// Hn = norm(H, add=False): zero diag, col j scaled by HNSC/deg[j], fp8 out.
// 8 elems/thread: 16 B bf16 in, 8 B fp8 out.
// ---------------------------------------------------------------------------
__global__ __launch_bounds__(256) void col_scale_k(const __hip_bfloat16* __restrict__ H,
                                                   const float* __restrict__ deg,
                                                   unsigned char* __restrict__ out) {
  size_t base = ((size_t)blockIdx.x * 256 + threadIdx.x) * 8;  // over 2*NN
  int c = (int)(base >> 22);
  int i = (int)((base >> 11) & (NDIM - 1));
  int j0 = (int)(base & (NDIM - 1));
  union { short8v v; unsigned short u[8]; } p;
  p.v = *(const short8v*)(H + base);
  float f[8];
#pragma unroll
  for (int t = 0; t < 8; ++t) {
    int j = j0 + t;
    float d = deg[c * NDIM + j];
    float inv = (d == 0.f) ? 0.f : HNSC / d;
    float v = (i == j) ? 0.f : bf2f(p.u[t]);
    f[t] = v * inv;
  }
  int w0 = __builtin_amdgcn_cvt_pk_fp8_f32(f[0], f[1], 0, false);
  w0 = __builtin_amdgcn_cvt_pk_fp8_f32(f[2], f[3], w0, true);
  int w1 = __builtin_amdgcn_cvt_pk_fp8_f32(f[4], f[5], 0, false);
  w1 = __builtin_amdgcn_cvt_pk_fp8_f32(f[6], f[7], w1, true);
  int2v o; o.x = w0; o.y = w1;
  *(int2v*)(out + base) = o;
}

// ---------------------------------------------------------------------------
// row norms over H1T (2ch bf16, values *HNSC): Hn2T[0], Hn2T[1], HsT bf16
// (diag forced to 1). Descales by HNSCI at load.
// ---------------------------------------------------------------------------
__global__ __launch_bounds__(256) void rowmega_k(const __hip_bfloat16* __restrict__ H1T,
                                                 __hip_bfloat16* __restrict__ Hn2T,
                                                 __hip_bfloat16* __restrict__ HsT) {
  const int m = blockIdx.x;
  const int tid = threadIdx.x;
  const size_t rb = (size_t)m * NDIM + tid * 8;
  union { short8v v; unsigned short u[8]; } a0, a1;
  a0.v = *(const short8v*)(H1T + rb);
  a1.v = *(const short8v*)(H1T + NN + rb);
  float v0[8], v1[8];
  float s0 = 0.f, s1 = 0.f;
#pragma unroll
  for (int t = 0; t < 8; ++t) {
    v0[t] = bf2f(a0.u[t]) * HNSCI;
    v1[t] = bf2f(a1.u[t]) * HNSCI;
    s0 += v0[t]; s1 += v1[t];
  }
  __shared__ float ds[2];
  __shared__ float red[2][4];
  __shared__ float bc[3];
  if (tid == (m >> 3)) { ds[0] = v0[m & 7]; ds[1] = v1[m & 7]; }
  for (int off = 32; off > 0; off >>= 1) {
    s0 += __shfl_down(s0, off, 64);
    s1 += __shfl_down(s1, off, 64);
  }
  if ((tid & 63) == 0) { red[0][tid >> 6] = s0; red[1][tid >> 6] = s1; }
  __syncthreads();
  if (tid == 0) {
    float t0 = red[0][0] + red[0][1] + red[0][2] + red[0][3];
    float t1 = red[1][0] + red[1][1] + red[1][2] + red[1][3];
    float r0 = t0 - ds[0] + 1.f;
    float r1 = t1 - ds[1] + 1.f;
    float rs = t0 + t1 - ds[0] - ds[1] + 1.f;
    bc[0] = (r0 == 0.f) ? 0.f : 1.f / r0;
    bc[1] = (r1 == 0.f) ? 0.f : 1.f / r1;
    bc[2] = (rs == 0.f) ? 0.f : 1.f / rs;
  }
  __syncthreads();
  float i0 = bc[0], i1 = bc[1], is = bc[2];
  union { short8v v; unsigned short u[8]; } o0, o1, os;
#pragma unroll
  for (int t = 0; t < 8; ++t) {
    bool dg = (tid * 8 + t == m);
    o0.u[t] = f2bf((dg ? 1.f : v0[t]) * i0);
    o1.u[t] = f2bf((dg ? 1.f : v1[t]) * i1);
    os.u[t] = f2bf((dg ? 1.f : (v0[t] + v1[t])) * is);
  }
  *(short8v*)(Hn2T + rb) = o0.v;
  *(short8v*)(Hn2T + NN + rb) = o1.v;
  *(short8v*)(HsT + rb) = os.v;
}

// ---------------------------------------------------------------------------
// fp32 GEMM (small K), stores TRANSPOSED bf16: Dt[N][M], ldt=M.
// amode=1: A element (n,k) = relu(XcPre[k>>7][n][k&127]) (lda ignored).
// ---------------------------------------------------------------------------
#define TS 64
#define BK 16
__global__ __launch_bounds__(256) void sgemm_tb_k(const float* __restrict__ A,
                                                  const float* __restrict__ B,
                                                  __hip_bfloat16* __restrict__ Dt,
                                                  int K, int lda, int ldb, int ldt,
                                                  int amode) {
  __shared__ float As[BK][TS];
  __shared__ float Bs[BK][TS + 4];
  const int tid = threadIdx.x;
  const int brow = blockIdx.y * TS;
  const int bcol = blockIdx.x * TS;
  const int tx = tid & 15;
  const int ty = tid >> 4;
  const int la_r = tid >> 2;
  const int la_k = (tid & 3) << 2;
  const int lb_k = tid >> 4;
  const int lb_c = (tid & 15) << 2;
  float acc[4][4] = {{0.f}};
  for (int k0 = 0; k0 < K; k0 += BK) {
    float4 av;
    if (amode == 0) {
      av = *(const float4*)(A + (size_t)(brow + la_r) * lda + k0 + la_k);
    } else {
      int k = k0 + la_k;
      const float* ap = A + (size_t)(k >> 7) * ((size_t)NDIM * WOUT) +
                        (size_t)(brow + la_r) * WOUT + (k & 127);
      av = *(const float4*)ap;
      av.x = fmaxf(av.x, 0.f); av.y = fmaxf(av.y, 0.f);
      av.z = fmaxf(av.z, 0.f); av.w = fmaxf(av.w, 0.f);
    }
    float4 bv = *(const float4*)(B + (size_t)(k0 + lb_k) * ldb + bcol + lb_c);
    __syncthreads();
    As[la_k + 0][la_r] = av.x;
    As[la_k + 1][la_r] = av.y;
    As[la_k + 2][la_r] = av.z;
    As[la_k + 3][la_r] = av.w;
    *(float4*)&Bs[lb_k][lb_c] = bv;
    __syncthreads();
#pragma unroll
    for (int kk = 0; kk < BK; ++kk) {
      float a0 = As[kk][ty * 4 + 0], a1 = As[kk][ty * 4 + 1];
      float a2 = As[kk][ty * 4 + 2], a3 = As[kk][ty * 4 + 3];
      float b0 = Bs[kk][tx * 4 + 0], b1 = Bs[kk][tx * 4 + 1];
      float b2 = Bs[kk][tx * 4 + 2], b3 = Bs[kk][tx * 4 + 3];
      acc[0][0] += a0 * b0; acc[0][1] += a0 * b1; acc[0][2] += a0 * b2; acc[0][3] += a0 * b3;
      acc[1][0] += a1 * b0; acc[1][1] += a1 * b1; acc[1][2] += a1 * b2; acc[1][3] += a1 * b3;
      acc[2][0] += a2 * b0; acc[2][1] += a2 * b1; acc[2][2] += a2 * b2; acc[2][3] += a2 * b3;
      acc[3][0] += a3 * b0; acc[3][1] += a3 * b1; acc[3][2] += a3 * b2; acc[3][3] += a3 * b3;
    }
  }
#pragma unroll
  for (int i = 0; i < 4; ++i)
#pragma unroll
    for (int j = 0; j < 4; ++j)
      Dt[(size_t)(bcol + tx * 4 + j) * ldt + brow + ty * 4 + i] = __float2bfloat16(acc[i][j]);
}

// ---------------------------------------------------------------------------
// blocks [0,2048): BCE loss row n. blocks [2048,3072): y + class loss.
// ---------------------------------------------------------------------------
__global__ __launch_bounds__(256) void loss_mega_k(const float* __restrict__ XoXr,
                                                   const float* __restrict__ X,
                                                   const float* __restrict__ lin_w,
                                                   const float* __restrict__ lin_b,
                                                   const int* __restrict__ txs,
                                                   const int* __restrict__ tgt,
                                                   float* __restrict__ yout,
                                                   float* __restrict__ acc) {
  const int b = blockIdx.x;
  const int tid = threadIdx.x;
  if (b < 2048) {
    float xr = XoXr[(size_t)b * 384 + 128 + tid];
    if (xr > 1.f) xr = 1.f / (1.f + expf(-xr));
    if (xr < 0.f) xr = 1.f / (1.f + expf(-xr));
    float p = fminf(fmaxf(xr, 1e-7f), 1.f - 1e-7f);
    float xv = X[(size_t)b * WIN + tid];
    float t = xv * logf(p) + (1.f - xv) * log1pf(-p);
    for (int off = 32; off > 0; off >>= 1) t += __shfl_down(t, off, 64);
    __shared__ float red[4];
    if ((tid & 63) == 0) red[tid >> 6] = t;
    __syncthreads();
    if (tid == 0) atomicAdd(acc + 1, red[0] + red[1] + red[2] + red[3]);
    return;
  }
  const int t = b - 2048;
  __shared__ float xo[WOUT];
  __shared__ float ys[NCLS];
  int x = txs[t];
  if (tid < WOUT) xo[tid] = XoXr[(size_t)x * 384 + tid];
  __syncthreads();
  if (tid < NCLS) {
    float s = lin_b[tid];
    for (int d = 0; d < WOUT; ++d) s += xo[d] * lin_w[tid * WOUT + d];
    ys[tid] = s;
    yout[(size_t)t * NCLS + tid] = s;
  }
  __syncthreads();
  if (tid == 0) {
    float m = ys[0];
    for (int k = 1; k < NCLS; ++k) m = fmaxf(m, ys[k]);
    float se = 0.f;
    for (int k = 0; k < NCLS; ++k) se += expf(ys[k] - m);
    float lse = m + logf(se);
    atomicAdd(acc, lse - ys[tgt[t]]);
  }
}

__global__ void finalize_k(const float* __restrict__ acc, float* __restrict__ dout) {
  float lossC = acc[0] / (float)NTGT;
  float lossR = -acc[1] / (float)(NDIM * WIN);
  dout[0] = lossC + lossR;
  dout[1 + NTGT * NCLS + 30] = lossR;
}

// ---------------------------------------------------------------------------
extern "C" void kernel_launch(void* const* d_in, const int* in_sizes, int n_in,
                              void* d_out, int out_size, void* d_ws, size_t ws_size,
                              hipStream_t stream) {
  const float* A    = (const float*)d_in[0];
  const float* X    = (const float*)d_in[1];
  const float* W    = (const float*)d_in[2];
  const float* W1   = (const float*)d_in[3];
  const float* W2   = (const float*)d_in[4];
  const float* linw = (const float*)d_in[5];
  const float* linb = (const float*)d_in[6];
  const float* w0a  = (const float*)d_in[7];
  const float* w0b  = (const float*)d_in[8];
  const float* w1a  = (const float*)d_in[9];
  const int* txs    = (const int*)d_in[10];
  const int* tgt    = (const int*)d_in[11];
  float* dout = (float*)d_out;

  float* ws = (float*)d_ws;
  unsigned char* wb = (unsigned char*)d_ws;
  // fp8 regions (bytes): a, bT, a1T, Hn -> first 8*NN bytes = [0, 2NN floats)
  unsigned char* P_a   = wb;
  unsigned char* P_bT  = wb + 2 * NN;
  unsigned char* P_a1T = wb + 4 * NN;
  unsigned char* P_Hn  = wb + 6 * NN;
  // bf16 regions (each NN floats = 2NN bf16):
  __hip_bfloat16* H_bf   = (__hip_bfloat16*)(ws + 2 * NN);  // H (2ch)
  __hip_bfloat16* H1T_bf = (__hip_bfloat16*)(ws + 3 * NN);  // H1T*HNSC (2ch)
  __hip_bfloat16* Hn2T   = (__hip_bfloat16*)(ws + 4 * NN);  // (2ch)
  __hip_bfloat16* HsT    = (__hip_bfloat16*)(ws);           // 1ch, overlays dead P_a/P_bT
  float* sm   = ws + 5 * NN;
  float* acc   = sm;                 sm += 16;
  float* deg   = sm;                 sm += CDIM * NDIM;
  __hip_bfloat16* XWT = (__hip_bfloat16*)sm;    sm += (size_t)NDIM * WOUT / 2;
  float* XcPre = sm;                 sm += (size_t)CDIM * NDIM * WOUT;
  float* W12   = sm;                 sm += (size_t)(2 * WOUT) * 384;
  __hip_bfloat16* XC12T = (__hip_bfloat16*)sm;  sm += (size_t)NDIM * 384 / 2;
  float* XoXr  = sm;                 sm += (size_t)NDIM * 384;

  dim3 blk256(256);

  // 1. fused setup: a/bT/a1T fp8 + zeroing + W12 + Ws
  wsum_mega_k<<<dim3(4096 + (N_PREP + 255) / 256), blk256, 0, stream>>>(
      A, w0a, w0b, w1a, P_a, P_bT, P_a1T, acc, deg, XcPre, XoXr, W12, W1, W2, dout);
  // 2. H[c] = a[c] @ b[c] -> bf16; diag-excluded column sums -> deg
  mfma_fp8_k<<<dim3(16, 16, 2), blk256, 0, stream>>>(P_a, P_bT, H_bf, NDIM, NDIM,
                                                     NN, NN, NN, deg);
  // 3. Hn*HNSC = colscale(H) -> fp8
  col_scale_k<<<dim3((unsigned)(2 * NN / 2048)), blk256, 0, stream>>>(H_bf, deg, P_Hn);
  // 4. H1T[c]*HNSC = a1T[c] @ (Hn[c]*HNSC)^T -> bf16
  mfma_fp8_k<<<dim3(16, 16, 2), blk256, 0, stream>>>(P_a1T, P_Hn, H1T_bf, NDIM, NDIM,
                                                     NN, NN, NN, nullptr);
  // 5. row norms (descale 1/HNSC): Hn2T (2ch), HsT
  rowmega_k<<<dim3(NDIM), blk256, 0, stream>>>(H1T_bf, Hn2T, HsT);
  // 6. XWT = (X @ W)^T bf16
  sgemm_tb_k<<<dim3(WOUT / TS, NDIM / TS), blk256, 0, stream>>>(X, W, XWT, WIN,
                                                                WIN, WOUT, NDIM, 0);
  // 7. XcPre[c] = Hn2T[c] @ XW (split-K 8, atomic f32)
  mfma_bt_k<<<dim3(1, 16, 16), blk256, 0, stream>>>(Hn2T, XWT, XcPre, NDIM, WOUT,
                                                    NN, 0, (size_t)NDIM * WOUT, 8);
  // 8. XC12T = (relu(Xcat) @ [W1|W2])^T bf16  (relu+concat fused into A-load)
  sgemm_tb_k<<<dim3(384 / TS, NDIM / TS), blk256, 0, stream>>>(XcPre, W12, XC12T, 2 * WOUT,
                                                               0, 384, NDIM, 1);
  // 9. XoXr = HsT @ XC12 (split-K 8, atomic f32)
  mfma_bt_k<<<dim3(3, 16, 8), blk256, 0, stream>>>(HsT, XC12T, XoXr, NDIM, 384,
                                                   0, 0, 0, 8);
  // 10. losses + y
  loss_mega_k<<<dim3(2048 + NTGT), blk256, 0, stream>>>(XoXr, X, linw, linb, txs, tgt,
                                                        dout + 1, acc);
  finalize_k<<<dim3(1), dim3(1), 0, stream>>>(acc, dout);
}

// Round 7
// 300.071 us; speedup vs baseline: 6.6623x; 1.1387x over previous
//
#include <hip/hip_runtime.h>
#include <hip/hip_bf16.h>
#include <math.h>

#define NDIM 2048
#define EDIM 5
#define CDIM 2
#define WIN 256
#define WOUT 128
#define NCLS 8
#define NTGT 1024
#define NN ((size_t)NDIM * NDIM)
#define HNSC 256.0f          // Hn stored as fp8 * HNSC (raw ~5e-4 underflows e4m3)
#define HNSCI 0.00390625f    // 1/HNSC

typedef __attribute__((ext_vector_type(8))) short short8v;
typedef __attribute__((ext_vector_type(4))) float float4v;
typedef __attribute__((ext_vector_type(8))) int int8v;
typedef __attribute__((ext_vector_type(4))) int int4v;
typedef __attribute__((ext_vector_type(2))) int int2v;

__device__ __forceinline__ void gl2lds16(const void* g, void* l) {
  __builtin_amdgcn_global_load_lds((__attribute__((address_space(1))) const unsigned int*)g,
                                   (__attribute__((address_space(3))) unsigned int*)l, 16, 0, 0);
}
__device__ __forceinline__ float bf2f(unsigned short u) {
  return __uint_as_float(((unsigned)u) << 16);
}
__device__ __forceinline__ unsigned short f2bf(float f) {
  __hip_bfloat16 h = __float2bfloat16(f);
  return *(unsigned short*)&h;
}
__device__ __forceinline__ unsigned char f2fp8(float f) {
  return (unsigned char)(__builtin_amdgcn_cvt_pk_fp8_f32(f, f, 0, false) & 0xff);
}

// ---------------------------------------------------------------------------
// mega setup kernel. blocks < 4096: one 32x32 tile of A -> a, bT, a1T (fp8
// e4m3). blocks >= 4096: Xbf = bf16(X); WTbf = W^T bf16; W12Tbf = [W1|W2]^T
// bf16; zero deg/acc; Ws softmax outputs.
// ---------------------------------------------------------------------------
#define N_XBF (NDIM * WIN)          // 524288
#define N_WT (WIN * WOUT)           // 32768
#define N_W12T (384 * WIN)          // 98304
#define N_PREP (N_XBF + N_WT + N_W12T + CDIM * NDIM + 16 + 30)
__global__ __launch_bounds__(256) void wsum_mega_k(
    const float* __restrict__ A, const float* __restrict__ w0a,
    const float* __restrict__ w0b, const float* __restrict__ w1a,
    unsigned char* __restrict__ a_out, unsigned char* __restrict__ bT,
    unsigned char* __restrict__ a1T,
    float* __restrict__ acc, float* __restrict__ deg,
    const float* __restrict__ X, const float* __restrict__ W,
    const float* __restrict__ W1, const float* __restrict__ W2,
    __hip_bfloat16* __restrict__ Xbf, __hip_bfloat16* __restrict__ WTbf,
    __hip_bfloat16* __restrict__ W12Tbf,
    float* __restrict__ dout) {
  const int b = blockIdx.x;
  const int tid = threadIdx.x;
  if (b >= 4096) {
    int idx = (b - 4096) * 256 + tid;
    if (idx < N_XBF) { Xbf[idx] = __float2bfloat16(X[idx]); return; }
    idx -= N_XBF;
    if (idx < N_WT) {  // WTbf[d][k] = W[k][d]
      int d = idx >> 8, k = idx & 255;
      WTbf[idx] = __float2bfloat16(W[k * WOUT + d]);
      return;
    }
    idx -= N_WT;
    if (idx < N_W12T) {  // W12Tbf[j][k] = (j<128 ? W1[k][j] : W2[k][j-128])
      int j = idx >> 8, k = idx & 255;
      W12Tbf[idx] = __float2bfloat16(j < 128 ? W1[k * 128 + j] : W2[k * 256 + (j - 128)]);
      return;
    }
    idx -= N_W12T;
    if (idx < CDIM * NDIM) { deg[idx] = 0.f; return; }
    idx -= CDIM * NDIM;
    if (idx < 16) { acc[idx] = 0.f; return; }
    idx -= 16;
    if (idx < 30) {
      int m = idx / 10, rr = idx - m * 10, c = rr / 5, e = rr - c * 5;
      const float* src = (m == 0) ? w0a : (m == 1) ? w0b : w1a;
      float mx = -1e30f;
      for (int t = 0; t < 5; ++t) mx = fmaxf(mx, src[c * 5 + t]);
      float s = 0.f, ve = 0.f;
      for (int t = 0; t < 5; ++t) {
        float ex = expf(src[c * 5 + t] - mx);
        s += ex;
        if (t == e) ve = ex;
      }
      dout[1 + NTGT * NCLS + idx] = ve / s;
    }
    return;
  }
  // tile work
  __shared__ float swl[32];
  __shared__ float tb[CDIM][32][33];
  __shared__ float tc[CDIM][32][33];
  if (tid < 6) {
    int m = tid >> 1, c = tid & 1;
    const float* src = (m == 0) ? w0a : (m == 1) ? w0b : w1a;
    float mx = -1e30f;
    for (int e = 0; e < 5; ++e) mx = fmaxf(mx, src[c * 5 + e]);
    float ex[5]; float s = 0.f;
    for (int e = 0; e < 5; ++e) { ex[e] = expf(src[c * 5 + e] - mx); s += ex[e]; }
    for (int e = 0; e < 5; ++e) swl[m * 10 + c * 5 + e] = ex[e] / s;
  }
  __syncthreads();
  const int bx = (b & 63) * 32, by = (b >> 6) * 32;
  const int tx = tid & 31, ty = tid >> 5;
#pragma unroll
  for (int rr = 0; rr < 32; rr += 8) {
    int n = by + ty + rr, m = bx + tx;
    size_t base = ((size_t)n * NDIM + m) * EDIM;
    float v0 = A[base], v1 = A[base + 1], v2 = A[base + 2], v3 = A[base + 3], v4 = A[base + 4];
#pragma unroll
    for (int c = 0; c < CDIM; ++c) {
      float sa = swl[c*5]*v0 + swl[c*5+1]*v1 + swl[c*5+2]*v2 + swl[c*5+3]*v3 + swl[c*5+4]*v4;
      float sb = swl[10+c*5]*v0 + swl[10+c*5+1]*v1 + swl[10+c*5+2]*v2 + swl[10+c*5+3]*v3 + swl[10+c*5+4]*v4;
      float sc = swl[20+c*5]*v0 + swl[20+c*5+1]*v1 + swl[20+c*5+2]*v2 + swl[20+c*5+3]*v3 + swl[20+c*5+4]*v4;
      a_out[c * NN + (size_t)n * NDIM + m] = f2fp8(sa);
      tb[c][ty + rr][tx] = sb;
      tc[c][ty + rr][tx] = sc;
    }
  }
  __syncthreads();
#pragma unroll
  for (int rr = 0; rr < 32; rr += 8) {
    int mm = bx + ty + rr, nn2 = by + tx;
#pragma unroll
    for (int c = 0; c < CDIM; ++c) {
      bT[c * NN + (size_t)mm * NDIM + nn2] = f2fp8(tb[c][tx][ty + rr]);
      a1T[c * NN + (size_t)mm * NDIM + nn2] = f2fp8(tc[c][tx][ty + rr]);
    }
  }
}

// ---------------------------------------------------------------------------
// MX-fp8 (unit scale) MFMA GEMM, B^T input. 128x128 tile, BK=128, swizzled.
// Output bf16 at batch*sC. cs: diag-excluded column sums -> cs[batch*N + col].
// ---------------------------------------------------------------------------
__global__ __launch_bounds__(256) void mfma_fp8_k(
    const unsigned char* __restrict__ Ab, const unsigned char* __restrict__ Bt,
    __hip_bfloat16* __restrict__ Cv, int K, int ldc,
    size_t sA, size_t sB, size_t sC, float* __restrict__ cs) {
  __shared__ __align__(16) unsigned char As[128 * 128];
  __shared__ __align__(16) unsigned char Bs[128 * 128];
  const int tid = threadIdx.x;
  const int lane = tid & 63;
  const int wave = tid >> 6;
  const int batch = blockIdx.z;
  const unsigned char* A = Ab + (size_t)batch * sA;
  const unsigned char* B = Bt + (size_t)batch * sB;
  const int row0 = blockIdx.y * 128;
  const int col0 = blockIdx.x * 128;

  const int wr = (wave >> 1) * 64;
  const int wc = (wave & 1) * 64;
  const int q = lane >> 4;
  const int r = lane & 15;

  float4v acc[4][4] = {};

  const int srow = lane >> 3;
  const int scol = ((lane & 7) ^ (srow & 7)) * 16;
  const int fsw = r & 7;

  for (int k0 = 0; k0 < K; k0 += 128) {
    __syncthreads();
#pragma unroll
    for (int s = 0; s < 4; ++s) {
      gl2lds16(A + (size_t)(row0 + s * 32 + wave * 8 + srow) * K + k0 + scol,
               As + s * 4096 + wave * 1024);
      gl2lds16(B + (size_t)(col0 + s * 32 + wave * 8 + srow) * K + k0 + scol,
               Bs + s * 4096 + wave * 1024);
    }
    __syncthreads();

    union { int8v v; int4v h[2]; } ua[4], ub[4];
#pragma unroll
    for (int i = 0; i < 4; ++i) {
      const unsigned char* pa = As + (size_t)(wr + i * 16 + r) * 128;
      const unsigned char* pb = Bs + (size_t)(wc + i * 16 + r) * 128;
      ua[i].h[0] = *(const int4v*)(pa + (((2 * q) ^ fsw) * 16));
      ua[i].h[1] = *(const int4v*)(pa + (((2 * q + 1) ^ fsw) * 16));
      ub[i].h[0] = *(const int4v*)(pb + (((2 * q) ^ fsw) * 16));
      ub[i].h[1] = *(const int4v*)(pb + (((2 * q + 1) ^ fsw) * 16));
    }
#pragma unroll
    for (int i = 0; i < 4; ++i)
#pragma unroll
      for (int j = 0; j < 4; ++j)
        acc[i][j] = __builtin_amdgcn_mfma_scale_f32_16x16x128_f8f6f4(
            ua[i].v, ub[j].v, acc[i][j], 0, 0, 0, 0x7F7F7F7F, 0, 0x7F7F7F7F);
  }

  __hip_bfloat16* Cp = Cv + (size_t)batch * sC;
#pragma unroll
  for (int i = 0; i < 4; ++i) {
    int row = row0 + wr + i * 16 + q * 4;
#pragma unroll
    for (int j = 0; j < 4; ++j) {
      int col = col0 + wc + j * 16 + r;
#pragma unroll
      for (int e = 0; e < 4; ++e)
        Cp[(size_t)(row + e) * ldc + col] = __float2bfloat16(acc[i][j][e]);
    }
  }

  if (cs) {
    float* csp = cs + (size_t)batch * NDIM;
#pragma unroll
    for (int j = 0; j < 4; ++j) {
      int col = col0 + wc + j * 16 + r;
      float s = 0.f;
#pragma unroll
      for (int i = 0; i < 4; ++i) {
        int rowb = row0 + wr + i * 16 + q * 4;
#pragma unroll
        for (int e = 0; e < 4; ++e)
          if (rowb + e != col) s += acc[i][j][e];
      }
      s += __shfl_xor(s, 16, 64);
      s += __shfl_xor(s, 32, 64);
      if (lane < 16) atomicAdd(&csp[col], s);
    }
  }
}

// ---------------------------------------------------------------------------
// bf16 MFMA GEMM (tail): B^T input, BK=64, swizzled.
// mode 1: bf16 store at batch*sC (bf16 elems).
// mode 2: f32 partial store at batch*sC + split*sSplit (f32 elems) — split-K
//         partials, NO atomics; consumer sums the nsplit buffers.
// ---------------------------------------------------------------------------
__global__ __launch_bounds__(256) void mfma_bt_k(
    const __hip_bfloat16* __restrict__ Ab, const __hip_bfloat16* __restrict__ Bt,
    void* __restrict__ Cv, int K, int ldc,
    size_t sA, size_t sB, size_t sC, size_t sSplit, int nsplit, int mode) {
  __shared__ __hip_bfloat16 As[128 * 64];
  __shared__ __hip_bfloat16 Bs[128 * 64];
  const int tid = threadIdx.x;
  const int lane = tid & 63;
  const int wave = tid >> 6;
  const int batch = blockIdx.z / nsplit;
  const int split = blockIdx.z - batch * nsplit;
  const __hip_bfloat16* A = Ab + (size_t)batch * sA;
  const __hip_bfloat16* B = Bt + (size_t)batch * sB;
  const int row0 = blockIdx.y * 128;
  const int col0 = blockIdx.x * 128;
  const int kchunk = K / nsplit;
  const int kbeg = split * kchunk;
  const int kend = kbeg + kchunk;

  const int wr = (wave >> 1) * 64;
  const int wc = (wave & 1) * 64;
  const int q = lane >> 4;
  const int r = lane & 15;

  float4v acc[4][4] = {};

  const int srow = lane >> 3;
  const int scol = ((lane & 7) ^ (srow & 7)) * 8;
  const int fsw = r & 7;

  for (int k0 = kbeg; k0 < kend; k0 += 64) {
    __syncthreads();
#pragma unroll
    for (int s = 0; s < 4; ++s) {
      gl2lds16(A + (size_t)(row0 + s * 32 + wave * 8 + srow) * K + k0 + scol,
               (char*)As + s * 4096 + wave * 1024);
      gl2lds16(B + (size_t)(col0 + s * 32 + wave * 8 + srow) * K + k0 + scol,
               (char*)Bs + s * 4096 + wave * 1024);
    }
    __syncthreads();
#pragma unroll
    for (int h = 0; h < 2; ++h) {
      short8v af[4], bf[4];
#pragma unroll
      for (int i = 0; i < 4; ++i) {
        af[i] = *(const short8v*)((const char*)As + (size_t)(wr + i * 16 + r) * 128 +
                                  (((h * 4 + q) ^ fsw) * 16));
        bf[i] = *(const short8v*)((const char*)Bs + (size_t)(wc + i * 16 + r) * 128 +
                                  (((h * 4 + q) ^ fsw) * 16));
      }
#pragma unroll
      for (int i = 0; i < 4; ++i)
#pragma unroll
        for (int j = 0; j < 4; ++j)
          acc[i][j] = __builtin_amdgcn_mfma_f32_16x16x32_bf16(af[i], bf[j], acc[i][j], 0, 0, 0);
    }
  }

  if (mode == 1) {
    __hip_bfloat16* Cp = (__hip_bfloat16*)Cv + (size_t)batch * sC;
#pragma unroll
    for (int i = 0; i < 4; ++i) {
      int row = row0 + wr + i * 16 + q * 4;
#pragma unroll
      for (int j = 0; j < 4; ++j) {
        int col = col0 + wc + j * 16 + r;
#pragma unroll
        for (int e = 0; e < 4; ++e)
          Cp[(size_t)(row + e) * ldc + col] = __float2bfloat16(acc[i][j][e]);
      }
    }
  } else {
    float* Cp = (float*)Cv + (size_t)batch * sC + (size_t)split * sSplit;
#pragma unroll
    for (int i = 0; i < 4; ++i) {
      int row = row0 + wr + i * 16 + q * 4;
#pragma unroll
      for (int j = 0; j < 4; ++j) {
        int col = col0 + wc + j * 16 + r;
#pragma unroll
        for (int e = 0; e < 4; ++e)
          Cp[(size_t)(row + e) * ldc + col] = acc[i][j][e];
      }
    }
  }
}

// ---------------------------------------------------------------------------
// Hn = norm(H, add=False): zero diag, col j scaled by HNSC/deg[j], fp8 out.
// ---------------------------------------------------------------------------
__global__ __launch_bounds__(256) void col_scale_k(const __hip_bfloat16* __restrict__ H,
                                                   const float* __restrict__ deg,
                                                   unsigned char* __restrict__ out) {
  size_t base = ((size_t)blockIdx.x * 256 + threadIdx.x) * 8;  // over 2*NN
  int c = (int)(base >> 22);
  int i = (int)((base >> 11) & (NDIM - 1));
  int j0 = (int)(base & (NDIM - 1));
  union { short8v v; unsigned short u[8]; } p;
  p.v = *(const short8v*)(H + base);
  float f[8];
#pragma unroll
  for (int t = 0; t < 8; ++t) {
    int j = j0 + t;
    float d = deg[c * NDIM + j];
    float inv = (d == 0.f) ? 0.f : HNSC / d;
    float v = (i == j) ? 0.f : bf2f(p.u[t]);
    f[t] = v * inv;
  }
  int w0 = __builtin_amdgcn_cvt_pk_fp8_f32(f[0], f[1], 0, false);
  w0 = __builtin_amdgcn_cvt_pk_fp8_f32(f[2], f[3], w0, true);
  int w1 = __builtin_amdgcn_cvt_pk_fp8_f32(f[4], f[5], 0, false);
  w1 = __builtin_amdgcn_cvt_pk_fp8_f32(f[6], f[7], w1, true);
  int2v o; o.x = w0; o.y = w1;
  *(int2v*)(out + base) = o;
}

// ---------------------------------------------------------------------------
// row norms over H1T (2ch bf16, values *HNSC): Hn2T[0], Hn2T[1], HsT bf16
// ---------------------------------------------------------------------------
__global__ __launch_bounds__(256) void rowmega_k(const __hip_bfloat16* __restrict__ H1T,
                                                 __hip_bfloat16* __restrict__ Hn2T,
                                                 __hip_bfloat16* __restrict__ HsT) {
  const int m = blockIdx.x;
  const int tid = threadIdx.x;
  const size_t rb = (size_t)m * NDIM + tid * 8;
  union { short8v v; unsigned short u[8]; } a0, a1;
  a0.v = *(const short8v*)(H1T + rb);
  a1.v = *(const short8v*)(H1T + NN + rb);
  float v0[8], v1[8];
  float s0 = 0.f, s1 = 0.f;
#pragma unroll
  for (int t = 0; t < 8; ++t) {
    v0[t] = bf2f(a0.u[t]) * HNSCI;
    v1[t] = bf2f(a1.u[t]) * HNSCI;
    s0 += v0[t]; s1 += v1[t];
  }
  __shared__ float ds[2];
  __shared__ float red[2][4];
  __shared__ float bc[3];
  if (tid == (m >> 3)) { ds[0] = v0[m & 7]; ds[1] = v1[m & 7]; }
  for (int off = 32; off > 0; off >>= 1) {
    s0 += __shfl_down(s0, off, 64);
    s1 += __shfl_down(s1, off, 64);
  }
  if ((tid & 63) == 0) { red[0][tid >> 6] = s0; red[1][tid >> 6] = s1; }
  __syncthreads();
  if (tid == 0) {
    float t0 = red[0][0] + red[0][1] + red[0][2] + red[0][3];
    float t1 = red[1][0] + red[1][1] + red[1][2] + red[1][3];
    float r0 = t0 - ds[0] + 1.f;
    float r1 = t1 - ds[1] + 1.f;
    float rs = t0 + t1 - ds[0] - ds[1] + 1.f;
    bc[0] = (r0 == 0.f) ? 0.f : 1.f / r0;
    bc[1] = (r1 == 0.f) ? 0.f : 1.f / r1;
    bc[2] = (rs == 0.f) ? 0.f : 1.f / rs;
  }
  __syncthreads();
  float i0 = bc[0], i1 = bc[1], is = bc[2];
  union { short8v v; unsigned short u[8]; } o0, o1, os;
#pragma unroll
  for (int t = 0; t < 8; ++t) {
    bool dg = (tid * 8 + t == m);
    o0.u[t] = f2bf((dg ? 1.f : v0[t]) * i0);
    o1.u[t] = f2bf((dg ? 1.f : v1[t]) * i1);
    os.u[t] = f2bf((dg ? 1.f : (v0[t] + v1[t])) * is);
  }
  *(short8v*)(Hn2T + rb) = o0.v;
  *(short8v*)(Hn2T + NN + rb) = o1.v;
  *(short8v*)(HsT + rb) = os.v;
}

// ---------------------------------------------------------------------------
// Xcat[n][c*128+d] = relu(sum_s P7[c][s][n][d])  (8 f32 partials -> bf16)
// ---------------------------------------------------------------------------
__global__ __launch_bounds__(256) void reduce_relu_k(const float* __restrict__ P7,
                                                     __hip_bfloat16* __restrict__ Xcat) {
  int idx = blockIdx.x * 256 + threadIdx.x;  // 524288
  int c = idx >> 18;
  int rem = idx & 262143;
  float s = 0.f;
#pragma unroll
  for (int sp = 0; sp < 8; ++sp)
    s += P7[(size_t)c * 2097152 + (size_t)sp * 262144 + rem];
  int n = rem >> 7, d = rem & 127;
  Xcat[(size_t)n * 256 + (c << 7) + d] = __float2bfloat16(fmaxf(s, 0.f));
}

// ---------------------------------------------------------------------------
// blocks [0,2048): BCE loss row n (sums 8 XoXr partials, cols 128..384).
// blocks [2048,3072): y + class loss (sums partials, cols 0..128).
// ---------------------------------------------------------------------------
__global__ __launch_bounds__(256) void loss_mega_k(const float* __restrict__ P10,
                                                   const float* __restrict__ X,
                                                   const float* __restrict__ lin_w,
                                                   const float* __restrict__ lin_b,
                                                   const int* __restrict__ txs,
                                                   const int* __restrict__ tgt,
                                                   float* __restrict__ yout,
                                                   float* __restrict__ acc) {
  const int b = blockIdx.x;
  const int tid = threadIdx.x;
  if (b < 2048) {
    float xr = 0.f;
#pragma unroll
    for (int sp = 0; sp < 8; ++sp)
      xr += P10[(size_t)sp * 786432 + (size_t)b * 384 + 128 + tid];
    if (xr > 1.f) xr = 1.f / (1.f + expf(-xr));
    if (xr < 0.f) xr = 1.f / (1.f + expf(-xr));
    float p = fminf(fmaxf(xr, 1e-7f), 1.f - 1e-7f);
    float xv = X[(size_t)b * WIN + tid];
    float t = xv * logf(p) + (1.f - xv) * log1pf(-p);
    for (int off = 32; off > 0; off >>= 1) t += __shfl_down(t, off, 64);
    __shared__ float red[4];
    if ((tid & 63) == 0) red[tid >> 6] = t;
    __syncthreads();
    if (tid == 0) atomicAdd(acc + 1, red[0] + red[1] + red[2] + red[3]);
    return;
  }
  const int t = b - 2048;
  __shared__ float xo[WOUT];
  __shared__ float ys[NCLS];
  int x = txs[t];
  if (tid < WOUT) {
    float s = 0.f;
#pragma unroll
    for (int sp = 0; sp < 8; ++sp)
      s += P10[(size_t)sp * 786432 + (size_t)x * 384 + tid];
    xo[tid] = s;
  }
  __syncthreads();
  if (tid < NCLS) {
    float s = lin_b[tid];
    for (int d = 0; d < WOUT; ++d) s += xo[d] * lin_w[tid * WOUT + d];
    ys[tid] = s;
    yout[(size_t)t * NCLS + tid] = s;
  }
  __syncthreads();
  if (tid == 0) {
    float m = ys[0];
    for (int k = 1; k < NCLS; ++k) m = fmaxf(m, ys[k]);
    float se = 0.f;
    for (int k = 0; k < NCLS; ++k) se += expf(ys[k] - m);
    float lse = m + logf(se);
    atomicAdd(acc, lse - ys[tgt[t]]);
  }
}

__global__ void finalize_k(const float* __restrict__ acc, float* __restrict__ dout) {
  float lossC = acc[0] / (float)NTGT;
  float lossR = -acc[1] / (float)(NDIM * WIN);
  dout[0] = lossC + lossR;
  dout[1 + NTGT * NCLS + 30] = lossR;
}

// ---------------------------------------------------------------------------
extern "C" void kernel_launch(void* const* d_in, const int* in_sizes, int n_in,
                              void* d_out, int out_size, void* d_ws, size_t ws_size,
                              hipStream_t stream) {
  const float* A    = (const float*)d_in[0];
  const float* X    = (const float*)d_in[1];
  const float* W    = (const float*)d_in[2];
  const float* W1   = (const float*)d_in[3];
  const float* W2   = (const float*)d_in[4];
  const float* linw = (const float*)d_in[5];
  const float* linb = (const float*)d_in[6];
  const float* w0a  = (const float*)d_in[7];
  const float* w0b  = (const float*)d_in[8];
  const float* w1a  = (const float*)d_in[9];
  const int* txs    = (const int*)d_in[10];
  const int* tgt    = (const int*)d_in[11];
  float* dout = (float*)d_out;

  float* ws = (float*)d_ws;
  unsigned char* wb = (unsigned char*)d_ws;
  // fp8 regions (bytes) in ws[0, 2NN floats):
  unsigned char* P_a   = wb;
  unsigned char* P_bT  = wb + 2 * NN;
  unsigned char* P_a1T = wb + 4 * NN;
  unsigned char* P_Hn  = wb + 6 * NN;
  // bf16 regions:
  __hip_bfloat16* H_bf   = (__hip_bfloat16*)(ws + 2 * NN);  // H (2ch)
  __hip_bfloat16* H1T_bf = (__hip_bfloat16*)(ws + 3 * NN);  // H1T*HNSC (2ch)
  __hip_bfloat16* Hn2T   = (__hip_bfloat16*)(ws + 4 * NN);  // (2ch)
  __hip_bfloat16* HsT    = (__hip_bfloat16*)(ws);           // 1ch, overlays dead fp8 a/bT
  float* sm   = ws + 5 * NN;
  float* acc   = sm;                 sm += 16;
  float* deg   = sm;                 sm += CDIM * NDIM;
  __hip_bfloat16* Xbf    = (__hip_bfloat16*)sm;  sm += N_XBF / 2;
  __hip_bfloat16* WTbf   = (__hip_bfloat16*)sm;  sm += N_WT / 2;
  __hip_bfloat16* W12Tbf = (__hip_bfloat16*)sm;  sm += N_W12T / 2;
  __hip_bfloat16* XWT    = (__hip_bfloat16*)sm;  sm += (size_t)WOUT * NDIM / 2;
  __hip_bfloat16* Xcat   = (__hip_bfloat16*)sm;  sm += (size_t)NDIM * 256 / 2;
  __hip_bfloat16* XC12T  = (__hip_bfloat16*)sm;  sm += (size_t)384 * NDIM / 2;
  float* P7   = sm;                  sm += (size_t)16 * 262144;  // [c][s][2048][128]
  float* P10  = sm;                  sm += (size_t)8 * 786432;   // [s][2048][384]

  dim3 blk256(256);

  // 1. fused setup: a/bT/a1T fp8 + Xbf/WTbf/W12Tbf + deg/acc zero + Ws
  wsum_mega_k<<<dim3(4096 + (N_PREP + 255) / 256), blk256, 0, stream>>>(
      A, w0a, w0b, w1a, P_a, P_bT, P_a1T, acc, deg, X, W, W1, W2,
      Xbf, WTbf, W12Tbf, dout);
  // 2. H[c] = a[c] @ b[c] -> bf16; diag-excluded column sums -> deg
  mfma_fp8_k<<<dim3(16, 16, 2), blk256, 0, stream>>>(P_a, P_bT, H_bf, NDIM, NDIM,
                                                     NN, NN, NN, deg);
  // 3. Hn*HNSC = colscale(H) -> fp8
  col_scale_k<<<dim3((unsigned)(2 * NN / 2048)), blk256, 0, stream>>>(H_bf, deg, P_Hn);
  // 4. H1T[c]*HNSC = a1T[c] @ (Hn[c]*HNSC)^T -> bf16
  mfma_fp8_k<<<dim3(16, 16, 2), blk256, 0, stream>>>(P_a1T, P_Hn, H1T_bf, NDIM, NDIM,
                                                     NN, NN, NN, nullptr);
  // 5. row norms (descale 1/HNSC): Hn2T (2ch), HsT
  rowmega_k<<<dim3(NDIM), blk256, 0, stream>>>(H1T_bf, Hn2T, HsT);
  // 6. XWT[128][2048] = WTbf @ Xbf^T  (bf16 out, row-major = step-7's B^T)
  mfma_bt_k<<<dim3(16, 1, 1), blk256, 0, stream>>>(WTbf, Xbf, XWT, WIN, NDIM,
                                                   0, 0, 0, 0, 1, 1);
  // 7. Xc partials: P7[c][s] = Hn2T[c] @ XWT^T (split-K 8, plain f32 stores)
  mfma_bt_k<<<dim3(1, 16, 16), blk256, 0, stream>>>(Hn2T, XWT, P7, NDIM, WOUT,
                                                    NN, 0, 2097152, 262144, 8, 2);
  // 8. Xcat bf16 = relu(sum partials)
  reduce_relu_k<<<dim3(2048), blk256, 0, stream>>>(P7, Xcat);
  // 9. XC12T[384][2048] = W12Tbf @ Xcat^T (bf16 out, row-major = step-10's B^T)
  mfma_bt_k<<<dim3(16, 3, 1), blk256, 0, stream>>>(W12Tbf, Xcat, XC12T, 256, NDIM,
                                                   0, 0, 0, 0, 1, 1);
  // 10. XoXr partials: P10[s] = HsT @ XC12T^T (split-K 8, plain f32 stores)
  mfma_bt_k<<<dim3(3, 16, 8), blk256, 0, stream>>>(HsT, XC12T, P10, NDIM, 384,
                                                   0, 0, 0, 786432, 8, 2);
  // 11. losses + y (sums P10 partials inline)
  loss_mega_k<<<dim3(2048 + NTGT), blk256, 0, stream>>>(P10, X, linw, linb, txs, tgt,
                                                        dout + 1, acc);
  finalize_k<<<dim3(1), dim3(1), 0, stream>>>(acc, dout);
}

// Round 8
// 289.280 us; speedup vs baseline: 6.9108x; 1.0373x over previous
//
#include <hip/hip_runtime.h>
#include <hip/hip_bf16.h>
#include <math.h>

#define NDIM 2048
#define EDIM 5
#define CDIM 2
#define WIN 256
#define WOUT 128
#define NCLS 8
#define NTGT 1024
#define NN ((size_t)NDIM * NDIM)
#define HNSC 256.0f          // Hn stored as fp8 * HNSC (raw ~5e-4 underflows e4m3)
#define HNSCI 0.00390625f    // 1/HNSC

typedef __attribute__((ext_vector_type(8))) short short8v;
typedef __attribute__((ext_vector_type(4))) float float4v;
typedef __attribute__((ext_vector_type(8))) int int8v;
typedef __attribute__((ext_vector_type(4))) int int4v;
typedef __attribute__((ext_vector_type(2))) int int2v;

__device__ __forceinline__ void gl2lds16(const void* g, void* l) {
  __builtin_amdgcn_global_load_lds((__attribute__((address_space(1))) const unsigned int*)g,
                                   (__attribute__((address_space(3))) unsigned int*)l, 16, 0, 0);
}
__device__ __forceinline__ float bf2f(unsigned short u) {
  return __uint_as_float(((unsigned)u) << 16);
}
__device__ __forceinline__ unsigned short f2bf(float f) {
  __hip_bfloat16 h = __float2bfloat16(f);
  return *(unsigned short*)&h;
}
__device__ __forceinline__ unsigned int pk4fp8(float a, float b, float c, float d) {
  int w = __builtin_amdgcn_cvt_pk_fp8_f32(a, b, 0, false);
  return (unsigned int)__builtin_amdgcn_cvt_pk_fp8_f32(c, d, w, true);
}

// ---------------------------------------------------------------------------
// mega setup. blocks < 4096: 32x32 tile of A -> a, bT, a1T (fp8, packed dword
// stores, float4 loads, 4 cols/thread). blocks >= 4096: Xbf/WTbf/W12Tbf bf16,
// zero deg/acc, Ws softmax outputs.
// ---------------------------------------------------------------------------
#define N_XBF (NDIM * WIN)          // 524288
#define N_WT (WIN * WOUT)           // 32768
#define N_W12T (384 * WIN)          // 98304
#define N_PREP (N_XBF + N_WT + N_W12T + CDIM * NDIM + 16 + 30)
__global__ __launch_bounds__(256) void wsum_mega_k(
    const float* __restrict__ A, const float* __restrict__ w0a,
    const float* __restrict__ w0b, const float* __restrict__ w1a,
    unsigned char* __restrict__ a_out, unsigned char* __restrict__ bT,
    unsigned char* __restrict__ a1T,
    float* __restrict__ acc, float* __restrict__ deg,
    const float* __restrict__ X, const float* __restrict__ W,
    const float* __restrict__ W1, const float* __restrict__ W2,
    __hip_bfloat16* __restrict__ Xbf, __hip_bfloat16* __restrict__ WTbf,
    __hip_bfloat16* __restrict__ W12Tbf,
    float* __restrict__ dout) {
  const int b = blockIdx.x;
  const int tid = threadIdx.x;
  if (b >= 4096) {
    int idx = (b - 4096) * 256 + tid;
    if (idx < N_XBF) { Xbf[idx] = __float2bfloat16(X[idx]); return; }
    idx -= N_XBF;
    if (idx < N_WT) {  // WTbf[d][k] = W[k][d]
      int d = idx >> 8, k = idx & 255;
      WTbf[idx] = __float2bfloat16(W[k * WOUT + d]);
      return;
    }
    idx -= N_WT;
    if (idx < N_W12T) {  // W12Tbf[j][k]
      int j = idx >> 8, k = idx & 255;
      W12Tbf[idx] = __float2bfloat16(j < 128 ? W1[k * 128 + j] : W2[k * 256 + (j - 128)]);
      return;
    }
    idx -= N_W12T;
    if (idx < CDIM * NDIM) { deg[idx] = 0.f; return; }
    idx -= CDIM * NDIM;
    if (idx < 16) { acc[idx] = 0.f; return; }
    idx -= 16;
    if (idx < 30) {
      int m = idx / 10, rr = idx - m * 10, c = rr / 5, e = rr - c * 5;
      const float* src = (m == 0) ? w0a : (m == 1) ? w0b : w1a;
      float mx = -1e30f;
      for (int t = 0; t < 5; ++t) mx = fmaxf(mx, src[c * 5 + t]);
      float s = 0.f, ve = 0.f;
      for (int t = 0; t < 5; ++t) {
        float ex = expf(src[c * 5 + t] - mx);
        s += ex;
        if (t == e) ve = ex;
      }
      dout[1 + NTGT * NCLS + idx] = ve / s;
    }
    return;
  }
  // tile work: 32x32, thread = 4 consecutive cols of one row
  __shared__ float swl[32];
  __shared__ float tb[CDIM][32][33];
  __shared__ float tc[CDIM][32][33];
  if (tid < 6) {
    int m = tid >> 1, c = tid & 1;
    const float* src = (m == 0) ? w0a : (m == 1) ? w0b : w1a;
    float mx = -1e30f;
    for (int e = 0; e < 5; ++e) mx = fmaxf(mx, src[c * 5 + e]);
    float ex[5]; float s = 0.f;
    for (int e = 0; e < 5; ++e) { ex[e] = expf(src[c * 5 + e] - mx); s += ex[e]; }
    for (int e = 0; e < 5; ++e) swl[m * 10 + c * 5 + e] = ex[e] / s;
  }
  __syncthreads();
  const int bx = (b & 63) * 32, by = (b >> 6) * 32;
  const int tx4 = tid & 7, ty = tid >> 3;
  const int n = by + ty, m0 = bx + tx4 * 4;
  // 20 consecutive floats = 4 elems x 5 edges, 16B-aligned
  const float* ap = A + ((size_t)n * NDIM + m0) * EDIM;
  float4 f0 = *(const float4*)(ap);
  float4 f1 = *(const float4*)(ap + 4);
  float4 f2 = *(const float4*)(ap + 8);
  float4 f3 = *(const float4*)(ap + 12);
  float4 f4 = *(const float4*)(ap + 16);
  float v[4][5] = {{f0.x, f0.y, f0.z, f0.w, f1.x},
                   {f1.y, f1.z, f1.w, f2.x, f2.y},
                   {f2.z, f2.w, f3.x, f3.y, f3.z},
                   {f3.w, f4.x, f4.y, f4.z, f4.w}};
#pragma unroll
  for (int c = 0; c < CDIM; ++c) {
    float sa[4], sb[4], sc[4];
#pragma unroll
    for (int t = 0; t < 4; ++t) {
      sa[t] = swl[c*5]*v[t][0] + swl[c*5+1]*v[t][1] + swl[c*5+2]*v[t][2] +
              swl[c*5+3]*v[t][3] + swl[c*5+4]*v[t][4];
      sb[t] = swl[10+c*5]*v[t][0] + swl[10+c*5+1]*v[t][1] + swl[10+c*5+2]*v[t][2] +
              swl[10+c*5+3]*v[t][3] + swl[10+c*5+4]*v[t][4];
      sc[t] = swl[20+c*5]*v[t][0] + swl[20+c*5+1]*v[t][1] + swl[20+c*5+2]*v[t][2] +
              swl[20+c*5+3]*v[t][3] + swl[20+c*5+4]*v[t][4];
      tb[c][ty][tx4 * 4 + t] = sb[t];
      tc[c][ty][tx4 * 4 + t] = sc[t];
    }
    *(unsigned int*)(a_out + c * NN + (size_t)n * NDIM + m0) =
        pk4fp8(sa[0], sa[1], sa[2], sa[3]);
  }
  __syncthreads();
  const int mm = bx + ty, nn0 = by + tx4 * 4;
#pragma unroll
  for (int c = 0; c < CDIM; ++c) {
    float b0 = tb[c][tx4*4+0][ty], b1 = tb[c][tx4*4+1][ty];
    float b2 = tb[c][tx4*4+2][ty], b3 = tb[c][tx4*4+3][ty];
    float c0 = tc[c][tx4*4+0][ty], c1 = tc[c][tx4*4+1][ty];
    float c2 = tc[c][tx4*4+2][ty], c3 = tc[c][tx4*4+3][ty];
    *(unsigned int*)(bT + c * NN + (size_t)mm * NDIM + nn0) = pk4fp8(b0, b1, b2, b3);
    *(unsigned int*)(a1T + c * NN + (size_t)mm * NDIM + nn0) = pk4fp8(c0, c1, c2, c3);
  }
}

// ---------------------------------------------------------------------------
// fp8 GEMM body (MX unit scale, B^T input, 128x128 tile, BK=128, swizzled)
// ---------------------------------------------------------------------------
__device__ __forceinline__ void fp8_gemm_body(
    const unsigned char* __restrict__ A, const unsigned char* __restrict__ B,
    __hip_bfloat16* __restrict__ Cp, float* __restrict__ csp,
    int K, int ldc, int row0, int col0,
    unsigned char* As, unsigned char* Bs) {
  const int tid = threadIdx.x;
  const int lane = tid & 63;
  const int wave = tid >> 6;
  const int wr = (wave >> 1) * 64;
  const int wc = (wave & 1) * 64;
  const int q = lane >> 4;
  const int r = lane & 15;

  float4v acc[4][4] = {};

  const int srow = lane >> 3;
  const int scol = ((lane & 7) ^ (srow & 7)) * 16;
  const int fsw = r & 15 & 7;

  for (int k0 = 0; k0 < K; k0 += 128) {
    __syncthreads();
#pragma unroll
    for (int s = 0; s < 4; ++s) {
      gl2lds16(A + (size_t)(row0 + s * 32 + wave * 8 + srow) * K + k0 + scol,
               As + s * 4096 + wave * 1024);
      gl2lds16(B + (size_t)(col0 + s * 32 + wave * 8 + srow) * K + k0 + scol,
               Bs + s * 4096 + wave * 1024);
    }
    __syncthreads();

    union { int8v v; int4v h[2]; } ua[4], ub[4];
#pragma unroll
    for (int i = 0; i < 4; ++i) {
      const unsigned char* pa = As + (size_t)(wr + i * 16 + r) * 128;
      const unsigned char* pb = Bs + (size_t)(wc + i * 16 + r) * 128;
      ua[i].h[0] = *(const int4v*)(pa + (((2 * q) ^ fsw) * 16));
      ua[i].h[1] = *(const int4v*)(pa + (((2 * q + 1) ^ fsw) * 16));
      ub[i].h[0] = *(const int4v*)(pb + (((2 * q) ^ fsw) * 16));
      ub[i].h[1] = *(const int4v*)(pb + (((2 * q + 1) ^ fsw) * 16));
    }
#pragma unroll
    for (int i = 0; i < 4; ++i)
#pragma unroll
      for (int j = 0; j < 4; ++j)
        acc[i][j] = __builtin_amdgcn_mfma_scale_f32_16x16x128_f8f6f4(
            ua[i].v, ub[j].v, acc[i][j], 0, 0, 0, 0x7F7F7F7F, 0, 0x7F7F7F7F);
  }

#pragma unroll
  for (int i = 0; i < 4; ++i) {
    int row = row0 + wr + i * 16 + q * 4;
#pragma unroll
    for (int j = 0; j < 4; ++j) {
      int col = col0 + wc + j * 16 + r;
#pragma unroll
      for (int e = 0; e < 4; ++e)
        Cp[(size_t)(row + e) * ldc + col] = __float2bfloat16(acc[i][j][e]);
    }
  }

  if (csp) {
#pragma unroll
    for (int j = 0; j < 4; ++j) {
      int col = col0 + wc + j * 16 + r;
      float s = 0.f;
#pragma unroll
      for (int i = 0; i < 4; ++i) {
        int rowb = row0 + wr + i * 16 + q * 4;
#pragma unroll
        for (int e = 0; e < 4; ++e)
          if (rowb + e != col) s += acc[i][j][e];
      }
      s += __shfl_xor(s, 16, 64);
      s += __shfl_xor(s, 32, 64);
      if (lane < 16) atomicAdd(&csp[col], s);
    }
  }
}

// ---------------------------------------------------------------------------
// bf16 GEMM body (B^T input, 128x128 tile, BK=64, swizzled, bf16 out)
// ---------------------------------------------------------------------------
__device__ __forceinline__ void bf16_gemm_body(
    const __hip_bfloat16* __restrict__ A, const __hip_bfloat16* __restrict__ B,
    __hip_bfloat16* __restrict__ Cp, int K, int ldc, int row0, int col0,
    int kbeg, int kend, char* As, char* Bs) {
  const int tid = threadIdx.x;
  const int lane = tid & 63;
  const int wave = tid >> 6;
  const int wr = (wave >> 1) * 64;
  const int wc = (wave & 1) * 64;
  const int q = lane >> 4;
  const int r = lane & 15;

  float4v acc[4][4] = {};

  const int srow = lane >> 3;
  const int scol = ((lane & 7) ^ (srow & 7)) * 8;
  const int fsw = r & 7;

  for (int k0 = kbeg; k0 < kend; k0 += 64) {
    __syncthreads();
#pragma unroll
    for (int s = 0; s < 4; ++s) {
      gl2lds16(A + (size_t)(row0 + s * 32 + wave * 8 + srow) * K + k0 + scol,
               As + s * 4096 + wave * 1024);
      gl2lds16(B + (size_t)(col0 + s * 32 + wave * 8 + srow) * K + k0 + scol,
               Bs + s * 4096 + wave * 1024);
    }
    __syncthreads();
#pragma unroll
    for (int h = 0; h < 2; ++h) {
      short8v af[4], bf[4];
#pragma unroll
      for (int i = 0; i < 4; ++i) {
        af[i] = *(const short8v*)(As + (size_t)(wr + i * 16 + r) * 128 +
                                  (((h * 4 + q) ^ fsw) * 16));
        bf[i] = *(const short8v*)(Bs + (size_t)(wc + i * 16 + r) * 128 +
                                  (((h * 4 + q) ^ fsw) * 16));
      }
#pragma unroll
      for (int i = 0; i < 4; ++i)
#pragma unroll
        for (int j = 0; j < 4; ++j)
          acc[i][j] = __builtin_amdgcn_mfma_f32_16x16x32_bf16(af[i], bf[j], acc[i][j], 0, 0, 0);
    }
  }

#pragma unroll
  for (int i = 0; i < 4; ++i) {
    int row = row0 + wr + i * 16 + q * 4;
#pragma unroll
    for (int j = 0; j < 4; ++j) {
      int col = col0 + wc + j * 16 + r;
#pragma unroll
      for (int e = 0; e < 4; ++e)
        Cp[(size_t)(row + e) * ldc + col] = __float2bfloat16(acc[i][j][e]);
    }
  }
}

// ---------------------------------------------------------------------------
// combined launch: z<2 -> GEMM1 batch z (H = a@b, fp8, col sums); z==2,y==0
// -> XWT[128][2048] = WTbf @ Xbf^T (bf16, K=256).
// ---------------------------------------------------------------------------
__global__ __launch_bounds__(256) void gemm1_xwt_k(
    const unsigned char* __restrict__ P_a, const unsigned char* __restrict__ P_bT,
    __hip_bfloat16* __restrict__ H_bf, float* __restrict__ deg,
    const __hip_bfloat16* __restrict__ WTbf, const __hip_bfloat16* __restrict__ Xbf,
    __hip_bfloat16* __restrict__ XWT) {
  __shared__ __align__(16) unsigned char smem[32768];
  const int z = blockIdx.z;
  if (z < 2) {
    fp8_gemm_body(P_a + (size_t)z * NN, P_bT + (size_t)z * NN,
                  H_bf + (size_t)z * NN, deg + (size_t)z * NDIM,
                  NDIM, NDIM, blockIdx.y * 128, blockIdx.x * 128,
                  smem, smem + 16384);
  } else {
    if (blockIdx.y != 0) return;
    bf16_gemm_body(WTbf, Xbf, XWT, WIN, NDIM, 0, blockIdx.x * 128,
                   0, WIN, (char*)smem, (char*)smem + 16384);
  }
}

// GEMM2: H1T*HNSC = a1T @ (Hn*HNSC)^T, fp8, no col sums
__global__ __launch_bounds__(256) void gemm2_k(
    const unsigned char* __restrict__ P_a1T, const unsigned char* __restrict__ P_Hn,
    __hip_bfloat16* __restrict__ H1T_bf) {
  __shared__ __align__(16) unsigned char smem[32768];
  const int z = blockIdx.z;
  fp8_gemm_body(P_a1T + (size_t)z * NN, P_Hn + (size_t)z * NN,
                H1T_bf + (size_t)z * NN, nullptr,
                NDIM, NDIM, blockIdx.y * 128, blockIdx.x * 128,
                smem, smem + 16384);
}

// bf16 tail GEMM: out bf16 at batch*sC + split*sSplit (bf16 elems)
__global__ __launch_bounds__(256) void mfma_bt_k(
    const __hip_bfloat16* __restrict__ Ab, const __hip_bfloat16* __restrict__ Bt,
    __hip_bfloat16* __restrict__ Cv, int K, int ldc,
    size_t sA, size_t sB, size_t sC, size_t sSplit, int nsplit) {
  __shared__ __align__(16) char smem[32768];
  const int batch = blockIdx.z / nsplit;
  const int split = blockIdx.z - batch * nsplit;
  const int kchunk = K / nsplit;
  bf16_gemm_body(Ab + (size_t)batch * sA, Bt + (size_t)batch * sB,
                 Cv + (size_t)batch * sC + (size_t)split * sSplit,
                 K, ldc, blockIdx.y * 128, blockIdx.x * 128,
                 split * kchunk, split * kchunk + kchunk,
                 smem, smem + 16384);
}

// ---------------------------------------------------------------------------
// Hn = norm(H, add=False): zero diag, col j scaled by HNSC/deg[j], fp8 out.
// ---------------------------------------------------------------------------
__global__ __launch_bounds__(256) void col_scale_k(const __hip_bfloat16* __restrict__ H,
                                                   const float* __restrict__ deg,
                                                   unsigned char* __restrict__ out) {
  size_t base = ((size_t)blockIdx.x * 256 + threadIdx.x) * 8;  // over 2*NN
  int c = (int)(base >> 22);
  int i = (int)((base >> 11) & (NDIM - 1));
  int j0 = (int)(base & (NDIM - 1));
  union { short8v v; unsigned short u[8]; } p;
  p.v = *(const short8v*)(H + base);
  float f[8];
#pragma unroll
  for (int t = 0; t < 8; ++t) {
    int j = j0 + t;
    float d = deg[c * NDIM + j];
    float inv = (d == 0.f) ? 0.f : HNSC / d;
    float v = (i == j) ? 0.f : bf2f(p.u[t]);
    f[t] = v * inv;
  }
  int2v o;
  o.x = (int)pk4fp8(f[0], f[1], f[2], f[3]);
  o.y = (int)pk4fp8(f[4], f[5], f[6], f[7]);
  *(int2v*)(out + base) = o;
}

// ---------------------------------------------------------------------------
// row norms over H1T (2ch bf16, values *HNSC): Hn2T[0], Hn2T[1], HsT bf16
// ---------------------------------------------------------------------------
__global__ __launch_bounds__(256) void rowmega_k(const __hip_bfloat16* __restrict__ H1T,
                                                 __hip_bfloat16* __restrict__ Hn2T,
                                                 __hip_bfloat16* __restrict__ HsT) {
  const int m = blockIdx.x;
  const int tid = threadIdx.x;
  const size_t rb = (size_t)m * NDIM + tid * 8;
  union { short8v v; unsigned short u[8]; } a0, a1;
  a0.v = *(const short8v*)(H1T + rb);
  a1.v = *(const short8v*)(H1T + NN + rb);
  float v0[8], v1[8];
  float s0 = 0.f, s1 = 0.f;
#pragma unroll
  for (int t = 0; t < 8; ++t) {
    v0[t] = bf2f(a0.u[t]) * HNSCI;
    v1[t] = bf2f(a1.u[t]) * HNSCI;
    s0 += v0[t]; s1 += v1[t];
  }
  __shared__ float ds[2];
  __shared__ float red[2][4];
  __shared__ float bc[3];
  if (tid == (m >> 3)) { ds[0] = v0[m & 7]; ds[1] = v1[m & 7]; }
  for (int off = 32; off > 0; off >>= 1) {
    s0 += __shfl_down(s0, off, 64);
    s1 += __shfl_down(s1, off, 64);
  }
  if ((tid & 63) == 0) { red[0][tid >> 6] = s0; red[1][tid >> 6] = s1; }
  __syncthreads();
  if (tid == 0) {
    float t0 = red[0][0] + red[0][1] + red[0][2] + red[0][3];
    float t1 = red[1][0] + red[1][1] + red[1][2] + red[1][3];
    float r0 = t0 - ds[0] + 1.f;
    float r1 = t1 - ds[1] + 1.f;
    float rs = t0 + t1 - ds[0] - ds[1] + 1.f;
    bc[0] = (r0 == 0.f) ? 0.f : 1.f / r0;
    bc[1] = (r1 == 0.f) ? 0.f : 1.f / r1;
    bc[2] = (rs == 0.f) ? 0.f : 1.f / rs;
  }
  __syncthreads();
  float i0 = bc[0], i1 = bc[1], is = bc[2];
  union { short8v v; unsigned short u[8]; } o0, o1, os;
#pragma unroll
  for (int t = 0; t < 8; ++t) {
    bool dg = (tid * 8 + t == m);
    o0.u[t] = f2bf((dg ? 1.f : v0[t]) * i0);
    o1.u[t] = f2bf((dg ? 1.f : v1[t]) * i1);
    os.u[t] = f2bf((dg ? 1.f : (v0[t] + v1[t])) * is);
  }
  *(short8v*)(Hn2T + rb) = o0.v;
  *(short8v*)(Hn2T + NN + rb) = o1.v;
  *(short8v*)(HsT + rb) = os.v;
}

// ---------------------------------------------------------------------------
// Xcat[n][c*128+d] = relu(sum_s P7[c][s][n][d])  (8 bf16 partials -> bf16)
// ---------------------------------------------------------------------------
__global__ __launch_bounds__(256) void reduce_relu_k(const __hip_bfloat16* __restrict__ P7,
                                                     __hip_bfloat16* __restrict__ Xcat) {
  int idx = blockIdx.x * 256 + threadIdx.x;  // 524288
  int c = idx >> 18;
  int rem = idx & 262143;
  float s = 0.f;
#pragma unroll
  for (int sp = 0; sp < 8; ++sp)
    s += __bfloat162float(P7[(size_t)c * 2097152 + (size_t)sp * 262144 + rem]);
  int n = rem >> 7, d = rem & 127;
  Xcat[(size_t)n * 256 + (c << 7) + d] = __float2bfloat16(fmaxf(s, 0.f));
}

// ---------------------------------------------------------------------------
// blocks [0,2048): BCE loss row n (sums 8 bf16 partials, cols 128..384).
// blocks [2048,3072): y + class loss (cols 0..128).
// ---------------------------------------------------------------------------
__global__ __launch_bounds__(256) void loss_mega_k(const __hip_bfloat16* __restrict__ P10,
                                                   const float* __restrict__ X,
                                                   const float* __restrict__ lin_w,
                                                   const float* __restrict__ lin_b,
                                                   const int* __restrict__ txs,
                                                   const int* __restrict__ tgt,
                                                   float* __restrict__ yout,
                                                   float* __restrict__ acc) {
  const int b = blockIdx.x;
  const int tid = threadIdx.x;
  if (b < 2048) {
    float xr = 0.f;
#pragma unroll
    for (int sp = 0; sp < 8; ++sp)
      xr += __bfloat162float(P10[(size_t)sp * 786432 + (size_t)b * 384 + 128 + tid]);
    if (xr > 1.f) xr = 1.f / (1.f + expf(-xr));
    if (xr < 0.f) xr = 1.f / (1.f + expf(-xr));
    float p = fminf(fmaxf(xr, 1e-7f), 1.f - 1e-7f);
    float xv = X[(size_t)b * WIN + tid];
    float t = xv * logf(p) + (1.f - xv) * log1pf(-p);
    for (int off = 32; off > 0; off >>= 1) t += __shfl_down(t, off, 64);
    __shared__ float red[4];
    if ((tid & 63) == 0) red[tid >> 6] = t;
    __syncthreads();
    if (tid == 0) atomicAdd(acc + 1, red[0] + red[1] + red[2] + red[3]);
    return;
  }
  const int t = b - 2048;
  __shared__ float xo[WOUT];
  __shared__ float ys[NCLS];
  int x = txs[t];
  if (tid < WOUT) {
    float s = 0.f;
#pragma unroll
    for (int sp = 0; sp < 8; ++sp)
      s += __bfloat162float(P10[(size_t)sp * 786432 + (size_t)x * 384 + tid]);
    xo[tid] = s;
  }
  __syncthreads();
  if (tid < NCLS) {
    float s = lin_b[tid];
    for (int d = 0; d < WOUT; ++d) s += xo[d] * lin_w[tid * WOUT + d];
    ys[tid] = s;
    yout[(size_t)t * NCLS + tid] = s;
  }
  __syncthreads();
  if (tid == 0) {
    float m = ys[0];
    for (int k = 1; k < NCLS; ++k) m = fmaxf(m, ys[k]);
    float se = 0.f;
    for (int k = 0; k < NCLS; ++k) se += expf(ys[k] - m);
    float lse = m + logf(se);
    atomicAdd(acc, lse - ys[tgt[t]]);
  }
}

__global__ void finalize_k(const float* __restrict__ acc, float* __restrict__ dout) {
  float lossC = acc[0] / (float)NTGT;
  float lossR = -acc[1] / (float)(NDIM * WIN);
  dout[0] = lossC + lossR;
  dout[1 + NTGT * NCLS + 30] = lossR;
}

// ---------------------------------------------------------------------------
extern "C" void kernel_launch(void* const* d_in, const int* in_sizes, int n_in,
                              void* d_out, int out_size, void* d_ws, size_t ws_size,
                              hipStream_t stream) {
  const float* A    = (const float*)d_in[0];
  const float* X    = (const float*)d_in[1];
  const float* W    = (const float*)d_in[2];
  const float* W1   = (const float*)d_in[3];
  const float* W2   = (const float*)d_in[4];
  const float* linw = (const float*)d_in[5];
  const float* linb = (const float*)d_in[6];
  const float* w0a  = (const float*)d_in[7];
  const float* w0b  = (const float*)d_in[8];
  const float* w1a  = (const float*)d_in[9];
  const int* txs    = (const int*)d_in[10];
  const int* tgt    = (const int*)d_in[11];
  float* dout = (float*)d_out;

  float* ws = (float*)d_ws;
  unsigned char* wb = (unsigned char*)d_ws;
  unsigned char* P_a   = wb;
  unsigned char* P_bT  = wb + 2 * NN;
  unsigned char* P_a1T = wb + 4 * NN;
  unsigned char* P_Hn  = wb + 6 * NN;
  __hip_bfloat16* H_bf   = (__hip_bfloat16*)(ws + 2 * NN);  // H (2ch)
  __hip_bfloat16* H1T_bf = (__hip_bfloat16*)(ws + 3 * NN);  // H1T*HNSC (2ch)
  __hip_bfloat16* Hn2T   = (__hip_bfloat16*)(ws + 4 * NN);  // (2ch)
  __hip_bfloat16* HsT    = (__hip_bfloat16*)(ws);           // 1ch, overlays dead fp8 a/bT
  float* sm   = ws + 5 * NN;
  float* acc   = sm;                 sm += 16;
  float* deg   = sm;                 sm += CDIM * NDIM;
  __hip_bfloat16* Xbf    = (__hip_bfloat16*)sm;  sm += N_XBF / 2;
  __hip_bfloat16* WTbf   = (__hip_bfloat16*)sm;  sm += N_WT / 2;
  __hip_bfloat16* W12Tbf = (__hip_bfloat16*)sm;  sm += N_W12T / 2;
  __hip_bfloat16* XWT    = (__hip_bfloat16*)sm;  sm += (size_t)WOUT * NDIM / 2;
  __hip_bfloat16* Xcat   = (__hip_bfloat16*)sm;  sm += (size_t)NDIM * 256 / 2;
  __hip_bfloat16* XC12T  = (__hip_bfloat16*)sm;  sm += (size_t)384 * NDIM / 2;
  __hip_bfloat16* P7bf   = (__hip_bfloat16*)sm;  sm += (size_t)16 * 262144 / 2; // [c][s][2048][128]
  __hip_bfloat16* P10bf  = (__hip_bfloat16*)sm;  sm += (size_t)8 * 786432 / 2;  // [s][2048][384]

  dim3 blk256(256);

  // 1. fused setup: a/bT/a1T fp8 + Xbf/WTbf/W12Tbf + deg/acc zero + Ws
  wsum_mega_k<<<dim3(4096 + (N_PREP + 255) / 256), blk256, 0, stream>>>(
      A, w0a, w0b, w1a, P_a, P_bT, P_a1T, acc, deg, X, W, W1, W2,
      Xbf, WTbf, W12Tbf, dout);
  // 2. GEMM1 (H, col sums) + XWT GEMM in one launch
  gemm1_xwt_k<<<dim3(16, 16, 3), blk256, 0, stream>>>(P_a, P_bT, H_bf, deg,
                                                      WTbf, Xbf, XWT);
  // 3. Hn*HNSC = colscale(H) -> fp8
  col_scale_k<<<dim3((unsigned)(2 * NN / 2048)), blk256, 0, stream>>>(H_bf, deg, P_Hn);
  // 4. H1T*HNSC = a1T @ (Hn*HNSC)^T -> bf16
  gemm2_k<<<dim3(16, 16, 2), blk256, 0, stream>>>(P_a1T, P_Hn, H1T_bf);
  // 5. row norms (descale 1/HNSC): Hn2T (2ch), HsT
  rowmega_k<<<dim3(NDIM), blk256, 0, stream>>>(H1T_bf, Hn2T, HsT);
  // 6. Xc partials: P7bf[c][s] = Hn2T[c] @ XWT^T (split-K 8, bf16 partials)
  mfma_bt_k<<<dim3(1, 16, 16), blk256, 0, stream>>>(Hn2T, XWT, P7bf, NDIM, WOUT,
                                                    NN, 0, 2097152, 262144, 8);
  // 7. Xcat bf16 = relu(sum partials)
  reduce_relu_k<<<dim3(2048), blk256, 0, stream>>>(P7bf, Xcat);
  // 8. XC12T[384][2048] = W12Tbf @ Xcat^T
  mfma_bt_k<<<dim3(16, 3, 1), blk256, 0, stream>>>(W12Tbf, Xcat, XC12T, 256, NDIM,
                                                   0, 0, 0, 0, 1);
  // 9. XoXr partials: P10bf[s] = HsT @ XC12T^T (split-K 8, bf16 partials)
  mfma_bt_k<<<dim3(3, 16, 8), blk256, 0, stream>>>(HsT, XC12T, P10bf, NDIM, 384,
                                                   0, 0, 0, 786432, 8);
  // 10. losses + y (sums P10 partials inline)
  loss_mega_k<<<dim3(2048 + NTGT), blk256, 0, stream>>>(P10bf, X, linw, linb, txs, tgt,
                                                        dout + 1, acc);
  finalize_k<<<dim3(1), dim3(1), 0, stream>>>(acc, dout);
}

// Round 9
// 282.410 us; speedup vs baseline: 7.0790x; 1.0243x over previous
//
#include <hip/hip_runtime.h>
#include <hip/hip_bf16.h>
#include <math.h>

#define NDIM 2048
#define EDIM 5
#define CDIM 2
#define WIN 256
#define WOUT 128
#define NCLS 8
#define NTGT 1024
#define NN ((size_t)NDIM * NDIM)
#define HNSC 256.0f          // Hn stored as fp8 * HNSC (raw ~5e-4 underflows e4m3)
#define HNSCI 0.00390625f    // 1/HNSC

typedef __attribute__((ext_vector_type(8))) short short8v;
typedef __attribute__((ext_vector_type(4))) float float4v;
typedef __attribute__((ext_vector_type(8))) int int8v;
typedef __attribute__((ext_vector_type(4))) int int4v;
typedef __attribute__((ext_vector_type(2))) int int2v;

__device__ __forceinline__ void gl2lds16(const void* g, void* l) {
  __builtin_amdgcn_global_load_lds((__attribute__((address_space(1))) const unsigned int*)g,
                                   (__attribute__((address_space(3))) unsigned int*)l, 16, 0, 0);
}
__device__ __forceinline__ float bf2f(unsigned short u) {
  return __uint_as_float(((unsigned)u) << 16);
}
__device__ __forceinline__ unsigned short f2bf(float f) {
  __hip_bfloat16 h = __float2bfloat16(f);
  return *(unsigned short*)&h;
}
__device__ __forceinline__ unsigned int pk4fp8(float a, float b, float c, float d) {
  int w = __builtin_amdgcn_cvt_pk_fp8_f32(a, b, 0, false);
  return (unsigned int)__builtin_amdgcn_cvt_pk_fp8_f32(c, d, w, true);
}

// ---------------------------------------------------------------------------
// mega setup. blocks < 4096: 32x32 tile of A -> a, bT, a1T (fp8, packed dword
// stores, float4 loads). blocks >= 4096: Xbf/WTbf/W12Tbf bf16, zero deg/acc,
// Ws softmax outputs.
// ---------------------------------------------------------------------------
#define N_XBF (NDIM * WIN)          // 524288
#define N_WT (WIN * WOUT)           // 32768
#define N_W12T (384 * WIN)          // 98304
#define N_PREP (N_XBF + N_WT + N_W12T + CDIM * NDIM + 16 + 30)
__global__ __launch_bounds__(256) void wsum_mega_k(
    const float* __restrict__ A, const float* __restrict__ w0a,
    const float* __restrict__ w0b, const float* __restrict__ w1a,
    unsigned char* __restrict__ a_out, unsigned char* __restrict__ bT,
    unsigned char* __restrict__ a1T,
    float* __restrict__ acc, float* __restrict__ deg,
    const float* __restrict__ X, const float* __restrict__ W,
    const float* __restrict__ W1, const float* __restrict__ W2,
    __hip_bfloat16* __restrict__ Xbf, __hip_bfloat16* __restrict__ WTbf,
    __hip_bfloat16* __restrict__ W12Tbf,
    float* __restrict__ dout) {
  const int b = blockIdx.x;
  const int tid = threadIdx.x;
  if (b >= 4096) {
    int idx = (b - 4096) * 256 + tid;
    if (idx < N_XBF) { Xbf[idx] = __float2bfloat16(X[idx]); return; }
    idx -= N_XBF;
    if (idx < N_WT) {
      int d = idx >> 8, k = idx & 255;
      WTbf[idx] = __float2bfloat16(W[k * WOUT + d]);
      return;
    }
    idx -= N_WT;
    if (idx < N_W12T) {
      int j = idx >> 8, k = idx & 255;
      W12Tbf[idx] = __float2bfloat16(j < 128 ? W1[k * 128 + j] : W2[k * 256 + (j - 128)]);
      return;
    }
    idx -= N_W12T;
    if (idx < CDIM * NDIM) { deg[idx] = 0.f; return; }
    idx -= CDIM * NDIM;
    if (idx < 16) { acc[idx] = 0.f; return; }
    idx -= 16;
    if (idx < 30) {
      int m = idx / 10, rr = idx - m * 10, c = rr / 5, e = rr - c * 5;
      const float* src = (m == 0) ? w0a : (m == 1) ? w0b : w1a;
      float mx = -1e30f;
      for (int t = 0; t < 5; ++t) mx = fmaxf(mx, src[c * 5 + t]);
      float s = 0.f, ve = 0.f;
      for (int t = 0; t < 5; ++t) {
        float ex = expf(src[c * 5 + t] - mx);
        s += ex;
        if (t == e) ve = ex;
      }
      dout[1 + NTGT * NCLS + idx] = ve / s;
    }
    return;
  }
  __shared__ float swl[32];
  __shared__ float tb[CDIM][32][33];
  __shared__ float tc[CDIM][32][33];
  if (tid < 6) {
    int m = tid >> 1, c = tid & 1;
    const float* src = (m == 0) ? w0a : (m == 1) ? w0b : w1a;
    float mx = -1e30f;
    for (int e = 0; e < 5; ++e) mx = fmaxf(mx, src[c * 5 + e]);
    float ex[5]; float s = 0.f;
    for (int e = 0; e < 5; ++e) { ex[e] = expf(src[c * 5 + e] - mx); s += ex[e]; }
    for (int e = 0; e < 5; ++e) swl[m * 10 + c * 5 + e] = ex[e] / s;
  }
  __syncthreads();
  const int bx = (b & 63) * 32, by = (b >> 6) * 32;
  const int tx4 = tid & 7, ty = tid >> 3;
  const int n = by + ty, m0 = bx + tx4 * 4;
  const float* ap = A + ((size_t)n * NDIM + m0) * EDIM;
  float4 f0 = *(const float4*)(ap);
  float4 f1 = *(const float4*)(ap + 4);
  float4 f2 = *(const float4*)(ap + 8);
  float4 f3 = *(const float4*)(ap + 12);
  float4 f4 = *(const float4*)(ap + 16);
  float v[4][5] = {{f0.x, f0.y, f0.z, f0.w, f1.x},
                   {f1.y, f1.z, f1.w, f2.x, f2.y},
                   {f2.z, f2.w, f3.x, f3.y, f3.z},
                   {f3.w, f4.x, f4.y, f4.z, f4.w}};
#pragma unroll
  for (int c = 0; c < CDIM; ++c) {
    float sa[4], sb[4], sc[4];
#pragma unroll
    for (int t = 0; t < 4; ++t) {
      sa[t] = swl[c*5]*v[t][0] + swl[c*5+1]*v[t][1] + swl[c*5+2]*v[t][2] +
              swl[c*5+3]*v[t][3] + swl[c*5+4]*v[t][4];
      sb[t] = swl[10+c*5]*v[t][0] + swl[10+c*5+1]*v[t][1] + swl[10+c*5+2]*v[t][2] +
              swl[10+c*5+3]*v[t][3] + swl[10+c*5+4]*v[t][4];
      sc[t] = swl[20+c*5]*v[t][0] + swl[20+c*5+1]*v[t][1] + swl[20+c*5+2]*v[t][2] +
              swl[20+c*5+3]*v[t][3] + swl[20+c*5+4]*v[t][4];
      tb[c][ty][tx4 * 4 + t] = sb[t];
      tc[c][ty][tx4 * 4 + t] = sc[t];
    }
    *(unsigned int*)(a_out + c * NN + (size_t)n * NDIM + m0) =
        pk4fp8(sa[0], sa[1], sa[2], sa[3]);
  }
  __syncthreads();
  const int mm = bx + ty, nn0 = by + tx4 * 4;
#pragma unroll
  for (int c = 0; c < CDIM; ++c) {
    float b0 = tb[c][tx4*4+0][ty], b1 = tb[c][tx4*4+1][ty];
    float b2 = tb[c][tx4*4+2][ty], b3 = tb[c][tx4*4+3][ty];
    float c0 = tc[c][tx4*4+0][ty], c1 = tc[c][tx4*4+1][ty];
    float c2 = tc[c][tx4*4+2][ty], c3 = tc[c][tx4*4+3][ty];
    *(unsigned int*)(bT + c * NN + (size_t)mm * NDIM + nn0) = pk4fp8(b0, b1, b2, b3);
    *(unsigned int*)(a1T + c * NN + (size_t)mm * NDIM + nn0) = pk4fp8(c0, c1, c2, c3);
  }
}

// ---------------------------------------------------------------------------
// fp8 GEMM body, DOUBLE-BUFFERED LDS (2 x 32 KB), ONE barrier per K-iter:
// iter k issues k+1's global_load_lds into the idle buffer before computing,
// so global latency overlaps ds_read+MFMA instead of being drained serially.
// ---------------------------------------------------------------------------
__device__ __forceinline__ void fp8_stage(const unsigned char* __restrict__ A,
                                          const unsigned char* __restrict__ B,
                                          int K, int row0, int col0, int k0,
                                          int wave, int srow, int scol,
                                          unsigned char* As, unsigned char* Bs) {
#pragma unroll
  for (int s = 0; s < 4; ++s) {
    gl2lds16(A + (size_t)(row0 + s * 32 + wave * 8 + srow) * K + k0 + scol,
             As + s * 4096 + wave * 1024);
    gl2lds16(B + (size_t)(col0 + s * 32 + wave * 8 + srow) * K + k0 + scol,
             Bs + s * 4096 + wave * 1024);
  }
}

__device__ __forceinline__ void fp8_gemm_body(
    const unsigned char* __restrict__ A, const unsigned char* __restrict__ B,
    __hip_bfloat16* __restrict__ Cp, float* __restrict__ csp,
    int K, int ldc, int row0, int col0, unsigned char* smem) {
  const int tid = threadIdx.x;
  const int lane = tid & 63;
  const int wave = tid >> 6;
  const int wr = (wave >> 1) * 64;
  const int wc = (wave & 1) * 64;
  const int q = lane >> 4;
  const int r = lane & 15;

  float4v acc[4][4] = {};

  const int srow = lane >> 3;
  const int scol = ((lane & 7) ^ (srow & 7)) * 16;
  const int fsw = r & 7;

  unsigned char* As[2] = {smem, smem + 32768};
  unsigned char* Bs[2] = {smem + 16384, smem + 49152};

  fp8_stage(A, B, K, row0, col0, 0, wave, srow, scol, As[0], Bs[0]);
  __syncthreads();

  int p = 0;
  for (int k0 = 0; k0 < K; k0 += 128, p ^= 1) {
    if (k0 + 128 < K)
      fp8_stage(A, B, K, row0, col0, k0 + 128, wave, srow, scol, As[p ^ 1], Bs[p ^ 1]);

    union { int8v v; int4v h[2]; } ua[4], ub[4];
#pragma unroll
    for (int i = 0; i < 4; ++i) {
      const unsigned char* pa = As[p] + (size_t)(wr + i * 16 + r) * 128;
      const unsigned char* pb = Bs[p] + (size_t)(wc + i * 16 + r) * 128;
      ua[i].h[0] = *(const int4v*)(pa + (((2 * q) ^ fsw) * 16));
      ua[i].h[1] = *(const int4v*)(pa + (((2 * q + 1) ^ fsw) * 16));
      ub[i].h[0] = *(const int4v*)(pb + (((2 * q) ^ fsw) * 16));
      ub[i].h[1] = *(const int4v*)(pb + (((2 * q + 1) ^ fsw) * 16));
    }
#pragma unroll
    for (int i = 0; i < 4; ++i)
#pragma unroll
      for (int j = 0; j < 4; ++j)
        acc[i][j] = __builtin_amdgcn_mfma_scale_f32_16x16x128_f8f6f4(
            ua[i].v, ub[j].v, acc[i][j], 0, 0, 0, 0x7F7F7F7F, 0, 0x7F7F7F7F);
    __syncthreads();  // waves done reading As[p]/Bs[p]; k+1 loads drained
  }

#pragma unroll
  for (int i = 0; i < 4; ++i) {
    int row = row0 + wr + i * 16 + q * 4;
#pragma unroll
    for (int j = 0; j < 4; ++j) {
      int col = col0 + wc + j * 16 + r;
#pragma unroll
      for (int e = 0; e < 4; ++e)
        Cp[(size_t)(row + e) * ldc + col] = __float2bfloat16(acc[i][j][e]);
    }
  }

  if (csp) {
#pragma unroll
    for (int j = 0; j < 4; ++j) {
      int col = col0 + wc + j * 16 + r;
      float s = 0.f;
#pragma unroll
      for (int i = 0; i < 4; ++i) {
        int rowb = row0 + wr + i * 16 + q * 4;
#pragma unroll
        for (int e = 0; e < 4; ++e)
          if (rowb + e != col) s += acc[i][j][e];
      }
      s += __shfl_xor(s, 16, 64);
      s += __shfl_xor(s, 32, 64);
      if (lane < 16) atomicAdd(&csp[col], s);
    }
  }
}

// ---------------------------------------------------------------------------
// bf16 GEMM body (B^T input, 128x128 tile, BK=64, swizzled, bf16 out)
// ---------------------------------------------------------------------------
__device__ __forceinline__ void bf16_gemm_body(
    const __hip_bfloat16* __restrict__ A, const __hip_bfloat16* __restrict__ B,
    __hip_bfloat16* __restrict__ Cp, int K, int ldc, int row0, int col0,
    int kbeg, int kend, char* As, char* Bs) {
  const int tid = threadIdx.x;
  const int lane = tid & 63;
  const int wave = tid >> 6;
  const int wr = (wave >> 1) * 64;
  const int wc = (wave & 1) * 64;
  const int q = lane >> 4;
  const int r = lane & 15;

  float4v acc[4][4] = {};

  const int srow = lane >> 3;
  const int scol = ((lane & 7) ^ (srow & 7)) * 8;
  const int fsw = r & 7;

  for (int k0 = kbeg; k0 < kend; k0 += 64) {
    __syncthreads();
#pragma unroll
    for (int s = 0; s < 4; ++s) {
      gl2lds16(A + (size_t)(row0 + s * 32 + wave * 8 + srow) * K + k0 + scol,
               As + s * 4096 + wave * 1024);
      gl2lds16(B + (size_t)(col0 + s * 32 + wave * 8 + srow) * K + k0 + scol,
               Bs + s * 4096 + wave * 1024);
    }
    __syncthreads();
#pragma unroll
    for (int h = 0; h < 2; ++h) {
      short8v af[4], bf[4];
#pragma unroll
      for (int i = 0; i < 4; ++i) {
        af[i] = *(const short8v*)(As + (size_t)(wr + i * 16 + r) * 128 +
                                  (((h * 4 + q) ^ fsw) * 16));
        bf[i] = *(const short8v*)(Bs + (size_t)(wc + i * 16 + r) * 128 +
                                  (((h * 4 + q) ^ fsw) * 16));
      }
#pragma unroll
      for (int i = 0; i < 4; ++i)
#pragma unroll
        for (int j = 0; j < 4; ++j)
          acc[i][j] = __builtin_amdgcn_mfma_f32_16x16x32_bf16(af[i], bf[j], acc[i][j], 0, 0, 0);
    }
  }

#pragma unroll
  for (int i = 0; i < 4; ++i) {
    int row = row0 + wr + i * 16 + q * 4;
#pragma unroll
    for (int j = 0; j < 4; ++j) {
      int col = col0 + wc + j * 16 + r;
#pragma unroll
      for (int e = 0; e < 4; ++e)
        Cp[(size_t)(row + e) * ldc + col] = __float2bfloat16(acc[i][j][e]);
    }
  }
}

// ---------------------------------------------------------------------------
// combined launch: z<2 -> GEMM1 batch z (H = a@b, fp8 dbuf, col sums);
// z==2,y==0 -> XWT[128][2048] = WTbf @ Xbf^T (bf16, K=256).
// ---------------------------------------------------------------------------
__global__ __launch_bounds__(256) void gemm1_xwt_k(
    const unsigned char* __restrict__ P_a, const unsigned char* __restrict__ P_bT,
    __hip_bfloat16* __restrict__ H_bf, float* __restrict__ deg,
    const __hip_bfloat16* __restrict__ WTbf, const __hip_bfloat16* __restrict__ Xbf,
    __hip_bfloat16* __restrict__ XWT) {
  __shared__ __align__(16) unsigned char smem[65536];
  const int z = blockIdx.z;
  if (z < 2) {
    fp8_gemm_body(P_a + (size_t)z * NN, P_bT + (size_t)z * NN,
                  H_bf + (size_t)z * NN, deg + (size_t)z * NDIM,
                  NDIM, NDIM, blockIdx.y * 128, blockIdx.x * 128, smem);
  } else {
    if (blockIdx.y != 0) return;
    bf16_gemm_body(WTbf, Xbf, XWT, WIN, NDIM, 0, blockIdx.x * 128,
                   0, WIN, (char*)smem, (char*)smem + 16384);
  }
}

// GEMM2: H1T*HNSC = a1T @ (Hn*HNSC)^T, fp8 dbuf, no col sums
__global__ __launch_bounds__(256) void gemm2_k(
    const unsigned char* __restrict__ P_a1T, const unsigned char* __restrict__ P_Hn,
    __hip_bfloat16* __restrict__ H1T_bf) {
  __shared__ __align__(16) unsigned char smem[65536];
  const int z = blockIdx.z;
  fp8_gemm_body(P_a1T + (size_t)z * NN, P_Hn + (size_t)z * NN,
                H1T_bf + (size_t)z * NN, nullptr,
                NDIM, NDIM, blockIdx.y * 128, blockIdx.x * 128, smem);
}

// bf16 tail GEMM: out bf16 at batch*sC + split*sSplit (bf16 elems)
__global__ __launch_bounds__(256) void mfma_bt_k(
    const __hip_bfloat16* __restrict__ Ab, const __hip_bfloat16* __restrict__ Bt,
    __hip_bfloat16* __restrict__ Cv, int K, int ldc,
    size_t sA, size_t sB, size_t sC, size_t sSplit, int nsplit) {
  __shared__ __align__(16) char smem[32768];
  const int batch = blockIdx.z / nsplit;
  const int split = blockIdx.z - batch * nsplit;
  const int kchunk = K / nsplit;
  bf16_gemm_body(Ab + (size_t)batch * sA, Bt + (size_t)batch * sB,
                 Cv + (size_t)batch * sC + (size_t)split * sSplit,
                 K, ldc, blockIdx.y * 128, blockIdx.x * 128,
                 split * kchunk, split * kchunk + kchunk,
                 smem, smem + 16384);
}

// ---------------------------------------------------------------------------
// Hn = norm(H, add=False): zero diag, col j scaled by HNSC/deg[j], fp8 out.
// ---------------------------------------------------------------------------
__global__ __launch_bounds__(256) void col_scale_k(const __hip_bfloat16* __restrict__ H,
                                                   const float* __restrict__ deg,
                                                   unsigned char* __restrict__ out) {
  size_t base = ((size_t)blockIdx.x * 256 + threadIdx.x) * 8;  // over 2*NN
  int c = (int)(base >> 22);
  int i = (int)((base >> 11) & (NDIM - 1));
  int j0 = (int)(base & (NDIM - 1));
  union { short8v v; unsigned short u[8]; } p;
  p.v = *(const short8v*)(H + base);
  float f[8];
#pragma unroll
  for (int t = 0; t < 8; ++t) {
    int j = j0 + t;
    float d = deg[c * NDIM + j];
    float inv = (d == 0.f) ? 0.f : HNSC / d;
    float v = (i == j) ? 0.f : bf2f(p.u[t]);
    f[t] = v * inv;
  }
  int2v o;
  o.x = (int)pk4fp8(f[0], f[1], f[2], f[3]);
  o.y = (int)pk4fp8(f[4], f[5], f[6], f[7]);
  *(int2v*)(out + base) = o;
}

// ---------------------------------------------------------------------------
// row norms over H1T (2ch bf16, values *HNSC): Hn2T[0], Hn2T[1], HsT bf16
// ---------------------------------------------------------------------------
__global__ __launch_bounds__(256) void rowmega_k(const __hip_bfloat16* __restrict__ H1T,
                                                 __hip_bfloat16* __restrict__ Hn2T,
                                                 __hip_bfloat16* __restrict__ HsT) {
  const int m = blockIdx.x;
  const int tid = threadIdx.x;
  const size_t rb = (size_t)m * NDIM + tid * 8;
  union { short8v v; unsigned short u[8]; } a0, a1;
  a0.v = *(const short8v*)(H1T + rb);
  a1.v = *(const short8v*)(H1T + NN + rb);
  float v0[8], v1[8];
  float s0 = 0.f, s1 = 0.f;
#pragma unroll
  for (int t = 0; t < 8; ++t) {
    v0[t] = bf2f(a0.u[t]) * HNSCI;
    v1[t] = bf2f(a1.u[t]) * HNSCI;
    s0 += v0[t]; s1 += v1[t];
  }
  __shared__ float ds[2];
  __shared__ float red[2][4];
  __shared__ float bc[3];
  if (tid == (m >> 3)) { ds[0] = v0[m & 7]; ds[1] = v1[m & 7]; }
  for (int off = 32; off > 0; off >>= 1) {
    s0 += __shfl_down(s0, off, 64);
    s1 += __shfl_down(s1, off, 64);
  }
  if ((tid & 63) == 0) { red[0][tid >> 6] = s0; red[1][tid >> 6] = s1; }
  __syncthreads();
  if (tid == 0) {
    float t0 = red[0][0] + red[0][1] + red[0][2] + red[0][3];
    float t1 = red[1][0] + red[1][1] + red[1][2] + red[1][3];
    float r0 = t0 - ds[0] + 1.f;
    float r1 = t1 - ds[1] + 1.f;
    float rs = t0 + t1 - ds[0] - ds[1] + 1.f;
    bc[0] = (r0 == 0.f) ? 0.f : 1.f / r0;
    bc[1] = (r1 == 0.f) ? 0.f : 1.f / r1;
    bc[2] = (rs == 0.f) ? 0.f : 1.f / rs;
  }
  __syncthreads();
  float i0 = bc[0], i1 = bc[1], is = bc[2];
  union { short8v v; unsigned short u[8]; } o0, o1, os;
#pragma unroll
  for (int t = 0; t < 8; ++t) {
    bool dg = (tid * 8 + t == m);
    o0.u[t] = f2bf((dg ? 1.f : v0[t]) * i0);
    o1.u[t] = f2bf((dg ? 1.f : v1[t]) * i1);
    os.u[t] = f2bf((dg ? 1.f : (v0[t] + v1[t])) * is);
  }
  *(short8v*)(Hn2T + rb) = o0.v;
  *(short8v*)(Hn2T + NN + rb) = o1.v;
  *(short8v*)(HsT + rb) = os.v;
}

// ---------------------------------------------------------------------------
// Xcat[n][c*128+d] = relu(sum_s P7[c][s][n][d])  (8 bf16 partials -> bf16)
// ---------------------------------------------------------------------------
__global__ __launch_bounds__(256) void reduce_relu_k(const __hip_bfloat16* __restrict__ P7,
                                                     __hip_bfloat16* __restrict__ Xcat) {
  int idx = blockIdx.x * 256 + threadIdx.x;  // 524288
  int c = idx >> 18;
  int rem = idx & 262143;
  float s = 0.f;
#pragma unroll
  for (int sp = 0; sp < 8; ++sp)
    s += __bfloat162float(P7[(size_t)c * 2097152 + (size_t)sp * 262144 + rem]);
  int n = rem >> 7, d = rem & 127;
  Xcat[(size_t)n * 256 + (c << 7) + d] = __float2bfloat16(fmaxf(s, 0.f));
}

// ---------------------------------------------------------------------------
// blocks [0,2048): BCE loss row n (sums 8 bf16 partials, cols 128..384).
// blocks [2048,3072): y + class loss (cols 0..128).
// ---------------------------------------------------------------------------
__global__ __launch_bounds__(256) void loss_mega_k(const __hip_bfloat16* __restrict__ P10,
                                                   const float* __restrict__ X,
                                                   const float* __restrict__ lin_w,
                                                   const float* __restrict__ lin_b,
                                                   const int* __restrict__ txs,
                                                   const int* __restrict__ tgt,
                                                   float* __restrict__ yout,
                                                   float* __restrict__ acc) {
  const int b = blockIdx.x;
  const int tid = threadIdx.x;
  if (b < 2048) {
    float xr = 0.f;
#pragma unroll
    for (int sp = 0; sp < 8; ++sp)
      xr += __bfloat162float(P10[(size_t)sp * 786432 + (size_t)b * 384 + 128 + tid]);
    if (xr > 1.f) xr = 1.f / (1.f + expf(-xr));
    if (xr < 0.f) xr = 1.f / (1.f + expf(-xr));
    float p = fminf(fmaxf(xr, 1e-7f), 1.f - 1e-7f);
    float xv = X[(size_t)b * WIN + tid];
    float t = xv * logf(p) + (1.f - xv) * log1pf(-p);
    for (int off = 32; off > 0; off >>= 1) t += __shfl_down(t, off, 64);
    __shared__ float red[4];
    if ((tid & 63) == 0) red[tid >> 6] = t;
    __syncthreads();
    if (tid == 0) atomicAdd(acc + 1, red[0] + red[1] + red[2] + red[3]);
    return;
  }
  const int t = b - 2048;
  __shared__ float xo[WOUT];
  __shared__ float ys[NCLS];
  int x = txs[t];
  if (tid < WOUT) {
    float s = 0.f;
#pragma unroll
    for (int sp = 0; sp < 8; ++sp)
      s += __bfloat162float(P10[(size_t)sp * 786432 + (size_t)x * 384 + tid]);
    xo[tid] = s;
  }
  __syncthreads();
  if (tid < NCLS) {
    float s = lin_b[tid];
    for (int d = 0; d < WOUT; ++d) s += xo[d] * lin_w[tid * WOUT + d];
    ys[tid] = s;
    yout[(size_t)t * NCLS + tid] = s;
  }
  __syncthreads();
  if (tid == 0) {
    float m = ys[0];
    for (int k = 1; k < NCLS; ++k) m = fmaxf(m, ys[k]);
    float se = 0.f;
    for (int k = 0; k < NCLS; ++k) se += expf(ys[k] - m);
    float lse = m + logf(se);
    atomicAdd(acc, lse - ys[tgt[t]]);
  }
}

__global__ void finalize_k(const float* __restrict__ acc, float* __restrict__ dout) {
  float lossC = acc[0] / (float)NTGT;
  float lossR = -acc[1] / (float)(NDIM * WIN);
  dout[0] = lossC + lossR;
  dout[1 + NTGT * NCLS + 30] = lossR;
}

// ---------------------------------------------------------------------------
extern "C" void kernel_launch(void* const* d_in, const int* in_sizes, int n_in,
                              void* d_out, int out_size, void* d_ws, size_t ws_size,
                              hipStream_t stream) {
  const float* A    = (const float*)d_in[0];
  const float* X    = (const float*)d_in[1];
  const float* W    = (const float*)d_in[2];
  const float* W1   = (const float*)d_in[3];
  const float* W2   = (const float*)d_in[4];
  const float* linw = (const float*)d_in[5];
  const float* linb = (const float*)d_in[6];
  const float* w0a  = (const float*)d_in[7];
  const float* w0b  = (const float*)d_in[8];
  const float* w1a  = (const float*)d_in[9];
  const int* txs    = (const int*)d_in[10];
  const int* tgt    = (const int*)d_in[11];
  float* dout = (float*)d_out;

  float* ws = (float*)d_ws;
  unsigned char* wb = (unsigned char*)d_ws;
  unsigned char* P_a   = wb;
  unsigned char* P_bT  = wb + 2 * NN;
  unsigned char* P_a1T = wb + 4 * NN;
  unsigned char* P_Hn  = wb + 6 * NN;
  __hip_bfloat16* H_bf   = (__hip_bfloat16*)(ws + 2 * NN);  // H (2ch)
  __hip_bfloat16* H1T_bf = (__hip_bfloat16*)(ws + 3 * NN);  // H1T*HNSC (2ch)
  __hip_bfloat16* Hn2T   = (__hip_bfloat16*)(ws + 4 * NN);  // (2ch)
  __hip_bfloat16* HsT    = (__hip_bfloat16*)(ws);           // 1ch, overlays dead fp8 a/bT
  float* sm   = ws + 5 * NN;
  float* acc   = sm;                 sm += 16;
  float* deg   = sm;                 sm += CDIM * NDIM;
  __hip_bfloat16* Xbf    = (__hip_bfloat16*)sm;  sm += N_XBF / 2;
  __hip_bfloat16* WTbf   = (__hip_bfloat16*)sm;  sm += N_WT / 2;
  __hip_bfloat16* W12Tbf = (__hip_bfloat16*)sm;  sm += N_W12T / 2;
  __hip_bfloat16* XWT    = (__hip_bfloat16*)sm;  sm += (size_t)WOUT * NDIM / 2;
  __hip_bfloat16* Xcat   = (__hip_bfloat16*)sm;  sm += (size_t)NDIM * 256 / 2;
  __hip_bfloat16* XC12T  = (__hip_bfloat16*)sm;  sm += (size_t)384 * NDIM / 2;
  __hip_bfloat16* P7bf   = (__hip_bfloat16*)sm;  sm += (size_t)16 * 262144 / 2; // [c][s][2048][128]
  __hip_bfloat16* P10bf  = (__hip_bfloat16*)sm;  sm += (size_t)8 * 786432 / 2;  // [s][2048][384]

  dim3 blk256(256);

  // 1. fused setup: a/bT/a1T fp8 + Xbf/WTbf/W12Tbf + deg/acc zero + Ws
  wsum_mega_k<<<dim3(4096 + (N_PREP + 255) / 256), blk256, 0, stream>>>(
      A, w0a, w0b, w1a, P_a, P_bT, P_a1T, acc, deg, X, W, W1, W2,
      Xbf, WTbf, W12Tbf, dout);
  // 2. GEMM1 (H, col sums, dbuf) + XWT GEMM in one launch
  gemm1_xwt_k<<<dim3(16, 16, 3), blk256, 0, stream>>>(P_a, P_bT, H_bf, deg,
                                                      WTbf, Xbf, XWT);
  // 3. Hn*HNSC = colscale(H) -> fp8
  col_scale_k<<<dim3((unsigned)(2 * NN / 2048)), blk256, 0, stream>>>(H_bf, deg, P_Hn);
  // 4. H1T*HNSC = a1T @ (Hn*HNSC)^T -> bf16 (dbuf)
  gemm2_k<<<dim3(16, 16, 2), blk256, 0, stream>>>(P_a1T, P_Hn, H1T_bf);
  // 5. row norms (descale 1/HNSC): Hn2T (2ch), HsT
  rowmega_k<<<dim3(NDIM), blk256, 0, stream>>>(H1T_bf, Hn2T, HsT);
  // 6. Xc partials: P7bf[c][s] = Hn2T[c] @ XWT^T (split-K 8, bf16 partials)
  mfma_bt_k<<<dim3(1, 16, 16), blk256, 0, stream>>>(Hn2T, XWT, P7bf, NDIM, WOUT,
                                                    NN, 0, 2097152, 262144, 8);
  // 7. Xcat bf16 = relu(sum partials)
  reduce_relu_k<<<dim3(2048), blk256, 0, stream>>>(P7bf, Xcat);
  // 8. XC12T[384][2048] = W12Tbf @ Xcat^T
  mfma_bt_k<<<dim3(16, 3, 1), blk256, 0, stream>>>(W12Tbf, Xcat, XC12T, 256, NDIM,
                                                   0, 0, 0, 0, 1);
  // 9. XoXr partials: P10bf[s] = HsT @ XC12T^T (split-K 8, bf16 partials)
  mfma_bt_k<<<dim3(3, 16, 8), blk256, 0, stream>>>(HsT, XC12T, P10bf, NDIM, 384,
                                                   0, 0, 0, 786432, 8);
  // 10. losses + y (sums P10 partials inline)
  loss_mega_k<<<dim3(2048 + NTGT), blk256, 0, stream>>>(P10bf, X, linw, linb, txs, tgt,
                                                        dout + 1, acc);
  finalize_k<<<dim3(1), dim3(1), 0, stream>>>(acc, dout);
}